// Round 3
// baseline (460.703 us; speedup 1.0000x reference)
//
#include <hip/hip_runtime.h>
#include <math.h>

#define HID 128
typedef unsigned int uint;
typedef unsigned short ushort;
typedef __attribute__((ext_vector_type(8))) short short8;
typedef __attribute__((ext_vector_type(4))) float floatx4;
typedef __attribute__((ext_vector_type(2))) float f32x2;

// ---------- bf16 helpers ----------
__device__ __forceinline__ ushort f2b(float f) {
  uint u = __float_as_uint(f);
  u += 0x7fffu + ((u >> 16) & 1u);
  return (ushort)(u >> 16);
}
__device__ __forceinline__ float b2f(ushort s) {
  return __uint_as_float(((uint)s) << 16);
}
__device__ __forceinline__ float blo(uint u) { return __uint_as_float(u << 16); }
__device__ __forceinline__ float bhi(uint u) { return __uint_as_float(u & 0xffff0000u); }
__device__ __forceinline__ f32x2 b2x2(uint u) {
  f32x2 r;
  r.x = __uint_as_float(u << 16);
  r.y = __uint_as_float(u & 0xffff0000u);
  return r;
}

__device__ __forceinline__ void gll16(const ushort* g, ushort* l) {
  __builtin_amdgcn_global_load_lds(
      (const __attribute__((address_space(1))) void*)g,
      (__attribute__((address_space(3))) void*)l, 16, 0, 0);
}

// Packed tile layout (128 rows x 32 k, bf16), 16B slot within tile:
//   slot = row*4 + (chunk ^ ((row>>1)&3)), chunk = k/8. Conflict-free staging+frags.
__device__ __forceinline__ size_t a_packed_us(int rr, int col) {
  int tm = rr >> 7, prow = rr & 127;
  int ptk = col >> 5, kin = col & 31;
  int sw = (kin >> 3) ^ ((prow >> 1) & 3);
  return (((size_t)tm * 4 + ptk) * 512 + (size_t)prow * 4 + sw) * 8 + (kin & 7);
}

// ================= CSR params ==============================================
#define CSR_CH 2048   // edges per block in hist/scatter passes
#define CSR_SH 9      // 512 nodes per bucket

struct EdgeStreams {
  const int* src[4]; const int* dst[4];
  int off[4]; uint rel[4]; uint ldb[4];
};

// ================= prologue: pack x + combine_rel + weight prep + hist ======
struct PackSeg { const float* X; ushort* out; int M, K, Ktiles, start; };
struct WBlk { const float* src; ushort* dst; int K; int start; };
struct Prolog {
  PackSeg pk[3];
  int crwstart, wstart, bstart, total;
  const float *Wk, *bk, *Wv, *bv, *a_rel, *m_rel, *p_rel;
  ushort* kw_dst[4];
  ushort* vw_dst[4];
  float* bcat;
  int kb_off[4], vb_off[4];
  WBlk wb[10];
  const float* bq;
  int bq_off[3];
  // edge-hist segment (block-granular, blocks [0, NBH))
  const int* edst[4];
  int eoff[4];
  uint* hist;       // transposed: hist[bucket][block]
  int NBs, NBH, NBK, E;
};

// combine_rel: Wk_rel[e] = Wk[i] @ a_rel[e] (and Wv/m_rel), written DIRECTLY in
// packed-B bf16 layout. p_rel[e,h]/sqrt(D)*log2(e) is baked into the k weights
// and bias so the gather's logit feeds exp2 with no per-edge scale.
__device__ void combine_rel_elem(const Prolog& P, int idx)
{
  int col  = idx & 127;
  int rest = idx >> 7;
  int row  = rest % 129;
  rest /= 129;
  int kv = rest & 1;
  int e  = rest >> 1;
  int i  = (e + 1) >> 1;           // styp = {0,1,1,2}
  int h = col >> 4, j = col & 15;
  const float* Wsrc = kv ? P.Wv : P.Wk;
  const float* bsrc = kv ? P.bv : P.bk;
  const float* rel  = kv ? P.m_rel : P.a_rel;
  float acc = 0.f;
  if (row < 128) {
#pragma unroll
    for (int d = 0; d < 16; ++d)
      acc += Wsrc[(size_t)i * 16384 + (size_t)row * 128 + h * 16 + d] *
             rel[((e * 8 + h) * 16 + d) * 16 + j];
  } else {
#pragma unroll
    for (int d = 0; d < 16; ++d)
      acc += bsrc[i * 128 + h * 16 + d] * rel[((e * 8 + h) * 16 + d) * 16 + j];
  }
  if (!kv) acc *= P.p_rel[e * 8 + h] * 0.36067376022224085f;  // 0.25 * log2(e)
  if (row < 128) {
    ushort* dst = kv ? P.vw_dst[e] : P.kw_dst[e];
    int tk = row >> 5, chunk = (row >> 3) & 3, m = row & 7;
    int swf = chunk ^ ((col >> 1) & 3);
    dst[((tk * 512 + col * 4 + swf) << 3) + m] = f2b(acc);
  } else {
    P.bcat[(kv ? P.vb_off[e] : P.kb_off[e]) + col] = acc;
  }
}

// pure layout conversion of row-major fp32 [K][128] weights to packed-B bf16
__device__ void conv_elem(const Prolog& P, int s0)
{
  int si = 0;
#pragma unroll
  for (int k = 1; k < 10; ++k)
    if (s0 >= P.wb[k].start) si = k;
  WBlk b = P.wb[si];
  int s = s0 - b.start;
  int tk = s >> 9, o = s & 511;
  int c = o >> 2, swf = o & 3;
  int chunk = swf ^ ((c >> 1) & 3);
  int r0 = tk * 32 + chunk * 8;
  ushort tmp[8];
#pragma unroll
  for (int m = 0; m < 8; ++m) {
    int r = r0 + m;
    tmp[m] = (r < b.K) ? f2b(b.src[(size_t)r * 128 + c]) : (ushort)0;
  }
  *(short8*)&b.dst[(size_t)s * 8] = *(short8*)tmp;
}

__global__ __launch_bounds__(256)
void prologue(Prolog P)
{
  __shared__ uint h[512];
  int bI = blockIdx.x;
  if (bI < P.NBH) {
    // --- edge histogram segment (block-granular) ---
    int et = bI / P.NBs;
    int i0 = (bI - et * P.NBs) * CSR_CH;
    const int* dp = P.edst[et];
    int off = P.eoff[et];
    for (int t = threadIdx.x; t < P.NBK; t += 256) h[t] = 0;
    __syncthreads();
#pragma unroll
    for (int j = 0; j < CSR_CH / 256; ++j) {
      int idx = i0 + j * 256 + threadIdx.x;
      if (idx < P.E) atomicAdd(&h[(uint)(off + dp[idx]) >> CSR_SH], 1u);
    }
    __syncthreads();
    for (int t = threadIdx.x; t < P.NBK; t += 256)
      P.hist[(size_t)t * P.NBH + bI] = h[t];
    return;
  }
  int gtid = (bI - P.NBH) * 256 + threadIdx.x;
  if (gtid >= P.total) return;
  if (gtid >= P.bstart) {
    int j = gtid - P.bstart;
    P.bcat[P.bq_off[j >> 7] + (j & 127)] = P.bq[j];
    return;
  }
  if (gtid >= P.wstart) { conv_elem(P, gtid - P.wstart); return; }
  if (gtid >= P.crwstart) { combine_rel_elem(P, gtid - P.crwstart); return; }
  int si = 0;
  if (gtid >= P.pk[2].start) si = 2;
  else if (gtid >= P.pk[1].start) si = 1;
  const PackSeg s = P.pk[si];
  int slot = gtid - s.start;
  int spm = s.Ktiles << 9;
  int tm = slot / spm, r2 = slot - tm * spm;
  int tk = r2 >> 9, o = r2 & 511;
  int row = o >> 2, sw = o & 3;
  int chunk = sw ^ ((row >> 1) & 3);
  int grow = tm * 128 + row;
  int gk = tk * 32 + chunk * 8;
  ushort tmp[8];
  if (grow < s.M && gk + 8 <= s.K) {
    const float* p = s.X + (size_t)grow * s.K + gk;
    float4 a = *(const float4*)p, b = *(const float4*)(p + 4);
    tmp[0] = f2b(a.x); tmp[1] = f2b(a.y); tmp[2] = f2b(a.z); tmp[3] = f2b(a.w);
    tmp[4] = f2b(b.x); tmp[5] = f2b(b.y); tmp[6] = f2b(b.z); tmp[7] = f2b(b.w);
  } else {
#pragma unroll
    for (int j = 0; j < 8; ++j) {
      int kk = gk + j;
      tmp[j] = (grow < s.M && kk < s.K) ? f2b(s.X[(size_t)grow * s.K + kk]) : (ushort)0;
    }
  }
  *(short8*)&s.out[(size_t)slot * 8] = *(short8*)tmp;
}

// ================= CSR build: two-level counting sort =======================
// Pass B: per-bucket exclusive scan over blocks (transposed hist: coalesced),
// bucket totals out
__global__ __launch_bounds__(256)
void bucket_scan(uint* __restrict__ hist, uint* __restrict__ bucketTot, int NBH)
{
  __shared__ uint ws[4];
  __shared__ uint carry_s;
  int b = blockIdx.x;
  int t = threadIdx.x, lane = t & 63, w = t >> 6;
  if (t == 0) carry_s = 0;
  __syncthreads();
  for (int base = 0; base < NBH; base += 256) {
    int i = base + t;
    uint x = (i < NBH) ? hist[(size_t)b * NBH + i] : 0u;
    uint v = x;
#pragma unroll
    for (int o = 1; o < 64; o <<= 1) {
      uint y = __shfl_up(v, o, 64);
      if (lane >= o) v += y;
    }
    if (lane == 63) ws[w] = v;
    __syncthreads();
    uint add = carry_s;
    for (int k = 0; k < w; ++k) add += ws[k];
    if (i < NBH) hist[(size_t)b * NBH + i] = add + v - x;
    __syncthreads();
    if (t == 255) carry_s = add + v;
    __syncthreads();
  }
  if (t == 0) bucketTot[b] = carry_s;
}

// local exclusive scan of bucketTot (<=512 entries) into sb[]; 2 slots/thread
__device__ __forceinline__ void base_scan(const uint* __restrict__ bucketTot,
                                          uint* sb, uint* ws, int NBK)
{
  int t = threadIdx.x, lane = t & 63, w = t >> 6;
  sb[t] = (t < NBK) ? bucketTot[t] : 0u;
  sb[t + 256] = (t + 256 < NBK) ? bucketTot[t + 256] : 0u;
  __syncthreads();
  uint a0 = sb[2 * t], a1 = sb[2 * t + 1];
  uint s = a0 + a1;
  uint v = s;
#pragma unroll
  for (int o = 1; o < 64; o <<= 1) {
    uint y = __shfl_up(v, o, 64);
    if (lane >= o) v += y;
  }
  if (lane == 63) ws[w] = v;
  __syncthreads();
  uint add = 0;
  for (int k = 0; k < w; ++k) add += ws[k];
  uint e0 = add + v - s;
  sb[2 * t] = e0;
  sb[2 * t + 1] = e0 + a0;
  __syncthreads();
}

// Pass C: scatter (payload, dst) into bucket-contiguous intermediate
__global__ __launch_bounds__(256)
void bucket_scatter(EdgeStreams es, const uint* __restrict__ hist,
                    const uint* __restrict__ bucketTot,
                    uint2* __restrict__ inter, int NBs, int NBH, int NBK, int E)
{
  __shared__ uint sb[516];
  __shared__ uint ws[4];
  __shared__ uint cur[512];
  base_scan(bucketTot, sb, ws, NBK);
  int b = blockIdx.x;
  int et = b / NBs;
  int i0 = (b - et * NBs) * CSR_CH;
  const int* dp = es.dst[et];
  const int* sp = es.src[et];
  int off = es.off[et];
  uint rel = es.rel[et], ldb = es.ldb[et];
  for (int t = threadIdx.x; t < NBK; t += 256)
    cur[t] = sb[t] + hist[(size_t)t * NBH + b];
  __syncthreads();
#pragma unroll
  for (int j = 0; j < CSR_CH / 256; ++j) {
    int idx = i0 + j * 256 + threadIdx.x;
    if (idx < E) {
      int g = off + dp[idx];
      uint pos = atomicAdd(&cur[(uint)g >> CSR_SH], 1u);
      inter[pos] = make_uint2(rel + (uint)sp[idx] * ldb, (uint)g);
    }
  }
}

// Pass D: one block per bucket; per-node count+scan in LDS, write starts and
// final payload into this block's contiguous region (single-writer lines).
__global__ __launch_bounds__(256)
void bucket_finalize(const uint2* __restrict__ inter,
                     const uint* __restrict__ bucketTot,
                     int* __restrict__ starts, uint* __restrict__ payload,
                     int Ntot, int NBK)
{
  __shared__ uint sb[516];
  __shared__ uint ncnt[512];
  __shared__ uint ws[4];
  base_scan(bucketTot, sb, ws, NBK);
  int b = blockIdx.x;
  int g0 = b << CSR_SH;
  int t = threadIdx.x, lane = t & 63, w = t >> 6;
  uint r0 = sb[b], r1 = sb[b + 1];
  if (b == NBK - 1 && t == 0) starts[Ntot] = (int)r1;
  ncnt[t] = 0; ncnt[t + 256] = 0;
  __syncthreads();
  for (uint i = r0 + t; i < r1; i += 256)
    atomicAdd(&ncnt[inter[i].y - g0], 1u);
  __syncthreads();
  uint a0 = ncnt[2 * t], a1 = ncnt[2 * t + 1];
  uint s = a0 + a1;
  uint v = s;
#pragma unroll
  for (int o = 1; o < 64; o <<= 1) {
    uint y = __shfl_up(v, o, 64);
    if (lane >= o) v += y;
  }
  if (lane == 63) ws[w] = v;
  __syncthreads();
  uint add = r0;
  for (int k = 0; k < w; ++k) add += ws[k];
  uint e0 = add + v - s;
  int gi = g0 + 2 * t;
  if (gi < Ntot)     starts[gi]     = (int)e0;
  if (gi + 1 < Ntot) starts[gi + 1] = (int)(e0 + a0);
  ncnt[2 * t] = e0;          // reuse as cursors
  ncnt[2 * t + 1] = e0 + a0;
  __syncthreads();
  for (uint i = r0 + t; i < r1; i += 256) {
    uint2 rec = inter[i];
    uint pos = atomicAdd(&ncnt[rec.y - g0], 1u);
    payload[pos] = rec.x;
  }
}

// ================= fused multi-segment MFMA GEMM ==========================
struct GemmSeg {
  const ushort* A; const ushort* B; const float* bias;
  void* out; const ushort* xsP;
  int Ktiles, ldo, Mreal, skip_idx, epi, NT, start;
};
struct Gemm3 { GemmSeg s[3]; const float* skip; int nseg; };

__launch_bounds__(256)
__global__ void gemm_sched(Gemm3 g3)
{
  __shared__ __align__(16) ushort As[2][4096];
  __shared__ __align__(16) ushort Bs[2][4096];
  int bid = blockIdx.x;
  int si = 0;
  if (g3.nseg > 1 && bid >= g3.s[1].start)
    si = (g3.nseg > 2 && bid >= g3.s[2].start) ? 2 : 1;
  const GemmSeg sg = g3.s[si];
  int local = bid - sg.start;
  int tm = local / sg.NT, tn = local - tm * sg.NT;

  const int t = threadIdx.x;
  const int wave = t >> 6, lane = t & 63;
  const int wm = (wave >> 1) * 64, wn = (wave & 1) * 64;
  const int l16 = lane & 15, quad = lane >> 4;
  const int Ktiles = sg.Ktiles;

  const ushort* Abase = sg.A + (size_t)tm * Ktiles * 4096;
  const ushort* Bbase = sg.B + (size_t)tn * Ktiles * 4096;

  floatx4 acc[4][4];
#pragma unroll
  for (int i = 0; i < 4; ++i)
#pragma unroll
    for (int j = 0; j < 4; ++j) acc[i][j] = (floatx4){0.f, 0.f, 0.f, 0.f};

  auto stage = [&](int tk, int buf) {
#pragma unroll
    for (int j = 0; j < 4; ++j) {
      int c = wave * 4 + j;
      if (c < 8)
        gll16(Abase + (size_t)tk * 4096 + c * 512 + lane * 8, &As[buf][c * 512]);
      else
        gll16(Bbase + (size_t)tk * 4096 + (c - 8) * 512 + lane * 8, &Bs[buf][(c - 8) * 512]);
    }
  };

  stage(0, 0);
  __syncthreads();

  for (int tk = 0; tk < Ktiles; ++tk) {
    int buf = tk & 1;
    if (tk + 1 < Ktiles) stage(tk + 1, buf ^ 1);

    short8 af[4], bfr[4];
    const int swz = (quad ^ ((l16 >> 1) & 3)) * 8;
#pragma unroll
    for (int i = 0; i < 4; ++i) {
      af[i]  = *(const short8*)&As[buf][(wm + i * 16 + l16) * 32 + swz];
      bfr[i] = *(const short8*)&Bs[buf][(wn + i * 16 + l16) * 32 + swz];
    }
#pragma unroll
    for (int mi = 0; mi < 4; ++mi)
#pragma unroll
      for (int ni = 0; ni < 4; ++ni)
        acc[mi][ni] = __builtin_amdgcn_mfma_f32_16x16x32_bf16(
            af[mi], bfr[ni], acc[mi][ni], 0, 0, 0);
    __syncthreads();
  }

  const int epi = sg.epi;
  float g = 0.f, omg = 0.f;
  if (epi == 2 || epi == 3) {
    float s = g3.skip[sg.skip_idx];
    g = 1.f / (1.f + __expf(-s));
    omg = 1.f - g;
  }
#pragma unroll
  for (int ni = 0; ni < 4; ++ni) {
    int col = tn * 128 + wn + ni * 16 + l16;
    float bb = sg.bias[col];
#pragma unroll
    for (int mi = 0; mi < 4; ++mi) {
      int rloc = wm + mi * 16 + quad * 4;
#pragma unroll
      for (int r = 0; r < 4; ++r) {
        int prow = rloc + r;
        int rr = tm * 128 + prow;
        float v = acc[mi][ni][r] + bb;
        if (epi == 0) {
          ((ushort*)sg.out)[(size_t)rr * sg.ldo + col] = f2b(v);
        } else if (epi == 1) {
          if (rr < sg.Mreal) ((float*)sg.out)[(size_t)rr * sg.ldo + col] = v;
        } else if (epi == 2) {
          if (rr < sg.Mreal) {
            float xo = b2f(sg.xsP[a_packed_us(rr, col)]);
            ((float*)sg.out)[(size_t)rr * sg.ldo + col] = fmaxf(g * v + omg * xo, 0.f);
          }
        } else if (epi == 3) {
          float xo = b2f(sg.xsP[a_packed_us(rr, col)]);
          ((ushort*)sg.out)[a_packed_us(rr, col)] = f2b(fmaxf(g * v + omg * xo, 0.f));
        } else {  // 4: plain packed bf16
          ((ushort*)sg.out)[a_packed_us(rr, col)] = f2b(v);
        }
      }
    }
  }
}

// ================= gather: one wave per dst node, 4x4 edges/iter ==========
// payload holds the precomputed byte offset of each edge's k-row (v at +256B),
// p_rel/sqrt(D)/log2e baked into k -> logit feeds exp2 directly. 16 edges per
// iteration: all 12 VMEM loads issued before any consume (MLP). Dot and
// accumulate use f32x2 (v_pk_fma_f32). Epilogue gelu spread over all 64 lanes.
struct GatherType { const ushort* q; ushort* agg; int ldq; };
struct GatherDesc { GatherType ty[3]; int n0, n1; };

__launch_bounds__(256)
__global__ void gather_all(const int* __restrict__ starts,
                           const uint* __restrict__ payload,
                           const ushort* __restrict__ kvbase,
                           GatherDesc gd, int Ntot)
{
  int wid = (blockIdx.x * 256 + threadIdx.x) >> 6;
  if (wid >= Ntot) return;
  int lane = threadIdx.x & 63;
  int g = lane >> 4, l = lane & 15;

  GatherType T;
  int d;
  if (wid < gd.n0)      { T = gd.ty[0]; d = wid; }
  else if (wid < gd.n1) { T = gd.ty[1]; d = wid - gd.n0; }
  else                  { T = gd.ty[2]; d = wid - gd.n1; }

  const char* kvl = (const char*)kvbase + l * 16;   // per-lane base, hoisted

  uint4 qv = *(const uint4*)(T.q + (size_t)d * T.ldq + l * 8);
  f32x2 q0 = b2x2(qv.x), q1 = b2x2(qv.y), q2 = b2x2(qv.z), q3 = b2x2(qv.w);

  int e0 = starts[wid], e1 = starts[wid + 1];
  float lsum = 0.f;
  f32x2 ac0 = {0.f, 0.f}, ac1 = {0.f, 0.f}, ac2 = {0.f, 0.f}, ac3 = {0.f, 0.f};

  for (int eb = e0; eb < e1; eb += 16) {
    uint p[4];
    bool act[4];
#pragma unroll
    for (int b = 0; b < 4; ++b) {
      int e = eb + g + 4 * b;
      act[b] = e < e1;
      p[b] = payload[act[b] ? e : e0];
    }
    uint4 kk[4], vv[4];
#pragma unroll
    for (int b = 0; b < 4; ++b) {
      const char* ba = kvl + p[b];
      kk[b] = *(const uint4*)ba;
      vv[b] = *(const uint4*)(ba + 256);
    }
    float ex[4];
#pragma unroll
    for (int b = 0; b < 4; ++b) {
      f32x2 dA = q0 * b2x2(kk[b].x);
      dA = __builtin_elementwise_fma(q1, b2x2(kk[b].y), dA);
      dA = __builtin_elementwise_fma(q2, b2x2(kk[b].z), dA);
      dA = __builtin_elementwise_fma(q3, b2x2(kk[b].w), dA);
      float pa = dA.x + dA.y;
      pa += __shfl_xor(pa, 1, 64);
      float t2 = exp2f(fminf(pa, 115.4f));
      ex[b] = act[b] ? t2 : 0.f;
    }
    lsum += (ex[0] + ex[1]) + (ex[2] + ex[3]);
#pragma unroll
    for (int b = 0; b < 4; ++b) {
      f32x2 xb = {ex[b], ex[b]};
      ac0 = __builtin_elementwise_fma(xb, b2x2(vv[b].x), ac0);
      ac1 = __builtin_elementwise_fma(xb, b2x2(vv[b].y), ac1);
      ac2 = __builtin_elementwise_fma(xb, b2x2(vv[b].z), ac2);
      ac3 = __builtin_elementwise_fma(xb, b2x2(vv[b].w), ac3);
    }
  }

  float s0 = ac0.x, s1 = ac0.y, s2 = ac1.x, s3 = ac1.y;
  float s4 = ac2.x, s5 = ac2.y, s6 = ac3.x, s7 = ac3.y;
#define MRG(v) v += __shfl_xor(v, 16, 64); v += __shfl_xor(v, 32, 64)
  MRG(lsum); MRG(s0); MRG(s1); MRG(s2); MRG(s3); MRG(s4); MRG(s5); MRG(s6); MRG(s7);
#undef MRG

  // each lane finishes channels c0 = 8*l + 2*g and c0+1
  float inv = 1.f / (lsum + 1e-16f);
  float m0 = (g & 1) ? s2 : s0, m1 = (g & 1) ? s6 : s4;
  float n0 = (g & 1) ? s3 : s1, n1 = (g & 1) ? s7 : s5;
  float x0 = ((g & 2) ? m1 : m0) * inv;
  float x1 = ((g & 2) ? n1 : n0) * inv;
  float g0 = 0.5f * x0 * (1.f + erff(x0 * 0.70710678118654752f));
  float g1 = 0.5f * x1 * (1.f + erff(x1 * 0.70710678118654752f));
  int tm = d >> 7, row = d & 127;
  int tk = l >> 2, sw = (l & 3) ^ ((row >> 1) & 3);
  size_t us = (((size_t)tm * 4 + tk) * 512 + (size_t)row * 4 + sw) * 8 + 2 * g;
  *(uint*)(T.agg + us) = ((uint)f2b(g1) << 16) | (uint)f2b(g0);
}

// ================= host =====================================================
extern "C" void kernel_launch(void* const* d_in, const int* in_sizes, int n_in,
                              void* d_out, int out_size, void* d_ws, size_t ws_size,
                              hipStream_t stream)
{
  const float* x_herb = (const float*)d_in[0];
  const float* x_ing  = (const float*)d_in[1];
  const float* x_tgt  = (const float*)d_in[2];
  const float* W_herb = (const float*)d_in[3];
  const float* b_herb = (const float*)d_in[4];
  const float* W_ing  = (const float*)d_in[5];
  const float* b_ing  = (const float*)d_in[6];
  const float* W_tgt  = (const float*)d_in[7];
  const float* b_tgt  = (const float*)d_in[8];
  const float* Wk     = (const float*)d_in[9];
  const float* bk     = (const float*)d_in[10];
  const float* Wq     = (const float*)d_in[11];
  const float* bq     = (const float*)d_in[12];
  const float* Wv     = (const float*)d_in[13];
  const float* bv     = (const float*)d_in[14];
  const float* a_rel  = (const float*)d_in[15];
  const float* m_rel  = (const float*)d_in[16];
  const float* p_rel  = (const float*)d_in[17];
  const float* Wa     = (const float*)d_in[18];
  const float* ba     = (const float*)d_in[19];
  const float* skip   = (const float*)d_in[20];
  const float* W_out  = (const float*)d_in[21];
  const float* b_out  = (const float*)d_in[22];
  const int* srcs[4] = {(const int*)d_in[23], (const int*)d_in[25],
                        (const int*)d_in[27], (const int*)d_in[29]};
  const int* dsts[4] = {(const int*)d_in[24], (const int*)d_in[26],
                        (const int*)d_in[28], (const int*)d_in[30]};

  const int Nh = in_sizes[0] / 400;
  const int Ni = in_sizes[1] / 300;
  const int Nt = in_sizes[2] / 200;
  const int E  = in_sizes[23];
  const int Ntot = Nh + Ni + Nt;

  const int MT_h = (Nh + 127) / 128, MT_i = (Ni + 127) / 128, MT_t = (Nt + 127) / 128;
  const int KT_h = 13, KT_i = 10, KT_t = 7;   // Kpad 416/320/224

  // CSR sort params
  const int NBs = (E + CSR_CH - 1) / CSR_CH;
  const int NBH = 4 * NBs;
  const int NBK = (Ntot + (1 << CSR_SH) - 1) >> CSR_SH;   // <= 511

  char* base = (char*)d_ws;
  size_t off = 0;
  auto A = [&](size_t bytes) -> void* {
    void* p = base + off; off += (bytes + 255) & ~(size_t)255; return p;
  };
  ushort* xp_h  = (ushort*)A((size_t)MT_h * KT_h * 8192);
  ushort* xp_i  = (ushort*)A((size_t)MT_i * KT_i * 8192);
  ushort* xp_t  = (ushort*)A((size_t)MT_t * KT_t * 8192);
  ushort* xsP_h = (ushort*)A((size_t)MT_h * 4 * 8192);
  ushort* xsP_i = (ushort*)A((size_t)MT_i * 4 * 8192);
  ushort* xsP_t = (ushort*)A((size_t)MT_t * 4 * 8192);
  ushort* fused_h = (ushort*)A((size_t)MT_h * 128 * 384 * 2);  // [q|k0|v0]
  ushort* fused_i = (ushort*)A((size_t)MT_i * 128 * 640 * 2);  // [q|k1|v1|k2|v2]
  ushort* fused_t = (ushort*)A((size_t)MT_t * 128 * 384 * 2);  // [q|k3|v3]
  ushort* aggp_h  = (ushort*)A((size_t)MT_h * 4 * 8192);
  ushort* aggp_i  = (ushort*)A((size_t)MT_i * 4 * 8192);
  ushort* aggp_t  = (ushort*)A((size_t)MT_t * 4 * 8192);
  ushort* htmp_p  = (ushort*)A((size_t)MT_h * 4 * 8192);
  ushort* Weff1_h = (ushort*)A((size_t)KT_h * 8192);
  ushort* Weff1_i = (ushort*)A((size_t)KT_i * 8192);
  ushort* Weff1_t = (ushort*)A((size_t)KT_t * 8192);
  ushort* Wcat_h = (ushort*)A((size_t)3 * 4 * 8192);
  ushort* Wcat_i = (ushort*)A((size_t)5 * 4 * 8192);
  ushort* Wcat_t = (ushort*)A((size_t)3 * 4 * 8192);
  float* bcat   = (float*)A(1408 * 4);
  ushort* Wa_t   = (ushort*)A((size_t)3 * 16384 * 2);
  ushort* Wout_t = (ushort*)A((size_t)16384 * 2);
  int* starts  = (int*)A((size_t)(Ntot + 4) * 4);
  uint* payload = (uint*)A((size_t)(4 * E + 8) * 4);
  uint* hist    = (uint*)A((size_t)NBK * NBH * 4);
  uint* bucketTot  = (uint*)A((size_t)NBK * 4);
  uint2* inter  = (uint2*)A((size_t)(4 * E + 8) * 8);
  (void)ws_size; (void)n_in;

  const int toff_h = 0, toff_i = Nh, toff_t = Nh + Ni;
  dim3 blk(256);

  uint fi2 = (uint)((size_t)(fused_i - fused_h) * 2);
  uint ft2 = (uint)((size_t)(fused_t - fused_h) * 2);

  // --- 1: prologue (pack x3 + combine_rel + all weight prep + edge hist) ---
  int sl_h = MT_h * KT_h * 512, sl_i = MT_i * KT_i * 512, sl_t = MT_t * KT_t * 512;
  Prolog P;
  P.pk[0] = {x_herb, xp_h, Nh, 400, KT_h, 0};
  P.pk[1] = {x_ing,  xp_i, Ni, 300, KT_i, sl_h};
  P.pk[2] = {x_tgt,  xp_t, Nt, 200, KT_t, sl_h + sl_i};
  P.crwstart = sl_h + sl_i + sl_t;
  P.wstart = P.crwstart + 4 * 2 * 129 * 128;
  {
    const float* wsrc10[10] = {W_herb, W_ing, W_tgt, Wq, Wq + 16384, Wq + 32768,
                               Wa, Wa + 16384, Wa + 32768, W_out};
    ushort* wdst10[10] = {Weff1_h, Weff1_i, Weff1_t, Wcat_h, Wcat_i, Wcat_t,
                          Wa_t, Wa_t + 16384, Wa_t + 32768, Wout_t};
    int wk10[10] = {400, 300, 200, 128, 128, 128, 128, 128, 128, 128};
    int wcum = 0;
    for (int z = 0; z < 10; ++z) {
      P.wb[z] = {wsrc10[z], wdst10[z], wk10[z], wcum};
      wcum += ((wk10[z] + 31) / 32) * 512;
    }
    P.bstart = P.wstart + wcum;
  }
  P.total = P.bstart + 384;
  P.Wk = Wk; P.bk = bk; P.Wv = Wv; P.bv = bv;
  P.a_rel = a_rel; P.m_rel = m_rel; P.p_rel = p_rel;
  P.kw_dst[0] = Wcat_h + 16384; P.vw_dst[0] = Wcat_h + 32768;
  P.kw_dst[1] = Wcat_i + 16384; P.vw_dst[1] = Wcat_i + 32768;
  P.kw_dst[2] = Wcat_i + 49152; P.vw_dst[2] = Wcat_i + 65536;
  P.kw_dst[3] = Wcat_t + 16384; P.vw_dst[3] = Wcat_t + 32768;
  P.bcat = bcat;
  P.kb_off[0] = 128;  P.vb_off[0] = 256;
  P.kb_off[1] = 512;  P.vb_off[1] = 640;
  P.kb_off[2] = 768;  P.vb_off[2] = 896;
  P.kb_off[3] = 1152; P.vb_off[3] = 1280;
  P.bq = bq;
  P.bq_off[0] = 0; P.bq_off[1] = 384; P.bq_off[2] = 1024;
  P.edst[0] = dsts[0]; P.eoff[0] = toff_i;
  P.edst[1] = dsts[1]; P.eoff[1] = toff_h;
  P.edst[2] = dsts[2]; P.eoff[2] = toff_t;
  P.edst[3] = dsts[3]; P.eoff[3] = toff_i;
  P.hist = hist; P.NBs = NBs; P.NBH = NBH; P.NBK = NBK; P.E = E;
  prologue<<<NBH + (P.total + 255) / 256, blk, 0, stream>>>(P);

  // --- 2: CSR build (scan -> scatter -> finalize) ---
  EdgeStreams ES;
  ES.src[0] = srcs[0]; ES.dst[0] = dsts[0]; ES.off[0] = toff_i;
  ES.rel[0] = 256u;        ES.ldb[0] = 768u;
  ES.src[1] = srcs[1]; ES.dst[1] = dsts[1]; ES.off[1] = toff_h;
  ES.rel[1] = fi2 + 256u;  ES.ldb[1] = 1280u;
  ES.src[2] = srcs[2]; ES.dst[2] = dsts[2]; ES.off[2] = toff_t;
  ES.rel[2] = fi2 + 768u;  ES.ldb[2] = 1280u;
  ES.src[3] = srcs[3]; ES.dst[3] = dsts[3]; ES.off[3] = toff_i;
  ES.rel[3] = ft2 + 256u;  ES.ldb[3] = 768u;
  bucket_scan<<<NBK, blk, 0, stream>>>(hist, bucketTot, NBH);
  bucket_scatter<<<NBH, blk, 0, stream>>>(ES, hist, bucketTot, inter, NBs, NBH, NBK, E);
  bucket_finalize<<<NBK, blk, 0, stream>>>(inter, bucketTot, starts, payload, Ntot, NBK);

  // --- 3: GEMM1  xs = x @ Win  (packed-A bf16 output) ---
  Gemm3 G1;
  G1.skip = skip; G1.nseg = 3;
  G1.s[0] = {xp_h, Weff1_h, b_herb, xsP_h, nullptr, KT_h, 0, 0, 0, 4, 1, 0};
  G1.s[1] = {xp_i, Weff1_i, b_ing,  xsP_i, nullptr, KT_i, 0, 0, 0, 4, 1, MT_h};
  G1.s[2] = {xp_t, Weff1_t, b_tgt,  xsP_t, nullptr, KT_t, 0, 0, 0, 4, 1, MT_h + MT_i};
  gemm_sched<<<MT_h + MT_i + MT_t, blk, 0, stream>>>(G1);

  // --- 4: GEMM2  [q|k|v] = xs @ Wcat (row-major bf16 fused output) ---
  Gemm3 G2;
  G2.skip = skip; G2.nseg = 3;
  G2.s[0] = {xsP_h, Wcat_h, bcat + 0,    fused_h, nullptr, 4, 384, 0, 0, 0, 3, 0};
  G2.s[1] = {xsP_i, Wcat_i, bcat + 384,  fused_i, nullptr, 4, 640, 0, 0, 0, 5, MT_h * 3};
  G2.s[2] = {xsP_t, Wcat_t, bcat + 1024, fused_t, nullptr, 4, 384, 0, 0, 0, 3,
             MT_h * 3 + MT_i * 5};
  gemm_sched<<<MT_h * 3 + MT_i * 5 + MT_t * 3, blk, 0, stream>>>(G2);

  // --- 5: gather attention (all types, one wave per node) ---
  GatherDesc GD;
  GD.n0 = Nh; GD.n1 = Nh + Ni;
  GD.ty[0] = {fused_h, aggp_h, 384};
  GD.ty[1] = {fused_i, aggp_i, 640};
  GD.ty[2] = {fused_t, aggp_t, 384};
  gather_all<<<(Ntot + 3) / 4, blk, 0, stream>>>(starts, payload, fused_h, GD, Ntot);

  // --- 6: fused epilogue GEMMs (Wa per type; skip from packed xs) ---
  float* outp = (float*)d_out;
  float* out_herb = outp;
  float* out_ing  = outp + (size_t)Nh * HID;
  float* out_tgt  = outp + (size_t)(Nh + Ni) * HID;
  Gemm3 GE;
  GE.skip = skip; GE.nseg = 3;
  GE.s[0] = {aggp_h, Wa_t + 0 * 16384, ba + 0 * 128, htmp_p, xsP_h,
             4, 0, 0, 0, 3, 1, 0};
  GE.s[1] = {aggp_i, Wa_t + 1 * 16384, ba + 1 * 128, out_ing, xsP_i,
             4, 128, Ni, 1, 2, 1, MT_h};
  GE.s[2] = {aggp_t, Wa_t + 2 * 16384, ba + 2 * 128, out_tgt, xsP_t,
             4, 128, Nt, 2, 2, 1, MT_h + MT_i};
  gemm_sched<<<MT_h + MT_i + MT_t, blk, 0, stream>>>(GE);

  // --- 7: final herb GEMM ---
  Gemm3 GF;
  GF.skip = skip; GF.nseg = 1;
  GF.s[0] = {htmp_p, Wout_t, b_out, out_herb, nullptr, 4, 128, Nh, 0, 1, 1, 0};
  GF.s[1] = GF.s[0]; GF.s[2] = GF.s[0];
  gemm_sched<<<MT_h, blk, 0, stream>>>(GF);
  (void)out_size;
}

// Round 4
// 436.677 us; speedup vs baseline: 1.0550x; 1.0550x over previous
//
#include <hip/hip_runtime.h>
#include <math.h>

#define HID 128
typedef unsigned int uint;
typedef unsigned short ushort;
typedef __attribute__((ext_vector_type(8))) short short8;
typedef __attribute__((ext_vector_type(4))) float floatx4;
typedef __attribute__((ext_vector_type(2))) float f32x2;

// ---------- bf16 helpers ----------
__device__ __forceinline__ ushort f2b(float f) {
  uint u = __float_as_uint(f);
  u += 0x7fffu + ((u >> 16) & 1u);
  return (ushort)(u >> 16);
}
__device__ __forceinline__ float b2f(ushort s) {
  return __uint_as_float(((uint)s) << 16);
}
__device__ __forceinline__ float blo(uint u) { return __uint_as_float(u << 16); }
__device__ __forceinline__ float bhi(uint u) { return __uint_as_float(u & 0xffff0000u); }
__device__ __forceinline__ f32x2 b2x2(uint u) {
  f32x2 r;
  r.x = __uint_as_float(u << 16);
  r.y = __uint_as_float(u & 0xffff0000u);
  return r;
}

__device__ __forceinline__ void gll16(const ushort* g, ushort* l) {
  __builtin_amdgcn_global_load_lds(
      (const __attribute__((address_space(1))) void*)g,
      (__attribute__((address_space(3))) void*)l, 16, 0, 0);
}

// Packed tile layout (128 rows x 32 k, bf16), 16B slot within tile:
//   slot = row*4 + (chunk ^ ((row>>1)&3)), chunk = k/8. Conflict-free staging+frags.
__device__ __forceinline__ size_t a_packed_us(int rr, int col) {
  int tm = rr >> 7, prow = rr & 127;
  int ptk = col >> 5, kin = col & 31;
  int sw = (kin >> 3) ^ ((prow >> 1) & 3);
  return (((size_t)tm * 4 + ptk) * 512 + (size_t)prow * 4 + sw) * 8 + (kin & 7);
}

// ================= CSR params ==============================================
#define CSR_CH 2048   // edges per block in hist/scatter passes
#define CSR_SH 9      // 512 nodes per bucket

struct EdgeStreams {
  const int* src[4]; const int* dst[4];
  int off[4]; uint rel[4]; uint ldb[4];
};

// ================= prologue: pack x + combine_rel + weight prep + hist ======
struct PackSeg { const float* X; ushort* out; int M, K, Ktiles, start; };
struct WBlk { const float* src; ushort* dst; int K; int start; };
struct Prolog {
  PackSeg pk[3];
  int crwstart, wstart, bstart, total;
  const float *Wk, *bk, *Wv, *bv, *a_rel, *m_rel, *p_rel;
  ushort* kw_dst[4];
  ushort* vw_dst[4];
  float* bcat;
  int kb_off[4], vb_off[4];
  WBlk wb[10];
  const float* bq;
  int bq_off[3];
  // edge-hist segment (block-granular, blocks [0, NBH))
  const int* edst[4];
  int eoff[4];
  uint* hist;       // transposed: hist[bucket][block]
  int NBs, NBH, NBK, E;
};

// combine_rel: Wk_rel[e] = Wk[i] @ a_rel[e] (and Wv/m_rel), written DIRECTLY in
// packed-B bf16 layout. p_rel[e,h]/sqrt(D)*log2(e) is baked into the k weights
// and bias so the gather's logit feeds exp2 with no per-edge scale.
__device__ void combine_rel_elem(const Prolog& P, int idx)
{
  int col  = idx & 127;
  int rest = idx >> 7;
  int row  = rest % 129;
  rest /= 129;
  int kv = rest & 1;
  int e  = rest >> 1;
  int i  = (e + 1) >> 1;           // styp = {0,1,1,2}
  int h = col >> 4, j = col & 15;
  const float* Wsrc = kv ? P.Wv : P.Wk;
  const float* bsrc = kv ? P.bv : P.bk;
  const float* rel  = kv ? P.m_rel : P.a_rel;
  float acc = 0.f;
  if (row < 128) {
#pragma unroll
    for (int d = 0; d < 16; ++d)
      acc += Wsrc[(size_t)i * 16384 + (size_t)row * 128 + h * 16 + d] *
             rel[((e * 8 + h) * 16 + d) * 16 + j];
  } else {
#pragma unroll
    for (int d = 0; d < 16; ++d)
      acc += bsrc[i * 128 + h * 16 + d] * rel[((e * 8 + h) * 16 + d) * 16 + j];
  }
  if (!kv) acc *= P.p_rel[e * 8 + h] * 0.36067376022224085f;  // 0.25 * log2(e)
  if (row < 128) {
    ushort* dst = kv ? P.vw_dst[e] : P.kw_dst[e];
    int tk = row >> 5, chunk = (row >> 3) & 3, m = row & 7;
    int swf = chunk ^ ((col >> 1) & 3);
    dst[((tk * 512 + col * 4 + swf) << 3) + m] = f2b(acc);
  } else {
    P.bcat[(kv ? P.vb_off[e] : P.kb_off[e]) + col] = acc;
  }
}

// pure layout conversion of row-major fp32 [K][128] weights to packed-B bf16
__device__ void conv_elem(const Prolog& P, int s0)
{
  int si = 0;
#pragma unroll
  for (int k = 1; k < 10; ++k)
    if (s0 >= P.wb[k].start) si = k;
  WBlk b = P.wb[si];
  int s = s0 - b.start;
  int tk = s >> 9, o = s & 511;
  int c = o >> 2, swf = o & 3;
  int chunk = swf ^ ((c >> 1) & 3);
  int r0 = tk * 32 + chunk * 8;
  ushort tmp[8];
#pragma unroll
  for (int m = 0; m < 8; ++m) {
    int r = r0 + m;
    tmp[m] = (r < b.K) ? f2b(b.src[(size_t)r * 128 + c]) : (ushort)0;
  }
  *(short8*)&b.dst[(size_t)s * 8] = *(short8*)tmp;
}

__global__ __launch_bounds__(256)
void prologue(Prolog P)
{
  __shared__ uint h[512];
  int bI = blockIdx.x;
  if (bI < P.NBH) {
    // --- edge histogram segment (block-granular) ---
    int et = bI / P.NBs;
    int i0 = (bI - et * P.NBs) * CSR_CH;
    const int* dp = P.edst[et];
    int off = P.eoff[et];
    for (int t = threadIdx.x; t < P.NBK; t += 256) h[t] = 0;
    __syncthreads();
#pragma unroll
    for (int j = 0; j < CSR_CH / 256; ++j) {
      int idx = i0 + j * 256 + threadIdx.x;
      if (idx < P.E) atomicAdd(&h[(uint)(off + dp[idx]) >> CSR_SH], 1u);
    }
    __syncthreads();
    for (int t = threadIdx.x; t < P.NBK; t += 256)
      P.hist[(size_t)t * P.NBH + bI] = h[t];
    return;
  }
  int gtid = (bI - P.NBH) * 256 + threadIdx.x;
  if (gtid >= P.total) return;
  if (gtid >= P.bstart) {
    int j = gtid - P.bstart;
    P.bcat[P.bq_off[j >> 7] + (j & 127)] = P.bq[j];
    return;
  }
  if (gtid >= P.wstart) { conv_elem(P, gtid - P.wstart); return; }
  if (gtid >= P.crwstart) { combine_rel_elem(P, gtid - P.crwstart); return; }
  int si = 0;
  if (gtid >= P.pk[2].start) si = 2;
  else if (gtid >= P.pk[1].start) si = 1;
  const PackSeg s = P.pk[si];
  int slot = gtid - s.start;
  int spm = s.Ktiles << 9;
  int tm = slot / spm, r2 = slot - tm * spm;
  int tk = r2 >> 9, o = r2 & 511;
  int row = o >> 2, sw = o & 3;
  int chunk = sw ^ ((row >> 1) & 3);
  int grow = tm * 128 + row;
  int gk = tk * 32 + chunk * 8;
  ushort tmp[8];
  if (grow < s.M && gk + 8 <= s.K) {
    const float* p = s.X + (size_t)grow * s.K + gk;
    float4 a = *(const float4*)p, b = *(const float4*)(p + 4);
    tmp[0] = f2b(a.x); tmp[1] = f2b(a.y); tmp[2] = f2b(a.z); tmp[3] = f2b(a.w);
    tmp[4] = f2b(b.x); tmp[5] = f2b(b.y); tmp[6] = f2b(b.z); tmp[7] = f2b(b.w);
  } else {
#pragma unroll
    for (int j = 0; j < 8; ++j) {
      int kk = gk + j;
      tmp[j] = (grow < s.M && kk < s.K) ? f2b(s.X[(size_t)grow * s.K + kk]) : (ushort)0;
    }
  }
  *(short8*)&s.out[(size_t)slot * 8] = *(short8*)tmp;
}

// ================= CSR build: two-level counting sort =======================
__global__ __launch_bounds__(256)
void bucket_scan(uint* __restrict__ hist, uint* __restrict__ bucketTot, int NBH)
{
  __shared__ uint ws[4];
  __shared__ uint carry_s;
  int b = blockIdx.x;
  int t = threadIdx.x, lane = t & 63, w = t >> 6;
  if (t == 0) carry_s = 0;
  __syncthreads();
  for (int base = 0; base < NBH; base += 256) {
    int i = base + t;
    uint x = (i < NBH) ? hist[(size_t)b * NBH + i] : 0u;
    uint v = x;
#pragma unroll
    for (int o = 1; o < 64; o <<= 1) {
      uint y = __shfl_up(v, o, 64);
      if (lane >= o) v += y;
    }
    if (lane == 63) ws[w] = v;
    __syncthreads();
    uint add = carry_s;
    for (int k = 0; k < w; ++k) add += ws[k];
    if (i < NBH) hist[(size_t)b * NBH + i] = add + v - x;
    __syncthreads();
    if (t == 255) carry_s = add + v;
    __syncthreads();
  }
  if (t == 0) bucketTot[b] = carry_s;
}

// local exclusive scan of bucketTot (<=512 entries) into sb[]; 2 slots/thread
__device__ __forceinline__ void base_scan(const uint* __restrict__ bucketTot,
                                          uint* sb, uint* ws, int NBK)
{
  int t = threadIdx.x, lane = t & 63, w = t >> 6;
  sb[t] = (t < NBK) ? bucketTot[t] : 0u;
  sb[t + 256] = (t + 256 < NBK) ? bucketTot[t + 256] : 0u;
  __syncthreads();
  uint a0 = sb[2 * t], a1 = sb[2 * t + 1];
  uint s = a0 + a1;
  uint v = s;
#pragma unroll
  for (int o = 1; o < 64; o <<= 1) {
    uint y = __shfl_up(v, o, 64);
    if (lane >= o) v += y;
  }
  if (lane == 63) ws[w] = v;
  __syncthreads();
  uint add = 0;
  for (int k = 0; k < w; ++k) add += ws[k];
  uint e0 = add + v - s;
  sb[2 * t] = e0;
  sb[2 * t + 1] = e0 + a0;
  __syncthreads();
}

// Pass C: scatter (payload, dst) into bucket-contiguous intermediate
__global__ __launch_bounds__(256)
void bucket_scatter(EdgeStreams es, const uint* __restrict__ hist,
                    const uint* __restrict__ bucketTot,
                    uint2* __restrict__ inter, int NBs, int NBH, int NBK, int E)
{
  __shared__ uint sb[516];
  __shared__ uint ws[4];
  __shared__ uint cur[512];
  base_scan(bucketTot, sb, ws, NBK);
  int b = blockIdx.x;
  int et = b / NBs;
  int i0 = (b - et * NBs) * CSR_CH;
  const int* dp = es.dst[et];
  const int* sp = es.src[et];
  int off = es.off[et];
  uint rel = es.rel[et], ldb = es.ldb[et];
  for (int t = threadIdx.x; t < NBK; t += 256)
    cur[t] = sb[t] + hist[(size_t)t * NBH + b];
  __syncthreads();
#pragma unroll
  for (int j = 0; j < CSR_CH / 256; ++j) {
    int idx = i0 + j * 256 + threadIdx.x;
    if (idx < E) {
      int g = off + dp[idx];
      uint pos = atomicAdd(&cur[(uint)g >> CSR_SH], 1u);
      inter[pos] = make_uint2(rel + (uint)sp[idx] * ldb, (uint)g);
    }
  }
}

// Pass D: one block per bucket; per-node count+scan in LDS, write starts and
// final payload into this block's contiguous region (single-writer lines).
__global__ __launch_bounds__(256)
void bucket_finalize(const uint2* __restrict__ inter,
                     const uint* __restrict__ bucketTot,
                     int* __restrict__ starts, uint* __restrict__ payload,
                     int Ntot, int NBK)
{
  __shared__ uint sb[516];
  __shared__ uint ncnt[512];
  __shared__ uint ws[4];
  base_scan(bucketTot, sb, ws, NBK);
  int b = blockIdx.x;
  int g0 = b << CSR_SH;
  int t = threadIdx.x, lane = t & 63, w = t >> 6;
  uint r0 = sb[b], r1 = sb[b + 1];
  if (b == NBK - 1 && t == 0) starts[Ntot] = (int)r1;
  ncnt[t] = 0; ncnt[t + 256] = 0;
  __syncthreads();
  for (uint i = r0 + t; i < r1; i += 256)
    atomicAdd(&ncnt[inter[i].y - g0], 1u);
  __syncthreads();
  uint a0 = ncnt[2 * t], a1 = ncnt[2 * t + 1];
  uint s = a0 + a1;
  uint v = s;
#pragma unroll
  for (int o = 1; o < 64; o <<= 1) {
    uint y = __shfl_up(v, o, 64);
    if (lane >= o) v += y;
  }
  if (lane == 63) ws[w] = v;
  __syncthreads();
  uint add = r0;
  for (int k = 0; k < w; ++k) add += ws[k];
  uint e0 = add + v - s;
  int gi = g0 + 2 * t;
  if (gi < Ntot)     starts[gi]     = (int)e0;
  if (gi + 1 < Ntot) starts[gi + 1] = (int)(e0 + a0);
  ncnt[2 * t] = e0;          // reuse as cursors
  ncnt[2 * t + 1] = e0 + a0;
  __syncthreads();
  for (uint i = r0 + t; i < r1; i += 256) {
    uint2 rec = inter[i];
    uint pos = atomicAdd(&ncnt[rec.y - g0], 1u);
    payload[pos] = rec.x;
  }
}

// ================= fused multi-segment MFMA GEMM (two-stage) ===============
// epi: 0 bf16 row-major unguarded; 1 fp32 guarded; 2 skip-relu fp32 guarded;
//      3 skip-relu bf16 packed; 4 plain bf16 packed (+Xs stash if n2>0);
//      5 skip-relu -> Xs ONLY (no global write; feeds stage 2)
// Stage 2 (n2>0): Xs (128x128 bf16, packed-A layout in LDS) @ B2[t2] + bias2,
// written to out2 (epi2: 0 bf16 row-major unguarded / 1 fp32 guarded).
struct GemmSeg {
  const ushort* A; const ushort* B; const float* bias;
  void* out; const ushort* xsP;
  int Ktiles, ldo, Mreal, skip_idx, epi, NT, start;
  int n2; const ushort* B2; const float* bias2;
  void* out2; int ldo2, Mreal2, epi2;
};
struct Gemm3 { GemmSeg s[3]; const float* skip; int nseg; };

__launch_bounds__(256)
__global__ void gemm_sched(Gemm3 g3)
{
  __shared__ __align__(16) ushort As[2][4096];
  __shared__ __align__(16) ushort Bs[2][4096];
  __shared__ __align__(16) ushort Xs[16384];
  int bid = blockIdx.x;
  int si = 0;
  if (g3.nseg > 1 && bid >= g3.s[1].start)
    si = (g3.nseg > 2 && bid >= g3.s[2].start) ? 2 : 1;
  const GemmSeg sg = g3.s[si];
  int local = bid - sg.start;
  int tm = local / sg.NT, tn = local - tm * sg.NT;

  const int t = threadIdx.x;
  const int wave = t >> 6, lane = t & 63;
  const int wm = (wave >> 1) * 64, wn = (wave & 1) * 64;
  const int l16 = lane & 15, quad = lane >> 4;
  const int Ktiles = sg.Ktiles;
  const int swz = (quad ^ ((l16 >> 1) & 3)) * 8;

  const ushort* Abase = sg.A + (size_t)tm * Ktiles * 4096;
  const ushort* Bbase = sg.B + (size_t)tn * Ktiles * 4096;

  floatx4 acc[4][4];
#pragma unroll
  for (int i = 0; i < 4; ++i)
#pragma unroll
    for (int j = 0; j < 4; ++j) acc[i][j] = (floatx4){0.f, 0.f, 0.f, 0.f};

  auto stage = [&](int tk, int buf) {
#pragma unroll
    for (int j = 0; j < 4; ++j) {
      int c = wave * 4 + j;
      if (c < 8)
        gll16(Abase + (size_t)tk * 4096 + c * 512 + lane * 8, &As[buf][c * 512]);
      else
        gll16(Bbase + (size_t)tk * 4096 + (c - 8) * 512 + lane * 8, &Bs[buf][(c - 8) * 512]);
    }
  };

  stage(0, 0);
  __syncthreads();

  for (int tk = 0; tk < Ktiles; ++tk) {
    int buf = tk & 1;
    if (tk + 1 < Ktiles) stage(tk + 1, buf ^ 1);

    short8 af[4], bfr[4];
#pragma unroll
    for (int i = 0; i < 4; ++i) {
      af[i]  = *(const short8*)&As[buf][(wm + i * 16 + l16) * 32 + swz];
      bfr[i] = *(const short8*)&Bs[buf][(wn + i * 16 + l16) * 32 + swz];
    }
#pragma unroll
    for (int mi = 0; mi < 4; ++mi)
#pragma unroll
      for (int ni = 0; ni < 4; ++ni)
        acc[mi][ni] = __builtin_amdgcn_mfma_f32_16x16x32_bf16(
            af[mi], bfr[ni], acc[mi][ni], 0, 0, 0);
    __syncthreads();
  }

  const int epi = sg.epi;
  float g = 0.f, omg = 0.f;
  if (epi == 2 || epi == 3 || epi == 5) {
    float s = g3.skip[sg.skip_idx];
    g = 1.f / (1.f + __expf(-s));
    omg = 1.f - g;
  }
#pragma unroll
  for (int ni = 0; ni < 4; ++ni) {
    int col = tn * 128 + wn + ni * 16 + l16;
    float bb = sg.bias[col];
    int ptk = col >> 5, kin = col & 31;
#pragma unroll
    for (int mi = 0; mi < 4; ++mi) {
      int rloc = wm + mi * 16 + quad * 4;
#pragma unroll
      for (int r = 0; r < 4; ++r) {
        int prow = rloc + r;
        int rr = tm * 128 + prow;
        float v = acc[mi][ni][r] + bb;
        if (epi == 0) {
          ((ushort*)sg.out)[(size_t)rr * sg.ldo + col] = f2b(v);
        } else if (epi == 1) {
          if (rr < sg.Mreal) ((float*)sg.out)[(size_t)rr * sg.ldo + col] = v;
        } else if (epi == 2) {
          if (rr < sg.Mreal) {
            float xo = b2f(sg.xsP[a_packed_us(rr, col)]);
            ((float*)sg.out)[(size_t)rr * sg.ldo + col] = fmaxf(g * v + omg * xo, 0.f);
          }
        } else if (epi == 3) {
          float xo = b2f(sg.xsP[a_packed_us(rr, col)]);
          ((ushort*)sg.out)[a_packed_us(rr, col)] = f2b(fmaxf(g * v + omg * xo, 0.f));
        } else if (epi == 4) {
          ushort bv = f2b(v);
          ((ushort*)sg.out)[a_packed_us(rr, col)] = bv;
          int sw2 = (kin >> 3) ^ ((prow >> 1) & 3);
          Xs[ptk * 4096 + prow * 32 + sw2 * 8 + (kin & 7)] = bv;
        } else {  // 5: skip-relu into Xs only
          float xo = b2f(sg.xsP[a_packed_us(rr, col)]);
          int sw2 = (kin >> 3) ^ ((prow >> 1) & 3);
          Xs[ptk * 4096 + prow * 32 + sw2 * 8 + (kin & 7)] =
              f2b(fmaxf(g * v + omg * xo, 0.f));
        }
      }
    }
  }

  // ---------------- stage 2: Xs @ B2[t2] ----------------
  if (sg.n2 == 0) return;
  __syncthreads();
  for (int t2 = 0; t2 < sg.n2; ++t2) {
    const ushort* B2b = sg.B2 + (size_t)t2 * 16384;
    auto stage2 = [&](int tk, int buf) {
#pragma unroll
      for (int j = 0; j < 2; ++j) {
        int c = wave * 2 + j;
        gll16(B2b + (size_t)tk * 4096 + c * 512 + lane * 8, &Bs[buf][c * 512]);
      }
    };
    floatx4 a2[4][4];
#pragma unroll
    for (int i = 0; i < 4; ++i)
#pragma unroll
      for (int j = 0; j < 4; ++j) a2[i][j] = (floatx4){0.f, 0.f, 0.f, 0.f};
    stage2(0, 0);
    __syncthreads();
#pragma unroll
    for (int tk = 0; tk < 4; ++tk) {
      int buf = tk & 1;
      if (tk + 1 < 4) stage2(tk + 1, buf ^ 1);
      short8 af[4], bfr[4];
#pragma unroll
      for (int i = 0; i < 4; ++i) {
        af[i]  = *(const short8*)&Xs[tk * 4096 + (wm + i * 16 + l16) * 32 + swz];
        bfr[i] = *(const short8*)&Bs[buf][(wn + i * 16 + l16) * 32 + swz];
      }
#pragma unroll
      for (int mi = 0; mi < 4; ++mi)
#pragma unroll
        for (int ni = 0; ni < 4; ++ni)
          a2[mi][ni] = __builtin_amdgcn_mfma_f32_16x16x32_bf16(
              af[mi], bfr[ni], a2[mi][ni], 0, 0, 0);
      __syncthreads();
    }
#pragma unroll
    for (int ni = 0; ni < 4; ++ni) {
      int col = t2 * 128 + wn + ni * 16 + l16;
      float bb = sg.bias2[col];
#pragma unroll
      for (int mi = 0; mi < 4; ++mi) {
        int rloc = wm + mi * 16 + quad * 4;
#pragma unroll
        for (int r = 0; r < 4; ++r) {
          int rr = tm * 128 + rloc + r;
          float v = a2[mi][ni][r] + bb;
          if (sg.epi2 == 0) {
            ((ushort*)sg.out2)[(size_t)rr * sg.ldo2 + col] = f2b(v);
          } else {
            if (rr < sg.Mreal2) ((float*)sg.out2)[(size_t)rr * sg.ldo2 + col] = v;
          }
        }
      }
    }
  }
}

// ================= gather: one wave per dst node, 2x4 edges/iter ==========
// (reverted to the measured-best 8-edge form: VGPR 32, occupancy ~70%)
struct GatherType { const ushort* q; ushort* agg; int ldq; };
struct GatherDesc { GatherType ty[3]; int n0, n1; };

__launch_bounds__(256)
__global__ void gather_all(const int* __restrict__ starts,
                           const uint* __restrict__ payload,
                           const ushort* __restrict__ kvbase,
                           GatherDesc gd, int Ntot)
{
  int wid = (blockIdx.x * 256 + threadIdx.x) >> 6;
  if (wid >= Ntot) return;
  int lane = threadIdx.x & 63;
  int g = lane >> 4, l = lane & 15;

  GatherType T;
  int d;
  if (wid < gd.n0)      { T = gd.ty[0]; d = wid; }
  else if (wid < gd.n1) { T = gd.ty[1]; d = wid - gd.n0; }
  else                  { T = gd.ty[2]; d = wid - gd.n1; }

  const char* kvb = (const char*)kvbase;
  const uint lofs = (uint)l * 16u;

  uint4 qv = *(const uint4*)(T.q + (size_t)d * T.ldq + l * 8);
  f32x2 q0 = b2x2(qv.x), q1 = b2x2(qv.y), q2 = b2x2(qv.z), q3 = b2x2(qv.w);

  int e0 = starts[wid], e1 = starts[wid + 1];
  float lsum = 0.f;
  f32x2 ac0 = {0.f, 0.f}, ac1 = {0.f, 0.f}, ac2 = {0.f, 0.f}, ac3 = {0.f, 0.f};

  for (int eb = e0; eb < e1; eb += 8) {
    int eA = eb + g, eB = eA + 4;
    bool actA = eA < e1, actB = eB < e1;
    uint pA = payload[actA ? eA : e0];
    uint pB = payload[actB ? eB : e0];
    const char* bA = kvb + (pA + lofs);
    const char* bB = kvb + (pB + lofs);
    uint4 kA = *(const uint4*)bA;
    uint4 vA = *(const uint4*)(bA + 256);
    uint4 kB = *(const uint4*)bB;
    uint4 vB = *(const uint4*)(bB + 256);

    f32x2 dA = q0 * b2x2(kA.x);
    dA = __builtin_elementwise_fma(q1, b2x2(kA.y), dA);
    dA = __builtin_elementwise_fma(q2, b2x2(kA.z), dA);
    dA = __builtin_elementwise_fma(q3, b2x2(kA.w), dA);
    f32x2 dB = q0 * b2x2(kB.x);
    dB = __builtin_elementwise_fma(q1, b2x2(kB.y), dB);
    dB = __builtin_elementwise_fma(q2, b2x2(kB.z), dB);
    dB = __builtin_elementwise_fma(q3, b2x2(kB.w), dB);
    float pa = dA.x + dA.y;
    float pb = dB.x + dB.y;
    pa += __shfl_xor(pa, 1, 64);
    pb += __shfl_xor(pb, 1, 64);
    float exA = exp2f(fminf(pa, 115.4f));
    float exB = exp2f(fminf(pb, 115.4f));
    exA = actA ? exA : 0.f;
    exB = actB ? exB : 0.f;
    lsum += exA + exB;
    f32x2 xA = {exA, exA}, xB = {exB, exB};
    ac0 = __builtin_elementwise_fma(xA, b2x2(vA.x), ac0);
    ac1 = __builtin_elementwise_fma(xA, b2x2(vA.y), ac1);
    ac2 = __builtin_elementwise_fma(xA, b2x2(vA.z), ac2);
    ac3 = __builtin_elementwise_fma(xA, b2x2(vA.w), ac3);
    ac0 = __builtin_elementwise_fma(xB, b2x2(vB.x), ac0);
    ac1 = __builtin_elementwise_fma(xB, b2x2(vB.y), ac1);
    ac2 = __builtin_elementwise_fma(xB, b2x2(vB.z), ac2);
    ac3 = __builtin_elementwise_fma(xB, b2x2(vB.w), ac3);
  }

  float s0 = ac0.x, s1 = ac0.y, s2 = ac1.x, s3 = ac1.y;
  float s4 = ac2.x, s5 = ac2.y, s6 = ac3.x, s7 = ac3.y;
#define MRG(v) v += __shfl_xor(v, 16, 64); v += __shfl_xor(v, 32, 64)
  MRG(lsum); MRG(s0); MRG(s1); MRG(s2); MRG(s3); MRG(s4); MRG(s5); MRG(s6); MRG(s7);
#undef MRG

  // each lane finishes channels c0 = 8*l + 2*g and c0+1
  float inv = 1.f / (lsum + 1e-16f);
  float m0 = (g & 1) ? s2 : s0, m1 = (g & 1) ? s6 : s4;
  float n0 = (g & 1) ? s3 : s1, n1 = (g & 1) ? s7 : s5;
  float x0 = ((g & 2) ? m1 : m0) * inv;
  float x1 = ((g & 2) ? n1 : n0) * inv;
  float g0 = 0.5f * x0 * (1.f + erff(x0 * 0.70710678118654752f));
  float g1 = 0.5f * x1 * (1.f + erff(x1 * 0.70710678118654752f));
  int tm = d >> 7, row = d & 127;
  int tk = l >> 2, sw = (l & 3) ^ ((row >> 1) & 3);
  size_t us = (((size_t)tm * 4 + tk) * 512 + (size_t)row * 4 + sw) * 8 + 2 * g;
  *(uint*)(T.agg + us) = ((uint)f2b(g1) << 16) | (uint)f2b(g0);
}

// ================= host =====================================================
extern "C" void kernel_launch(void* const* d_in, const int* in_sizes, int n_in,
                              void* d_out, int out_size, void* d_ws, size_t ws_size,
                              hipStream_t stream)
{
  const float* x_herb = (const float*)d_in[0];
  const float* x_ing  = (const float*)d_in[1];
  const float* x_tgt  = (const float*)d_in[2];
  const float* W_herb = (const float*)d_in[3];
  const float* b_herb = (const float*)d_in[4];
  const float* W_ing  = (const float*)d_in[5];
  const float* b_ing  = (const float*)d_in[6];
  const float* W_tgt  = (const float*)d_in[7];
  const float* b_tgt  = (const float*)d_in[8];
  const float* Wk     = (const float*)d_in[9];
  const float* bk     = (const float*)d_in[10];
  const float* Wq     = (const float*)d_in[11];
  const float* bq     = (const float*)d_in[12];
  const float* Wv     = (const float*)d_in[13];
  const float* bv     = (const float*)d_in[14];
  const float* a_rel  = (const float*)d_in[15];
  const float* m_rel  = (const float*)d_in[16];
  const float* p_rel  = (const float*)d_in[17];
  const float* Wa     = (const float*)d_in[18];
  const float* ba     = (const float*)d_in[19];
  const float* skip   = (const float*)d_in[20];
  const float* W_out  = (const float*)d_in[21];
  const float* b_out  = (const float*)d_in[22];
  const int* srcs[4] = {(const int*)d_in[23], (const int*)d_in[25],
                        (const int*)d_in[27], (const int*)d_in[29]};
  const int* dsts[4] = {(const int*)d_in[24], (const int*)d_in[26],
                        (const int*)d_in[28], (const int*)d_in[30]};

  const int Nh = in_sizes[0] / 400;
  const int Ni = in_sizes[1] / 300;
  const int Nt = in_sizes[2] / 200;
  const int E  = in_sizes[23];
  const int Ntot = Nh + Ni + Nt;

  const int MT_h = (Nh + 127) / 128, MT_i = (Ni + 127) / 128, MT_t = (Nt + 127) / 128;
  const int KT_h = 13, KT_i = 10, KT_t = 7;   // Kpad 416/320/224

  // CSR sort params
  const int NBs = (E + CSR_CH - 1) / CSR_CH;
  const int NBH = 4 * NBs;
  const int NBK = (Ntot + (1 << CSR_SH) - 1) >> CSR_SH;   // <= 511

  char* base = (char*)d_ws;
  size_t off = 0;
  auto A = [&](size_t bytes) -> void* {
    void* p = base + off; off += (bytes + 255) & ~(size_t)255; return p;
  };
  ushort* xp_h  = (ushort*)A((size_t)MT_h * KT_h * 8192);
  ushort* xp_i  = (ushort*)A((size_t)MT_i * KT_i * 8192);
  ushort* xp_t  = (ushort*)A((size_t)MT_t * KT_t * 8192);
  ushort* xsP_h = (ushort*)A((size_t)MT_h * 4 * 8192);
  ushort* xsP_i = (ushort*)A((size_t)MT_i * 4 * 8192);
  ushort* xsP_t = (ushort*)A((size_t)MT_t * 4 * 8192);
  ushort* fused_h = (ushort*)A((size_t)MT_h * 128 * 384 * 2);  // [q|k0|v0]
  ushort* fused_i = (ushort*)A((size_t)MT_i * 128 * 640 * 2);  // [q|k1|v1|k2|v2]
  ushort* fused_t = (ushort*)A((size_t)MT_t * 128 * 384 * 2);  // [q|k3|v3]
  ushort* aggp_h  = (ushort*)A((size_t)MT_h * 4 * 8192);
  ushort* aggp_i  = (ushort*)A((size_t)MT_i * 4 * 8192);
  ushort* aggp_t  = (ushort*)A((size_t)MT_t * 4 * 8192);
  ushort* Weff1_h = (ushort*)A((size_t)KT_h * 8192);
  ushort* Weff1_i = (ushort*)A((size_t)KT_i * 8192);
  ushort* Weff1_t = (ushort*)A((size_t)KT_t * 8192);
  ushort* Wcat_h = (ushort*)A((size_t)3 * 4 * 8192);
  ushort* Wcat_i = (ushort*)A((size_t)5 * 4 * 8192);
  ushort* Wcat_t = (ushort*)A((size_t)3 * 4 * 8192);
  float* bcat   = (float*)A(1408 * 4);
  ushort* Wa_t   = (ushort*)A((size_t)3 * 16384 * 2);
  ushort* Wout_t = (ushort*)A((size_t)16384 * 2);
  int* starts  = (int*)A((size_t)(Ntot + 4) * 4);
  uint* payload = (uint*)A((size_t)(4 * E + 8) * 4);
  uint* hist    = (uint*)A((size_t)NBK * NBH * 4);
  uint* bucketTot  = (uint*)A((size_t)NBK * 4);
  uint2* inter  = (uint2*)A((size_t)(4 * E + 8) * 8);
  (void)ws_size; (void)n_in;

  const int toff_h = 0, toff_i = Nh, toff_t = Nh + Ni;
  dim3 blk(256);

  uint fi2 = (uint)((size_t)(fused_i - fused_h) * 2);
  uint ft2 = (uint)((size_t)(fused_t - fused_h) * 2);

  // --- 1: prologue (pack x3 + combine_rel + all weight prep + edge hist) ---
  int sl_h = MT_h * KT_h * 512, sl_i = MT_i * KT_i * 512, sl_t = MT_t * KT_t * 512;
  Prolog P;
  P.pk[0] = {x_herb, xp_h, Nh, 400, KT_h, 0};
  P.pk[1] = {x_ing,  xp_i, Ni, 300, KT_i, sl_h};
  P.pk[2] = {x_tgt,  xp_t, Nt, 200, KT_t, sl_h + sl_i};
  P.crwstart = sl_h + sl_i + sl_t;
  P.wstart = P.crwstart + 4 * 2 * 129 * 128;
  {
    const float* wsrc10[10] = {W_herb, W_ing, W_tgt, Wq, Wq + 16384, Wq + 32768,
                               Wa, Wa + 16384, Wa + 32768, W_out};
    ushort* wdst10[10] = {Weff1_h, Weff1_i, Weff1_t, Wcat_h, Wcat_i, Wcat_t,
                          Wa_t, Wa_t + 16384, Wa_t + 32768, Wout_t};
    int wk10[10] = {400, 300, 200, 128, 128, 128, 128, 128, 128, 128};
    int wcum = 0;
    for (int z = 0; z < 10; ++z) {
      P.wb[z] = {wsrc10[z], wdst10[z], wk10[z], wcum};
      wcum += ((wk10[z] + 31) / 32) * 512;
    }
    P.bstart = P.wstart + wcum;
  }
  P.total = P.bstart + 384;
  P.Wk = Wk; P.bk = bk; P.Wv = Wv; P.bv = bv;
  P.a_rel = a_rel; P.m_rel = m_rel; P.p_rel = p_rel;
  P.kw_dst[0] = Wcat_h + 16384; P.vw_dst[0] = Wcat_h + 32768;
  P.kw_dst[1] = Wcat_i + 16384; P.vw_dst[1] = Wcat_i + 32768;
  P.kw_dst[2] = Wcat_i + 49152; P.vw_dst[2] = Wcat_i + 65536;
  P.kw_dst[3] = Wcat_t + 16384; P.vw_dst[3] = Wcat_t + 32768;
  P.bcat = bcat;
  P.kb_off[0] = 128;  P.vb_off[0] = 256;
  P.kb_off[1] = 512;  P.vb_off[1] = 640;
  P.kb_off[2] = 768;  P.vb_off[2] = 896;
  P.kb_off[3] = 1152; P.vb_off[3] = 1280;
  P.bq = bq;
  P.bq_off[0] = 0; P.bq_off[1] = 384; P.bq_off[2] = 1024;
  P.edst[0] = dsts[0]; P.eoff[0] = toff_i;
  P.edst[1] = dsts[1]; P.eoff[1] = toff_h;
  P.edst[2] = dsts[2]; P.eoff[2] = toff_t;
  P.edst[3] = dsts[3]; P.eoff[3] = toff_i;
  P.hist = hist; P.NBs = NBs; P.NBH = NBH; P.NBK = NBK; P.E = E;
  prologue<<<NBH + (P.total + 255) / 256, blk, 0, stream>>>(P);

  // --- 2: CSR build (scan -> scatter -> finalize) ---
  EdgeStreams ES;
  ES.src[0] = srcs[0]; ES.dst[0] = dsts[0]; ES.off[0] = toff_i;
  ES.rel[0] = 256u;        ES.ldb[0] = 768u;
  ES.src[1] = srcs[1]; ES.dst[1] = dsts[1]; ES.off[1] = toff_h;
  ES.rel[1] = fi2 + 256u;  ES.ldb[1] = 1280u;
  ES.src[2] = srcs[2]; ES.dst[2] = dsts[2]; ES.off[2] = toff_t;
  ES.rel[2] = fi2 + 768u;  ES.ldb[2] = 1280u;
  ES.src[3] = srcs[3]; ES.dst[3] = dsts[3]; ES.off[3] = toff_i;
  ES.rel[3] = ft2 + 256u;  ES.ldb[3] = 768u;
  bucket_scan<<<NBK, blk, 0, stream>>>(hist, bucketTot, NBH);
  bucket_scatter<<<NBH, blk, 0, stream>>>(ES, hist, bucketTot, inter, NBs, NBH, NBK, E);
  bucket_finalize<<<NBK, blk, 0, stream>>>(inter, bucketTot, starts, payload, Ntot, NBK);

  // --- 3: K1 = GEMM1 + GEMM2 fused (xs kept in LDS, 3-5 col-tiles of qkv) ---
  Gemm3 G1;
  G1.skip = skip; G1.nseg = 3;
  G1.s[0] = {xp_h, Weff1_h, b_herb, xsP_h, nullptr, KT_h, 0, 0, 0, 4, 1, 0,
             3, Wcat_h, bcat + 0, fused_h, 384, 0, 0};
  G1.s[1] = {xp_i, Weff1_i, b_ing,  xsP_i, nullptr, KT_i, 0, 0, 0, 4, 1, MT_h,
             5, Wcat_i, bcat + 384, fused_i, 640, 0, 0};
  G1.s[2] = {xp_t, Weff1_t, b_tgt,  xsP_t, nullptr, KT_t, 0, 0, 0, 4, 1, MT_h + MT_i,
             3, Wcat_t, bcat + 1024, fused_t, 384, 0, 0};
  gemm_sched<<<MT_h + MT_i + MT_t, blk, 0, stream>>>(G1);

  // --- 4: gather attention (all types, one wave per node) ---
  GatherDesc GD;
  GD.n0 = Nh; GD.n1 = Nh + Ni;
  GD.ty[0] = {fused_h, aggp_h, 384};
  GD.ty[1] = {fused_i, aggp_i, 640};
  GD.ty[2] = {fused_t, aggp_t, 384};
  gather_all<<<(Ntot + 3) / 4, blk, 0, stream>>>(starts, payload, fused_h, GD, Ntot);

  // --- 5: K2 = epilogue GEMMs; herb chains W_out stage from LDS (GF fused) ---
  float* outp = (float*)d_out;
  float* out_herb = outp;
  float* out_ing  = outp + (size_t)Nh * HID;
  float* out_tgt  = outp + (size_t)(Nh + Ni) * HID;
  Gemm3 GE;
  GE.skip = skip; GE.nseg = 3;
  GE.s[0] = {aggp_h, Wa_t + 0 * 16384, ba + 0 * 128, nullptr, xsP_h,
             4, 0, 0, 0, 5, 1, 0,
             1, Wout_t, b_out, out_herb, 128, Nh, 1};
  GE.s[1] = {aggp_i, Wa_t + 1 * 16384, ba + 1 * 128, out_ing, xsP_i,
             4, 128, Ni, 1, 2, 1, MT_h,
             0, nullptr, nullptr, nullptr, 0, 0, 0};
  GE.s[2] = {aggp_t, Wa_t + 2 * 16384, ba + 2 * 128, out_tgt, xsP_t,
             4, 128, Nt, 2, 2, 1, MT_h + MT_i,
             0, nullptr, nullptr, nullptr, 0, 0, 0};
  gemm_sched<<<MT_h + MT_i + MT_t, blk, 0, stream>>>(GE);
  (void)out_size;
}

// Round 5
// 399.060 us; speedup vs baseline: 1.1545x; 1.0943x over previous
//
#include <hip/hip_runtime.h>
#include <math.h>

#define HID 128
typedef unsigned int uint;
typedef unsigned short ushort;
typedef __attribute__((ext_vector_type(8))) short short8;
typedef __attribute__((ext_vector_type(4))) float floatx4;
typedef __attribute__((ext_vector_type(2))) float f32x2;

// ---------- bf16 helpers ----------
__device__ __forceinline__ ushort f2b(float f) {
  uint u = __float_as_uint(f);
  u += 0x7fffu + ((u >> 16) & 1u);
  return (ushort)(u >> 16);
}
__device__ __forceinline__ float b2f(ushort s) {
  return __uint_as_float(((uint)s) << 16);
}
__device__ __forceinline__ float blo(uint u) { return __uint_as_float(u << 16); }
__device__ __forceinline__ float bhi(uint u) { return __uint_as_float(u & 0xffff0000u); }
__device__ __forceinline__ f32x2 b2x2(uint u) {
  f32x2 r;
  r.x = __uint_as_float(u << 16);
  r.y = __uint_as_float(u & 0xffff0000u);
  return r;
}

__device__ __forceinline__ void gll16(const ushort* g, ushort* l) {
  __builtin_amdgcn_global_load_lds(
      (const __attribute__((address_space(1))) void*)g,
      (__attribute__((address_space(3))) void*)l, 16, 0, 0);
}

// Packed tile layout (128 rows x 32 k, bf16), 16B slot within tile:
//   slot = row*4 + (chunk ^ ((row>>1)&3)), chunk = k/8. Conflict-free staging+frags.
__device__ __forceinline__ size_t a_packed_us(int rr, int col) {
  int tm = rr >> 7, prow = rr & 127;
  int ptk = col >> 5, kin = col & 31;
  int sw = (kin >> 3) ^ ((prow >> 1) & 3);
  return (((size_t)tm * 4 + ptk) * 512 + (size_t)prow * 4 + sw) * 8 + (kin & 7);
}

// ================= CSR params ==============================================
#define CSR_CH 2048   // edges per block in hist/scatter passes
#define CSR_SH 9      // 512 nodes per bucket

struct EdgeStreams {
  const int* src[4]; const int* dst[4];
  int off[4]; uint rel[4]; uint ldb[4];
};

// ================= prologue: pack x + combine_rel + weight prep + hist ======
struct PackSeg { const float* X; ushort* out; int M, K, Ktiles, start; };
struct WBlk { const float* src; ushort* dst; int K; int start; };
struct Prolog {
  PackSeg pk[3];
  int crwstart, wstart, bstart, total;
  const float *Wk, *bk, *Wv, *bv, *a_rel, *m_rel, *p_rel;
  ushort* kw_dst[4];
  ushort* vw_dst[4];
  float* bcat;
  int kb_off[4], vb_off[4];
  WBlk wb[10];
  const float* bq;
  int bq_off[3];
  // edge-hist segment (block-granular, blocks [0, NBH))
  const int* edst[4];
  int eoff[4];
  uint* hist;       // transposed: hist[bucket][block]
  int NBs, NBH, NBK, E;
};

// combine_rel: Wk_rel[e] = Wk[i] @ a_rel[e] (and Wv/m_rel), written DIRECTLY in
// packed-B bf16 layout. p_rel[e,h]/sqrt(D)*log2(e) is baked into the k weights
// and bias so the gather's logit feeds exp2 with no per-edge scale.
__device__ void combine_rel_elem(const Prolog& P, int idx)
{
  int col  = idx & 127;
  int rest = idx >> 7;
  int row  = rest % 129;
  rest /= 129;
  int kv = rest & 1;
  int e  = rest >> 1;
  int i  = (e + 1) >> 1;           // styp = {0,1,1,2}
  int h = col >> 4, j = col & 15;
  const float* Wsrc = kv ? P.Wv : P.Wk;
  const float* bsrc = kv ? P.bv : P.bk;
  const float* rel  = kv ? P.m_rel : P.a_rel;
  float acc = 0.f;
  if (row < 128) {
#pragma unroll
    for (int d = 0; d < 16; ++d)
      acc += Wsrc[(size_t)i * 16384 + (size_t)row * 128 + h * 16 + d] *
             rel[((e * 8 + h) * 16 + d) * 16 + j];
  } else {
#pragma unroll
    for (int d = 0; d < 16; ++d)
      acc += bsrc[i * 128 + h * 16 + d] * rel[((e * 8 + h) * 16 + d) * 16 + j];
  }
  if (!kv) acc *= P.p_rel[e * 8 + h] * 0.36067376022224085f;  // 0.25 * log2(e)
  if (row < 128) {
    ushort* dst = kv ? P.vw_dst[e] : P.kw_dst[e];
    int tk = row >> 5, chunk = (row >> 3) & 3, m = row & 7;
    int swf = chunk ^ ((col >> 1) & 3);
    dst[((tk * 512 + col * 4 + swf) << 3) + m] = f2b(acc);
  } else {
    P.bcat[(kv ? P.vb_off[e] : P.kb_off[e]) + col] = acc;
  }
}

// pure layout conversion of row-major fp32 [K][128] weights to packed-B bf16
__device__ void conv_elem(const Prolog& P, int s0)
{
  int si = 0;
#pragma unroll
  for (int k = 1; k < 10; ++k)
    if (s0 >= P.wb[k].start) si = k;
  WBlk b = P.wb[si];
  int s = s0 - b.start;
  int tk = s >> 9, o = s & 511;
  int c = o >> 2, swf = o & 3;
  int chunk = swf ^ ((c >> 1) & 3);
  int r0 = tk * 32 + chunk * 8;
  ushort tmp[8];
#pragma unroll
  for (int m = 0; m < 8; ++m) {
    int r = r0 + m;
    tmp[m] = (r < b.K) ? f2b(b.src[(size_t)r * 128 + c]) : (ushort)0;
  }
  *(short8*)&b.dst[(size_t)s * 8] = *(short8*)tmp;
}

__global__ __launch_bounds__(256)
void prologue(Prolog P)
{
  __shared__ uint h[512];
  int bI = blockIdx.x;
  if (bI < P.NBH) {
    // --- edge histogram segment (block-granular) ---
    int et = bI / P.NBs;
    int i0 = (bI - et * P.NBs) * CSR_CH;
    const int* dp = P.edst[et];
    int off = P.eoff[et];
    for (int t = threadIdx.x; t < P.NBK; t += 256) h[t] = 0;
    __syncthreads();
#pragma unroll
    for (int j = 0; j < CSR_CH / 256; ++j) {
      int idx = i0 + j * 256 + threadIdx.x;
      if (idx < P.E) atomicAdd(&h[(uint)(off + dp[idx]) >> CSR_SH], 1u);
    }
    __syncthreads();
    for (int t = threadIdx.x; t < P.NBK; t += 256)
      P.hist[(size_t)t * P.NBH + bI] = h[t];
    return;
  }
  int gtid = (bI - P.NBH) * 256 + threadIdx.x;
  if (gtid >= P.total) return;
  if (gtid >= P.bstart) {
    int j = gtid - P.bstart;
    P.bcat[P.bq_off[j >> 7] + (j & 127)] = P.bq[j];
    return;
  }
  if (gtid >= P.wstart) { conv_elem(P, gtid - P.wstart); return; }
  if (gtid >= P.crwstart) { combine_rel_elem(P, gtid - P.crwstart); return; }
  int si = 0;
  if (gtid >= P.pk[2].start) si = 2;
  else if (gtid >= P.pk[1].start) si = 1;
  const PackSeg s = P.pk[si];
  int slot = gtid - s.start;
  int spm = s.Ktiles << 9;
  int tm = slot / spm, r2 = slot - tm * spm;
  int tk = r2 >> 9, o = r2 & 511;
  int row = o >> 2, sw = o & 3;
  int chunk = sw ^ ((row >> 1) & 3);
  int grow = tm * 128 + row;
  int gk = tk * 32 + chunk * 8;
  ushort tmp[8];
  if (grow < s.M && gk + 8 <= s.K) {
    const float* p = s.X + (size_t)grow * s.K + gk;
    float4 a = *(const float4*)p, b = *(const float4*)(p + 4);
    tmp[0] = f2b(a.x); tmp[1] = f2b(a.y); tmp[2] = f2b(a.z); tmp[3] = f2b(a.w);
    tmp[4] = f2b(b.x); tmp[5] = f2b(b.y); tmp[6] = f2b(b.z); tmp[7] = f2b(b.w);
  } else {
#pragma unroll
    for (int j = 0; j < 8; ++j) {
      int kk = gk + j;
      tmp[j] = (grow < s.M && kk < s.K) ? f2b(s.X[(size_t)grow * s.K + kk]) : (ushort)0;
    }
  }
  *(short8*)&s.out[(size_t)slot * 8] = *(short8*)tmp;
}

// ================= CSR build: two-level counting sort =======================
__global__ __launch_bounds__(256)
void bucket_scan(uint* __restrict__ hist, uint* __restrict__ bucketTot, int NBH)
{
  __shared__ uint ws[4];
  __shared__ uint carry_s;
  int b = blockIdx.x;
  int t = threadIdx.x, lane = t & 63, w = t >> 6;
  if (t == 0) carry_s = 0;
  __syncthreads();
  for (int base = 0; base < NBH; base += 256) {
    int i = base + t;
    uint x = (i < NBH) ? hist[(size_t)b * NBH + i] : 0u;
    uint v = x;
#pragma unroll
    for (int o = 1; o < 64; o <<= 1) {
      uint y = __shfl_up(v, o, 64);
      if (lane >= o) v += y;
    }
    if (lane == 63) ws[w] = v;
    __syncthreads();
    uint add = carry_s;
    for (int k = 0; k < w; ++k) add += ws[k];
    if (i < NBH) hist[(size_t)b * NBH + i] = add + v - x;
    __syncthreads();
    if (t == 255) carry_s = add + v;
    __syncthreads();
  }
  if (t == 0) bucketTot[b] = carry_s;
}

// local exclusive scan of bucketTot (<=512 entries) into sb[]; 2 slots/thread
__device__ __forceinline__ void base_scan(const uint* __restrict__ bucketTot,
                                          uint* sb, uint* ws, int NBK)
{
  int t = threadIdx.x, lane = t & 63, w = t >> 6;
  sb[t] = (t < NBK) ? bucketTot[t] : 0u;
  sb[t + 256] = (t + 256 < NBK) ? bucketTot[t + 256] : 0u;
  __syncthreads();
  uint a0 = sb[2 * t], a1 = sb[2 * t + 1];
  uint s = a0 + a1;
  uint v = s;
#pragma unroll
  for (int o = 1; o < 64; o <<= 1) {
    uint y = __shfl_up(v, o, 64);
    if (lane >= o) v += y;
  }
  if (lane == 63) ws[w] = v;
  __syncthreads();
  uint add = 0;
  for (int k = 0; k < w; ++k) add += ws[k];
  uint e0 = add + v - s;
  sb[2 * t] = e0;
  sb[2 * t + 1] = e0 + a0;
  __syncthreads();
}

// Pass C: scatter (payload, dst) into bucket-contiguous intermediate
__global__ __launch_bounds__(256)
void bucket_scatter(EdgeStreams es, const uint* __restrict__ hist,
                    const uint* __restrict__ bucketTot,
                    uint2* __restrict__ inter, int NBs, int NBH, int NBK, int E)
{
  __shared__ uint sb[516];
  __shared__ uint ws[4];
  __shared__ uint cur[512];
  base_scan(bucketTot, sb, ws, NBK);
  int b = blockIdx.x;
  int et = b / NBs;
  int i0 = (b - et * NBs) * CSR_CH;
  const int* dp = es.dst[et];
  const int* sp = es.src[et];
  int off = es.off[et];
  uint rel = es.rel[et], ldb = es.ldb[et];
  for (int t = threadIdx.x; t < NBK; t += 256)
    cur[t] = sb[t] + hist[(size_t)t * NBH + b];
  __syncthreads();
#pragma unroll
  for (int j = 0; j < CSR_CH / 256; ++j) {
    int idx = i0 + j * 256 + threadIdx.x;
    if (idx < E) {
      int g = off + dp[idx];
      uint pos = atomicAdd(&cur[(uint)g >> CSR_SH], 1u);
      inter[pos] = make_uint2(rel + (uint)sp[idx] * ldb, (uint)g);
    }
  }
}

// Pass D: one block per bucket; per-node count+scan in LDS, write starts and
// final payload into this block's contiguous region (single-writer lines).
__global__ __launch_bounds__(256)
void bucket_finalize(const uint2* __restrict__ inter,
                     const uint* __restrict__ bucketTot,
                     int* __restrict__ starts, uint* __restrict__ payload,
                     int Ntot, int NBK)
{
  __shared__ uint sb[516];
  __shared__ uint ncnt[512];
  __shared__ uint ws[4];
  base_scan(bucketTot, sb, ws, NBK);
  int b = blockIdx.x;
  int g0 = b << CSR_SH;
  int t = threadIdx.x, lane = t & 63, w = t >> 6;
  uint r0 = sb[b], r1 = sb[b + 1];
  if (b == NBK - 1 && t == 0) starts[Ntot] = (int)r1;
  ncnt[t] = 0; ncnt[t + 256] = 0;
  __syncthreads();
  for (uint i = r0 + t; i < r1; i += 256)
    atomicAdd(&ncnt[inter[i].y - g0], 1u);
  __syncthreads();
  uint a0 = ncnt[2 * t], a1 = ncnt[2 * t + 1];
  uint s = a0 + a1;
  uint v = s;
#pragma unroll
  for (int o = 1; o < 64; o <<= 1) {
    uint y = __shfl_up(v, o, 64);
    if (lane >= o) v += y;
  }
  if (lane == 63) ws[w] = v;
  __syncthreads();
  uint add = r0;
  for (int k = 0; k < w; ++k) add += ws[k];
  uint e0 = add + v - s;
  int gi = g0 + 2 * t;
  if (gi < Ntot)     starts[gi]     = (int)e0;
  if (gi + 1 < Ntot) starts[gi + 1] = (int)(e0 + a0);
  ncnt[2 * t] = e0;          // reuse as cursors
  ncnt[2 * t + 1] = e0 + a0;
  __syncthreads();
  for (uint i = r0 + t; i < r1; i += 256) {
    uint2 rec = inter[i];
    uint pos = atomicAdd(&ncnt[rec.y - g0], 1u);
    payload[pos] = rec.x;
  }
}

// ================= fused multi-segment MFMA GEMM (two-stage) ===============
// TRANSPOSED mfma (mfma(bfr, af)): lane's 4 acc regs = 4 consecutive output
// COLUMNS -> all epilogue stores are uint2 (bf16) / float4 (fp32).
// epi: 0 bf16 row-major unguarded; 1 fp32 guarded; 2 skip-relu fp32 guarded;
//      3 skip-relu bf16 packed; 4 plain bf16 packed (+Xs stash if n2>0);
//      5 skip-relu -> Xs ONLY (no global write; feeds stage 2)
// Stage 2 (n2>0): flat double-buffered pipeline over n2*4 k-steps of
// Xs(128x128, LDS) @ B2 (contiguous tiles), output per 4 steps.
// LDS 48KB: Xs aliases stage-1 As/Bs; B2 staging is separate 16KB.
struct GemmSeg {
  const ushort* A; const ushort* B; const float* bias;
  void* out; const ushort* xsP;
  int Ktiles, ldo, Mreal, skip_idx, epi, NT, start;
  int n2; const ushort* B2; const float* bias2;
  void* out2; int ldo2, Mreal2, epi2;
};
struct Gemm3 { GemmSeg s[3]; const float* skip; int nseg; };

__launch_bounds__(256)
__global__ void gemm_sched(Gemm3 g3)
{
  __shared__ __align__(16) ushort lds[24576];
  ushort* As0 = lds;           // stage1 A dbuf: [0, 8192)
  ushort* Bs0 = lds + 8192;    // stage1 B dbuf: [8192, 16384)
  ushort* Xs  = lds;           // stage2 X tile: [0, 16384)  (aliases As+Bs)
  ushort* B2s = lds + 16384;   // stage2 B dbuf: [16384, 24576)

  int bid = blockIdx.x;
  int si = 0;
  if (g3.nseg > 1 && bid >= g3.s[1].start)
    si = (g3.nseg > 2 && bid >= g3.s[2].start) ? 2 : 1;
  const GemmSeg sg = g3.s[si];
  int local = bid - sg.start;
  int tm = local / sg.NT, tn = local - tm * sg.NT;

  const int t = threadIdx.x;
  const int wave = t >> 6, lane = t & 63;
  const int wm = (wave >> 1) * 64, wn = (wave & 1) * 64;
  const int l16 = lane & 15, quad = lane >> 4;
  const int Ktiles = sg.Ktiles;
  const int swz = (quad ^ ((l16 >> 1) & 3)) * 8;

  const ushort* Abase = sg.A + (size_t)tm * Ktiles * 4096;
  const ushort* Bbase = sg.B + (size_t)tn * Ktiles * 4096;

  floatx4 acc[4][4];
#pragma unroll
  for (int i = 0; i < 4; ++i)
#pragma unroll
    for (int j = 0; j < 4; ++j) acc[i][j] = (floatx4){0.f, 0.f, 0.f, 0.f};

  auto stage = [&](int tk, int buf) {
#pragma unroll
    for (int j = 0; j < 4; ++j) {
      int c = wave * 4 + j;
      if (c < 8)
        gll16(Abase + (size_t)tk * 4096 + c * 512 + lane * 8, As0 + buf * 4096 + c * 512);
      else
        gll16(Bbase + (size_t)tk * 4096 + (c - 8) * 512 + lane * 8,
              Bs0 + buf * 4096 + (c - 8) * 512);
    }
  };
  auto stage2L = [&](int s2, int buf) {
#pragma unroll
    for (int j = 0; j < 2; ++j) {
      int c = wave * 2 + j;
      gll16(sg.B2 + (size_t)s2 * 4096 + c * 512 + lane * 8, B2s + buf * 4096 + c * 512);
    }
  };

  stage(0, 0);
  __syncthreads();

  for (int tk = 0; tk < Ktiles; ++tk) {
    int buf = tk & 1;
    if (tk + 1 < Ktiles) stage(tk + 1, buf ^ 1);

    short8 af[4], bfr[4];
#pragma unroll
    for (int i = 0; i < 4; ++i) {
      af[i]  = *(const short8*)&As0[buf * 4096 + (wm + i * 16 + l16) * 32 + swz];
      bfr[i] = *(const short8*)&Bs0[buf * 4096 + (wn + i * 16 + l16) * 32 + swz];
    }
#pragma unroll
    for (int mi = 0; mi < 4; ++mi)
#pragma unroll
      for (int ni = 0; ni < 4; ++ni)
        acc[mi][ni] = __builtin_amdgcn_mfma_f32_16x16x32_bf16(
            bfr[ni], af[mi], acc[mi][ni], 0, 0, 0);
    __syncthreads();
  }

  // prefetch first stage-2 B tile under the epilogue stores
  if (sg.n2 > 0) stage2L(0, 0);

  const int epi = sg.epi;
  float g = 0.f, omg = 0.f;
  if (epi == 2 || epi == 3 || epi == 5) {
    float s = g3.skip[sg.skip_idx];
    g = 1.f / (1.f + __expf(-s));
    omg = 1.f - g;
  }
#pragma unroll
  for (int ni = 0; ni < 4; ++ni) {
    int cl = wn + ni * 16 + quad * 4;     // 4 consecutive local cols
    int cb = tn * 128 + cl;
    float4 b4 = *(const float4*)&sg.bias[cb];
#pragma unroll
    for (int mi = 0; mi < 4; ++mi) {
      int prow = wm + mi * 16 + l16;
      int rr = tm * 128 + prow;
      float v0 = acc[mi][ni][0] + b4.x;
      float v1 = acc[mi][ni][1] + b4.y;
      float v2 = acc[mi][ni][2] + b4.z;
      float v3 = acc[mi][ni][3] + b4.w;
      if (epi == 0) {
        uint2 o = make_uint2(((uint)f2b(v1) << 16) | f2b(v0),
                             ((uint)f2b(v3) << 16) | f2b(v2));
        *(uint2*)&((ushort*)sg.out)[(size_t)rr * sg.ldo + cb] = o;
      } else if (epi == 1) {
        if (rr < sg.Mreal)
          *(float4*)&((float*)sg.out)[(size_t)rr * sg.ldo + cb] =
              make_float4(v0, v1, v2, v3);
      } else if (epi == 2) {
        if (rr < sg.Mreal) {
          uint2 xo = *(const uint2*)&sg.xsP[a_packed_us(rr, cb)];
          float4 o;
          o.x = fmaxf(g * v0 + omg * blo(xo.x), 0.f);
          o.y = fmaxf(g * v1 + omg * bhi(xo.x), 0.f);
          o.z = fmaxf(g * v2 + omg * blo(xo.y), 0.f);
          o.w = fmaxf(g * v3 + omg * bhi(xo.y), 0.f);
          *(float4*)&((float*)sg.out)[(size_t)rr * sg.ldo + cb] = o;
        }
      } else if (epi == 3) {
        uint2 xo = *(const uint2*)&sg.xsP[a_packed_us(rr, cb)];
        uint2 o = make_uint2(
            ((uint)f2b(fmaxf(g * v1 + omg * bhi(xo.x), 0.f)) << 16) |
                   f2b(fmaxf(g * v0 + omg * blo(xo.x), 0.f)),
            ((uint)f2b(fmaxf(g * v3 + omg * bhi(xo.y), 0.f)) << 16) |
                   f2b(fmaxf(g * v2 + omg * blo(xo.y), 0.f)));
        *(uint2*)&((ushort*)sg.out)[a_packed_us(rr, cb)] = o;
      } else if (epi == 4) {
        uint2 o = make_uint2(((uint)f2b(v1) << 16) | f2b(v0),
                             ((uint)f2b(v3) << 16) | f2b(v2));
        *(uint2*)&((ushort*)sg.out)[a_packed_us(rr, cb)] = o;
        int sw2 = ((cl & 31) >> 3) ^ ((prow >> 1) & 3);
        *(uint2*)&Xs[(cl >> 5) * 4096 + prow * 32 + sw2 * 8 + (cl & 7)] = o;
      } else {  // 5: skip-relu into Xs only
        uint2 xo = *(const uint2*)&sg.xsP[a_packed_us(rr, cb)];
        uint2 o = make_uint2(
            ((uint)f2b(fmaxf(g * v1 + omg * bhi(xo.x), 0.f)) << 16) |
                   f2b(fmaxf(g * v0 + omg * blo(xo.x), 0.f)),
            ((uint)f2b(fmaxf(g * v3 + omg * bhi(xo.y), 0.f)) << 16) |
                   f2b(fmaxf(g * v2 + omg * blo(xo.y), 0.f)));
        int sw2 = ((cl & 31) >> 3) ^ ((prow >> 1) & 3);
        *(uint2*)&Xs[(cl >> 5) * 4096 + prow * 32 + sw2 * 8 + (cl & 7)] = o;
      }
    }
  }

  // ---------------- stage 2: flat pipeline over n2*4 k-steps ----------------
  if (sg.n2 == 0) return;
  __syncthreads();   // Xs + first B2 tile ready
  int total2 = sg.n2 * 4;
  floatx4 a2[4][4];
#pragma unroll
  for (int i = 0; i < 4; ++i)
#pragma unroll
    for (int j = 0; j < 4; ++j) a2[i][j] = (floatx4){0.f, 0.f, 0.f, 0.f};
  for (int s2 = 0; s2 < total2; ++s2) {
    int buf = s2 & 1;
    if (s2 + 1 < total2) stage2L(s2 + 1, buf ^ 1);
    int xb = (s2 & 3) * 4096;
    short8 af[4], bfr[4];
#pragma unroll
    for (int i = 0; i < 4; ++i) {
      af[i]  = *(const short8*)&Xs[xb + (wm + i * 16 + l16) * 32 + swz];
      bfr[i] = *(const short8*)&B2s[buf * 4096 + (wn + i * 16 + l16) * 32 + swz];
    }
#pragma unroll
    for (int mi = 0; mi < 4; ++mi)
#pragma unroll
      for (int ni = 0; ni < 4; ++ni)
        a2[mi][ni] = __builtin_amdgcn_mfma_f32_16x16x32_bf16(
            bfr[ni], af[mi], a2[mi][ni], 0, 0, 0);
    __syncthreads();
    if ((s2 & 3) == 3) {
      int t2 = s2 >> 2;
#pragma unroll
      for (int ni = 0; ni < 4; ++ni) {
        int cb2 = t2 * 128 + wn + ni * 16 + quad * 4;
        float4 b4 = *(const float4*)&sg.bias2[cb2];
#pragma unroll
        for (int mi = 0; mi < 4; ++mi) {
          int rr = tm * 128 + wm + mi * 16 + l16;
          float v0 = a2[mi][ni][0] + b4.x;
          float v1 = a2[mi][ni][1] + b4.y;
          float v2 = a2[mi][ni][2] + b4.z;
          float v3 = a2[mi][ni][3] + b4.w;
          if (sg.epi2 == 0) {
            uint2 o = make_uint2(((uint)f2b(v1) << 16) | f2b(v0),
                                 ((uint)f2b(v3) << 16) | f2b(v2));
            *(uint2*)&((ushort*)sg.out2)[(size_t)rr * sg.ldo2 + cb2] = o;
          } else {
            if (rr < sg.Mreal2)
              *(float4*)&((float*)sg.out2)[(size_t)rr * sg.ldo2 + cb2] =
                  make_float4(v0, v1, v2, v3);
          }
          a2[mi][ni] = (floatx4){0.f, 0.f, 0.f, 0.f};
        }
      }
    }
  }
}

// ================= gather: one wave per dst node, 2x4 edges/iter ==========
// (measured-best 8-edge form: VGPR 32, occupancy ~70%)
struct GatherType { const ushort* q; ushort* agg; int ldq; };
struct GatherDesc { GatherType ty[3]; int n0, n1; };

__launch_bounds__(256)
__global__ void gather_all(const int* __restrict__ starts,
                           const uint* __restrict__ payload,
                           const ushort* __restrict__ kvbase,
                           GatherDesc gd, int Ntot)
{
  int wid = (blockIdx.x * 256 + threadIdx.x) >> 6;
  if (wid >= Ntot) return;
  int lane = threadIdx.x & 63;
  int g = lane >> 4, l = lane & 15;

  GatherType T;
  int d;
  if (wid < gd.n0)      { T = gd.ty[0]; d = wid; }
  else if (wid < gd.n1) { T = gd.ty[1]; d = wid - gd.n0; }
  else                  { T = gd.ty[2]; d = wid - gd.n1; }

  const char* kvb = (const char*)kvbase;
  const uint lofs = (uint)l * 16u;

  uint4 qv = *(const uint4*)(T.q + (size_t)d * T.ldq + l * 8);
  f32x2 q0 = b2x2(qv.x), q1 = b2x2(qv.y), q2 = b2x2(qv.z), q3 = b2x2(qv.w);

  int e0 = starts[wid], e1 = starts[wid + 1];
  float lsum = 0.f;
  f32x2 ac0 = {0.f, 0.f}, ac1 = {0.f, 0.f}, ac2 = {0.f, 0.f}, ac3 = {0.f, 0.f};

  for (int eb = e0; eb < e1; eb += 8) {
    int eA = eb + g, eB = eA + 4;
    bool actA = eA < e1, actB = eB < e1;
    uint pA = payload[actA ? eA : e0];
    uint pB = payload[actB ? eB : e0];
    const char* bA = kvb + (pA + lofs);
    const char* bB = kvb + (pB + lofs);
    uint4 kA = *(const uint4*)bA;
    uint4 vA = *(const uint4*)(bA + 256);
    uint4 kB = *(const uint4*)bB;
    uint4 vB = *(const uint4*)(bB + 256);

    f32x2 dA = q0 * b2x2(kA.x);
    dA = __builtin_elementwise_fma(q1, b2x2(kA.y), dA);
    dA = __builtin_elementwise_fma(q2, b2x2(kA.z), dA);
    dA = __builtin_elementwise_fma(q3, b2x2(kA.w), dA);
    f32x2 dB = q0 * b2x2(kB.x);
    dB = __builtin_elementwise_fma(q1, b2x2(kB.y), dB);
    dB = __builtin_elementwise_fma(q2, b2x2(kB.z), dB);
    dB = __builtin_elementwise_fma(q3, b2x2(kB.w), dB);
    float pa = dA.x + dA.y;
    float pb = dB.x + dB.y;
    pa += __shfl_xor(pa, 1, 64);
    pb += __shfl_xor(pb, 1, 64);
    float exA = exp2f(fminf(pa, 115.4f));
    float exB = exp2f(fminf(pb, 115.4f));
    exA = actA ? exA : 0.f;
    exB = actB ? exB : 0.f;
    lsum += exA + exB;
    f32x2 xA = {exA, exA}, xB = {exB, exB};
    ac0 = __builtin_elementwise_fma(xA, b2x2(vA.x), ac0);
    ac1 = __builtin_elementwise_fma(xA, b2x2(vA.y), ac1);
    ac2 = __builtin_elementwise_fma(xA, b2x2(vA.z), ac2);
    ac3 = __builtin_elementwise_fma(xA, b2x2(vA.w), ac3);
    ac0 = __builtin_elementwise_fma(xB, b2x2(vB.x), ac0);
    ac1 = __builtin_elementwise_fma(xB, b2x2(vB.y), ac1);
    ac2 = __builtin_elementwise_fma(xB, b2x2(vB.z), ac2);
    ac3 = __builtin_elementwise_fma(xB, b2x2(vB.w), ac3);
  }

  float s0 = ac0.x, s1 = ac0.y, s2 = ac1.x, s3 = ac1.y;
  float s4 = ac2.x, s5 = ac2.y, s6 = ac3.x, s7 = ac3.y;
#define MRG(v) v += __shfl_xor(v, 16, 64); v += __shfl_xor(v, 32, 64)
  MRG(lsum); MRG(s0); MRG(s1); MRG(s2); MRG(s3); MRG(s4); MRG(s5); MRG(s6); MRG(s7);
#undef MRG

  // each lane finishes channels c0 = 8*l + 2*g and c0+1
  float inv = 1.f / (lsum + 1e-16f);
  float m0 = (g & 1) ? s2 : s0, m1 = (g & 1) ? s6 : s4;
  float n0 = (g & 1) ? s3 : s1, n1 = (g & 1) ? s7 : s5;
  float x0 = ((g & 2) ? m1 : m0) * inv;
  float x1 = ((g & 2) ? n1 : n0) * inv;
  float g0 = 0.5f * x0 * (1.f + erff(x0 * 0.70710678118654752f));
  float g1 = 0.5f * x1 * (1.f + erff(x1 * 0.70710678118654752f));
  int tm = d >> 7, row = d & 127;
  int tk = l >> 2, sw = (l & 3) ^ ((row >> 1) & 3);
  size_t us = (((size_t)tm * 4 + tk) * 512 + (size_t)row * 4 + sw) * 8 + 2 * g;
  *(uint*)(T.agg + us) = ((uint)f2b(g1) << 16) | (uint)f2b(g0);
}

// ================= host =====================================================
extern "C" void kernel_launch(void* const* d_in, const int* in_sizes, int n_in,
                              void* d_out, int out_size, void* d_ws, size_t ws_size,
                              hipStream_t stream)
{
  const float* x_herb = (const float*)d_in[0];
  const float* x_ing  = (const float*)d_in[1];
  const float* x_tgt  = (const float*)d_in[2];
  const float* W_herb = (const float*)d_in[3];
  const float* b_herb = (const float*)d_in[4];
  const float* W_ing  = (const float*)d_in[5];
  const float* b_ing  = (const float*)d_in[6];
  const float* W_tgt  = (const float*)d_in[7];
  const float* b_tgt  = (const float*)d_in[8];
  const float* Wk     = (const float*)d_in[9];
  const float* bk     = (const float*)d_in[10];
  const float* Wq     = (const float*)d_in[11];
  const float* bq     = (const float*)d_in[12];
  const float* Wv     = (const float*)d_in[13];
  const float* bv     = (const float*)d_in[14];
  const float* a_rel  = (const float*)d_in[15];
  const float* m_rel  = (const float*)d_in[16];
  const float* p_rel  = (const float*)d_in[17];
  const float* Wa     = (const float*)d_in[18];
  const float* ba     = (const float*)d_in[19];
  const float* skip   = (const float*)d_in[20];
  const float* W_out  = (const float*)d_in[21];
  const float* b_out  = (const float*)d_in[22];
  const int* srcs[4] = {(const int*)d_in[23], (const int*)d_in[25],
                        (const int*)d_in[27], (const int*)d_in[29]};
  const int* dsts[4] = {(const int*)d_in[24], (const int*)d_in[26],
                        (const int*)d_in[28], (const int*)d_in[30]};

  const int Nh = in_sizes[0] / 400;
  const int Ni = in_sizes[1] / 300;
  const int Nt = in_sizes[2] / 200;
  const int E  = in_sizes[23];
  const int Ntot = Nh + Ni + Nt;

  const int MT_h = (Nh + 127) / 128, MT_i = (Ni + 127) / 128, MT_t = (Nt + 127) / 128;
  const int KT_h = 13, KT_i = 10, KT_t = 7;   // Kpad 416/320/224

  // CSR sort params
  const int NBs = (E + CSR_CH - 1) / CSR_CH;
  const int NBH = 4 * NBs;
  const int NBK = (Ntot + (1 << CSR_SH) - 1) >> CSR_SH;   // <= 511

  char* base = (char*)d_ws;
  size_t off = 0;
  auto A = [&](size_t bytes) -> void* {
    void* p = base + off; off += (bytes + 255) & ~(size_t)255; return p;
  };
  ushort* xp_h  = (ushort*)A((size_t)MT_h * KT_h * 8192);
  ushort* xp_i  = (ushort*)A((size_t)MT_i * KT_i * 8192);
  ushort* xp_t  = (ushort*)A((size_t)MT_t * KT_t * 8192);
  ushort* xsP_h = (ushort*)A((size_t)MT_h * 4 * 8192);
  ushort* xsP_i = (ushort*)A((size_t)MT_i * 4 * 8192);
  ushort* xsP_t = (ushort*)A((size_t)MT_t * 4 * 8192);
  ushort* fused_h = (ushort*)A((size_t)MT_h * 128 * 384 * 2);  // [q|k0|v0]
  ushort* fused_i = (ushort*)A((size_t)MT_i * 128 * 640 * 2);  // [q|k1|v1|k2|v2]
  ushort* fused_t = (ushort*)A((size_t)MT_t * 128 * 384 * 2);  // [q|k3|v3]
  ushort* aggp_h  = (ushort*)A((size_t)MT_h * 4 * 8192);
  ushort* aggp_i  = (ushort*)A((size_t)MT_i * 4 * 8192);
  ushort* aggp_t  = (ushort*)A((size_t)MT_t * 4 * 8192);
  ushort* Weff1_h = (ushort*)A((size_t)KT_h * 8192);
  ushort* Weff1_i = (ushort*)A((size_t)KT_i * 8192);
  ushort* Weff1_t = (ushort*)A((size_t)KT_t * 8192);
  ushort* Wcat_h = (ushort*)A((size_t)3 * 4 * 8192);
  ushort* Wcat_i = (ushort*)A((size_t)5 * 4 * 8192);
  ushort* Wcat_t = (ushort*)A((size_t)3 * 4 * 8192);
  float* bcat   = (float*)A(1408 * 4);
  ushort* Wa_t   = (ushort*)A((size_t)3 * 16384 * 2);
  ushort* Wout_t = (ushort*)A((size_t)16384 * 2);
  int* starts  = (int*)A((size_t)(Ntot + 4) * 4);
  uint* payload = (uint*)A((size_t)(4 * E + 8) * 4);
  uint* hist    = (uint*)A((size_t)NBK * NBH * 4);
  uint* bucketTot  = (uint*)A((size_t)NBK * 4);
  uint2* inter  = (uint2*)A((size_t)(4 * E + 8) * 8);
  (void)ws_size; (void)n_in;

  const int toff_h = 0, toff_i = Nh, toff_t = Nh + Ni;
  dim3 blk(256);

  uint fi2 = (uint)((size_t)(fused_i - fused_h) * 2);
  uint ft2 = (uint)((size_t)(fused_t - fused_h) * 2);

  // --- 1: prologue (pack x3 + combine_rel + all weight prep + edge hist) ---
  int sl_h = MT_h * KT_h * 512, sl_i = MT_i * KT_i * 512, sl_t = MT_t * KT_t * 512;
  Prolog P;
  P.pk[0] = {x_herb, xp_h, Nh, 400, KT_h, 0};
  P.pk[1] = {x_ing,  xp_i, Ni, 300, KT_i, sl_h};
  P.pk[2] = {x_tgt,  xp_t, Nt, 200, KT_t, sl_h + sl_i};
  P.crwstart = sl_h + sl_i + sl_t;
  P.wstart = P.crwstart + 4 * 2 * 129 * 128;
  {
    const float* wsrc10[10] = {W_herb, W_ing, W_tgt, Wq, Wq + 16384, Wq + 32768,
                               Wa, Wa + 16384, Wa + 32768, W_out};
    ushort* wdst10[10] = {Weff1_h, Weff1_i, Weff1_t, Wcat_h, Wcat_i, Wcat_t,
                          Wa_t, Wa_t + 16384, Wa_t + 32768, Wout_t};
    int wk10[10] = {400, 300, 200, 128, 128, 128, 128, 128, 128, 128};
    int wcum = 0;
    for (int z = 0; z < 10; ++z) {
      P.wb[z] = {wsrc10[z], wdst10[z], wk10[z], wcum};
      wcum += ((wk10[z] + 31) / 32) * 512;
    }
    P.bstart = P.wstart + wcum;
  }
  P.total = P.bstart + 384;
  P.Wk = Wk; P.bk = bk; P.Wv = Wv; P.bv = bv;
  P.a_rel = a_rel; P.m_rel = m_rel; P.p_rel = p_rel;
  P.kw_dst[0] = Wcat_h + 16384; P.vw_dst[0] = Wcat_h + 32768;
  P.kw_dst[1] = Wcat_i + 16384; P.vw_dst[1] = Wcat_i + 32768;
  P.kw_dst[2] = Wcat_i + 49152; P.vw_dst[2] = Wcat_i + 65536;
  P.kw_dst[3] = Wcat_t + 16384; P.vw_dst[3] = Wcat_t + 32768;
  P.bcat = bcat;
  P.kb_off[0] = 128;  P.vb_off[0] = 256;
  P.kb_off[1] = 512;  P.vb_off[1] = 640;
  P.kb_off[2] = 768;  P.vb_off[2] = 896;
  P.kb_off[3] = 1152; P.vb_off[3] = 1280;
  P.bq = bq;
  P.bq_off[0] = 0; P.bq_off[1] = 384; P.bq_off[2] = 1024;
  P.edst[0] = dsts[0]; P.eoff[0] = toff_i;
  P.edst[1] = dsts[1]; P.eoff[1] = toff_h;
  P.edst[2] = dsts[2]; P.eoff[2] = toff_t;
  P.edst[3] = dsts[3]; P.eoff[3] = toff_i;
  P.hist = hist; P.NBs = NBs; P.NBH = NBH; P.NBK = NBK; P.E = E;
  prologue<<<NBH + (P.total + 255) / 256, blk, 0, stream>>>(P);

  // --- 2: CSR build (scan -> scatter -> finalize) ---
  EdgeStreams ES;
  ES.src[0] = srcs[0]; ES.dst[0] = dsts[0]; ES.off[0] = toff_i;
  ES.rel[0] = 256u;        ES.ldb[0] = 768u;
  ES.src[1] = srcs[1]; ES.dst[1] = dsts[1]; ES.off[1] = toff_h;
  ES.rel[1] = fi2 + 256u;  ES.ldb[1] = 1280u;
  ES.src[2] = srcs[2]; ES.dst[2] = dsts[2]; ES.off[2] = toff_t;
  ES.rel[2] = fi2 + 768u;  ES.ldb[2] = 1280u;
  ES.src[3] = srcs[3]; ES.dst[3] = dsts[3]; ES.off[3] = toff_i;
  ES.rel[3] = ft2 + 256u;  ES.ldb[3] = 768u;
  bucket_scan<<<NBK, blk, 0, stream>>>(hist, bucketTot, NBH);
  bucket_scatter<<<NBH, blk, 0, stream>>>(ES, hist, bucketTot, inter, NBs, NBH, NBK, E);
  bucket_finalize<<<NBK, blk, 0, stream>>>(inter, bucketTot, starts, payload, Ntot, NBK);

  // --- 3: K1 = GEMM1 + GEMM2 fused (xs kept in LDS, 3-5 col-tiles of qkv) ---
  Gemm3 G1;
  G1.skip = skip; G1.nseg = 3;
  G1.s[0] = {xp_h, Weff1_h, b_herb, xsP_h, nullptr, KT_h, 0, 0, 0, 4, 1, 0,
             3, Wcat_h, bcat + 0, fused_h, 384, 0, 0};
  G1.s[1] = {xp_i, Weff1_i, b_ing,  xsP_i, nullptr, KT_i, 0, 0, 0, 4, 1, MT_h,
             5, Wcat_i, bcat + 384, fused_i, 640, 0, 0};
  G1.s[2] = {xp_t, Weff1_t, b_tgt,  xsP_t, nullptr, KT_t, 0, 0, 0, 4, 1, MT_h + MT_i,
             3, Wcat_t, bcat + 1024, fused_t, 384, 0, 0};
  gemm_sched<<<MT_h + MT_i + MT_t, blk, 0, stream>>>(G1);

  // --- 4: gather attention (all types, one wave per node) ---
  GatherDesc GD;
  GD.n0 = Nh; GD.n1 = Nh + Ni;
  GD.ty[0] = {fused_h, aggp_h, 384};
  GD.ty[1] = {fused_i, aggp_i, 640};
  GD.ty[2] = {fused_t, aggp_t, 384};
  gather_all<<<(Ntot + 3) / 4, blk, 0, stream>>>(starts, payload, fused_h, GD, Ntot);

  // --- 5: K2 = epilogue GEMMs; herb chains W_out stage from LDS (GF fused) ---
  float* outp = (float*)d_out;
  float* out_herb = outp;
  float* out_ing  = outp + (size_t)Nh * HID;
  float* out_tgt  = outp + (size_t)(Nh + Ni) * HID;
  Gemm3 GE;
  GE.skip = skip; GE.nseg = 3;
  GE.s[0] = {aggp_h, Wa_t + 0 * 16384, ba + 0 * 128, nullptr, xsP_h,
             4, 0, 0, 0, 5, 1, 0,
             1, Wout_t, b_out, out_herb, 128, Nh, 1};
  GE.s[1] = {aggp_i, Wa_t + 1 * 16384, ba + 1 * 128, out_ing, xsP_i,
             4, 128, Ni, 1, 2, 1, MT_h,
             0, nullptr, nullptr, nullptr, 0, 0, 0};
  GE.s[2] = {aggp_t, Wa_t + 2 * 16384, ba + 2 * 128, out_tgt, xsP_t,
             4, 128, Nt, 2, 2, 1, MT_h + MT_i,
             0, nullptr, nullptr, nullptr, 0, 0, 0};
  gemm_sched<<<MT_h + MT_i + MT_t, blk, 0, stream>>>(GE);
  (void)out_size;
}

// Round 6
// 378.877 us; speedup vs baseline: 1.2160x; 1.0533x over previous
//
#include <hip/hip_runtime.h>
#include <math.h>

#define HID 128
typedef unsigned int uint;
typedef unsigned short ushort;
typedef __attribute__((ext_vector_type(8))) short short8;
typedef __attribute__((ext_vector_type(4))) float floatx4;
typedef __attribute__((ext_vector_type(2))) float f32x2;

// ---------- bf16 helpers ----------
__device__ __forceinline__ ushort f2b(float f) {
  uint u = __float_as_uint(f);
  u += 0x7fffu + ((u >> 16) & 1u);
  return (ushort)(u >> 16);
}
__device__ __forceinline__ float b2f(ushort s) {
  return __uint_as_float(((uint)s) << 16);
}
__device__ __forceinline__ float blo(uint u) { return __uint_as_float(u << 16); }
__device__ __forceinline__ float bhi(uint u) { return __uint_as_float(u & 0xffff0000u); }
__device__ __forceinline__ f32x2 b2x2(uint u) {
  f32x2 r;
  r.x = __uint_as_float(u << 16);
  r.y = __uint_as_float(u & 0xffff0000u);
  return r;
}

__device__ __forceinline__ void gll16(const ushort* g, ushort* l) {
  __builtin_amdgcn_global_load_lds(
      (const __attribute__((address_space(1))) void*)g,
      (__attribute__((address_space(3))) void*)l, 16, 0, 0);
}

// Packed tile layout (128 rows x 32 k, bf16), 16B slot within tile:
//   slot = row*4 + (chunk ^ ((row>>1)&3)), chunk = k/8. Conflict-free staging+frags.
//   Rows [0,64) of a tile occupy the first 4096B contiguously (64-row halves
//   are independently addressable).
__device__ __forceinline__ size_t a_packed_us(int rr, int col) {
  int tm = rr >> 7, prow = rr & 127;
  int ptk = col >> 5, kin = col & 31;
  int sw = (kin >> 3) ^ ((prow >> 1) & 3);
  return (((size_t)tm * 4 + ptk) * 512 + (size_t)prow * 4 + sw) * 8 + (kin & 7);
}

// ================= CSR params ==============================================
#define CSR_CH 2048   // edges per block in hist/scatter passes
#define CSR_SH 9      // 512 nodes per bucket

struct EdgeStreams {
  const int* src[4]; const int* dst[4];
  int off[4]; uint rel[4]; uint ldb[4];
};

// ================= prologue: pack x + combine_rel + weight prep + hist ======
struct PackSeg { const float* X; ushort* out; int M, K, Ktiles, start; };
struct WBlk { const float* src; ushort* dst; int K; int start; };
struct Prolog {
  PackSeg pk[3];
  int crwstart, wstart, bstart, total;
  const float *Wk, *bk, *Wv, *bv, *a_rel, *m_rel, *p_rel;
  ushort* kw_dst[4];
  ushort* vw_dst[4];
  float* bcat;
  int kb_off[4], vb_off[4];
  WBlk wb[10];
  const float* bq;
  int bq_off[3];
  // edge-hist segment (block-granular, blocks [0, NBH))
  const int* edst[4];
  int eoff[4];
  uint* hist;       // transposed: hist[bucket][block]
  int NBs, NBH, NBK, E;
};

// combine_rel: Wk_rel[e] = Wk[i] @ a_rel[e] (and Wv/m_rel), written DIRECTLY in
// packed-B bf16 layout. p_rel[e,h]/sqrt(D)*log2(e) is baked into the k weights
// and bias so the gather's logit feeds exp2 with no per-edge scale.
__device__ void combine_rel_elem(const Prolog& P, int idx)
{
  int col  = idx & 127;
  int rest = idx >> 7;
  int row  = rest % 129;
  rest /= 129;
  int kv = rest & 1;
  int e  = rest >> 1;
  int i  = (e + 1) >> 1;           // styp = {0,1,1,2}
  int h = col >> 4, j = col & 15;
  const float* Wsrc = kv ? P.Wv : P.Wk;
  const float* bsrc = kv ? P.bv : P.bk;
  const float* rel  = kv ? P.m_rel : P.a_rel;
  float acc = 0.f;
  if (row < 128) {
#pragma unroll
    for (int d = 0; d < 16; ++d)
      acc += Wsrc[(size_t)i * 16384 + (size_t)row * 128 + h * 16 + d] *
             rel[((e * 8 + h) * 16 + d) * 16 + j];
  } else {
#pragma unroll
    for (int d = 0; d < 16; ++d)
      acc += bsrc[i * 128 + h * 16 + d] * rel[((e * 8 + h) * 16 + d) * 16 + j];
  }
  if (!kv) acc *= P.p_rel[e * 8 + h] * 0.36067376022224085f;  // 0.25 * log2(e)
  if (row < 128) {
    ushort* dst = kv ? P.vw_dst[e] : P.kw_dst[e];
    int tk = row >> 5, chunk = (row >> 3) & 3, m = row & 7;
    int swf = chunk ^ ((col >> 1) & 3);
    dst[((tk * 512 + col * 4 + swf) << 3) + m] = f2b(acc);
  } else {
    P.bcat[(kv ? P.vb_off[e] : P.kb_off[e]) + col] = acc;
  }
}

// pure layout conversion of row-major fp32 [K][128] weights to packed-B bf16
__device__ void conv_elem(const Prolog& P, int s0)
{
  int si = 0;
#pragma unroll
  for (int k = 1; k < 10; ++k)
    if (s0 >= P.wb[k].start) si = k;
  WBlk b = P.wb[si];
  int s = s0 - b.start;
  int tk = s >> 9, o = s & 511;
  int c = o >> 2, swf = o & 3;
  int chunk = swf ^ ((c >> 1) & 3);
  int r0 = tk * 32 + chunk * 8;
  ushort tmp[8];
#pragma unroll
  for (int m = 0; m < 8; ++m) {
    int r = r0 + m;
    tmp[m] = (r < b.K) ? f2b(b.src[(size_t)r * 128 + c]) : (ushort)0;
  }
  *(short8*)&b.dst[(size_t)s * 8] = *(short8*)tmp;
}

__global__ __launch_bounds__(256)
void prologue(Prolog P)
{
  __shared__ uint h[512];
  int bI = blockIdx.x;
  if (bI < P.NBH) {
    // --- edge histogram segment (block-granular) ---
    int et = bI / P.NBs;
    int i0 = (bI - et * P.NBs) * CSR_CH;
    const int* dp = P.edst[et];
    int off = P.eoff[et];
    for (int t = threadIdx.x; t < P.NBK; t += 256) h[t] = 0;
    __syncthreads();
#pragma unroll
    for (int j = 0; j < CSR_CH / 256; ++j) {
      int idx = i0 + j * 256 + threadIdx.x;
      if (idx < P.E) atomicAdd(&h[(uint)(off + dp[idx]) >> CSR_SH], 1u);
    }
    __syncthreads();
    for (int t = threadIdx.x; t < P.NBK; t += 256)
      P.hist[(size_t)t * P.NBH + bI] = h[t];
    return;
  }
  int gtid = (bI - P.NBH) * 256 + threadIdx.x;
  if (gtid >= P.total) return;
  if (gtid >= P.bstart) {
    int j = gtid - P.bstart;
    P.bcat[P.bq_off[j >> 7] + (j & 127)] = P.bq[j];
    return;
  }
  if (gtid >= P.wstart) { conv_elem(P, gtid - P.wstart); return; }
  if (gtid >= P.crwstart) { combine_rel_elem(P, gtid - P.crwstart); return; }
  int si = 0;
  if (gtid >= P.pk[2].start) si = 2;
  else if (gtid >= P.pk[1].start) si = 1;
  const PackSeg s = P.pk[si];
  int slot = gtid - s.start;
  int spm = s.Ktiles << 9;
  int tm = slot / spm, r2 = slot - tm * spm;
  int tk = r2 >> 9, o = r2 & 511;
  int row = o >> 2, sw = o & 3;
  int chunk = sw ^ ((row >> 1) & 3);
  int grow = tm * 128 + row;
  int gk = tk * 32 + chunk * 8;
  ushort tmp[8];
  if (grow < s.M && gk + 8 <= s.K) {
    const float* p = s.X + (size_t)grow * s.K + gk;
    float4 a = *(const float4*)p, b = *(const float4*)(p + 4);
    tmp[0] = f2b(a.x); tmp[1] = f2b(a.y); tmp[2] = f2b(a.z); tmp[3] = f2b(a.w);
    tmp[4] = f2b(b.x); tmp[5] = f2b(b.y); tmp[6] = f2b(b.z); tmp[7] = f2b(b.w);
  } else {
#pragma unroll
    for (int j = 0; j < 8; ++j) {
      int kk = gk + j;
      tmp[j] = (grow < s.M && kk < s.K) ? f2b(s.X[(size_t)grow * s.K + kk]) : (ushort)0;
    }
  }
  *(short8*)&s.out[(size_t)slot * 8] = *(short8*)tmp;
}

// ================= CSR build: two-level counting sort =======================
__global__ __launch_bounds__(256)
void bucket_scan(uint* __restrict__ hist, uint* __restrict__ bucketTot, int NBH)
{
  __shared__ uint ws[4];
  __shared__ uint carry_s;
  int b = blockIdx.x;
  int t = threadIdx.x, lane = t & 63, w = t >> 6;
  if (t == 0) carry_s = 0;
  __syncthreads();
  for (int base = 0; base < NBH; base += 256) {
    int i = base + t;
    uint x = (i < NBH) ? hist[(size_t)b * NBH + i] : 0u;
    uint v = x;
#pragma unroll
    for (int o = 1; o < 64; o <<= 1) {
      uint y = __shfl_up(v, o, 64);
      if (lane >= o) v += y;
    }
    if (lane == 63) ws[w] = v;
    __syncthreads();
    uint add = carry_s;
    for (int k = 0; k < w; ++k) add += ws[k];
    if (i < NBH) hist[(size_t)b * NBH + i] = add + v - x;
    __syncthreads();
    if (t == 255) carry_s = add + v;
    __syncthreads();
  }
  if (t == 0) bucketTot[b] = carry_s;
}

// local exclusive scan of bucketTot (<=512 entries) into sb[]; 2 slots/thread
__device__ __forceinline__ void base_scan(const uint* __restrict__ bucketTot,
                                          uint* sb, uint* ws, int NBK)
{
  int t = threadIdx.x, lane = t & 63, w = t >> 6;
  sb[t] = (t < NBK) ? bucketTot[t] : 0u;
  sb[t + 256] = (t + 256 < NBK) ? bucketTot[t + 256] : 0u;
  __syncthreads();
  uint a0 = sb[2 * t], a1 = sb[2 * t + 1];
  uint s = a0 + a1;
  uint v = s;
#pragma unroll
  for (int o = 1; o < 64; o <<= 1) {
    uint y = __shfl_up(v, o, 64);
    if (lane >= o) v += y;
  }
  if (lane == 63) ws[w] = v;
  __syncthreads();
  uint add = 0;
  for (int k = 0; k < w; ++k) add += ws[k];
  uint e0 = add + v - s;
  sb[2 * t] = e0;
  sb[2 * t + 1] = e0 + a0;
  __syncthreads();
}

// Pass C: scatter (payload, dst) into bucket-contiguous intermediate
__global__ __launch_bounds__(256)
void bucket_scatter(EdgeStreams es, const uint* __restrict__ hist,
                    const uint* __restrict__ bucketTot,
                    uint2* __restrict__ inter, int NBs, int NBH, int NBK, int E)
{
  __shared__ uint sb[516];
  __shared__ uint ws[4];
  __shared__ uint cur[512];
  base_scan(bucketTot, sb, ws, NBK);
  int b = blockIdx.x;
  int et = b / NBs;
  int i0 = (b - et * NBs) * CSR_CH;
  const int* dp = es.dst[et];
  const int* sp = es.src[et];
  int off = es.off[et];
  uint rel = es.rel[et], ldb = es.ldb[et];
  for (int t = threadIdx.x; t < NBK; t += 256)
    cur[t] = sb[t] + hist[(size_t)t * NBH + b];
  __syncthreads();
#pragma unroll
  for (int j = 0; j < CSR_CH / 256; ++j) {
    int idx = i0 + j * 256 + threadIdx.x;
    if (idx < E) {
      int g = off + dp[idx];
      uint pos = atomicAdd(&cur[(uint)g >> CSR_SH], 1u);
      inter[pos] = make_uint2(rel + (uint)sp[idx] * ldb, (uint)g);
    }
  }
}

// Pass D: one block per bucket; per-node count+scan in LDS, write starts and
// final payload into this block's contiguous region (single-writer lines).
__global__ __launch_bounds__(256)
void bucket_finalize(const uint2* __restrict__ inter,
                     const uint* __restrict__ bucketTot,
                     int* __restrict__ starts, uint* __restrict__ payload,
                     int Ntot, int NBK)
{
  __shared__ uint sb[516];
  __shared__ uint ncnt[512];
  __shared__ uint ws[4];
  base_scan(bucketTot, sb, ws, NBK);
  int b = blockIdx.x;
  int g0 = b << CSR_SH;
  int t = threadIdx.x, lane = t & 63, w = t >> 6;
  uint r0 = sb[b], r1 = sb[b + 1];
  if (b == NBK - 1 && t == 0) starts[Ntot] = (int)r1;
  ncnt[t] = 0; ncnt[t + 256] = 0;
  __syncthreads();
  for (uint i = r0 + t; i < r1; i += 256)
    atomicAdd(&ncnt[inter[i].y - g0], 1u);
  __syncthreads();
  uint a0 = ncnt[2 * t], a1 = ncnt[2 * t + 1];
  uint s = a0 + a1;
  uint v = s;
#pragma unroll
  for (int o = 1; o < 64; o <<= 1) {
    uint y = __shfl_up(v, o, 64);
    if (lane >= o) v += y;
  }
  if (lane == 63) ws[w] = v;
  __syncthreads();
  uint add = r0;
  for (int k = 0; k < w; ++k) add += ws[k];
  uint e0 = add + v - s;
  int gi = g0 + 2 * t;
  if (gi < Ntot)     starts[gi]     = (int)e0;
  if (gi + 1 < Ntot) starts[gi + 1] = (int)(e0 + a0);
  ncnt[2 * t] = e0;          // reuse as cursors
  ncnt[2 * t + 1] = e0 + a0;
  __syncthreads();
  for (uint i = r0 + t; i < r1; i += 256) {
    uint2 rec = inter[i];
    uint pos = atomicAdd(&ncnt[rec.y - g0], 1u);
    payload[pos] = rec.x;
  }
}

// ================= fused multi-segment MFMA GEMM (two-stage, 64-row) =======
// Each block owns a 64-row half of a packed 128-row M-tile (grid = 2x tiles;
// the packed layout stores rows [0,64) in the first 4096B of each tile, so a
// half is contiguous). 4 waves side-by-side along N: wave w = 64 rows x 32
// cols, acc[4][2]. TRANSPOSED mfma: lane's 4 acc regs = 4 consecutive output
// columns -> uint2/float4 stores.
// epi: 0 bf16 row-major unguarded; 1 fp32 guarded; 2 skip-relu fp32 guarded;
//      3 skip-relu bf16 packed; 4 plain bf16 packed (+Xs stash if n2>0);
//      5 skip-relu -> Xs ONLY (feeds stage 2)
// Stage 2 (n2>0): flat dbuf pipeline over n2*4 k-steps of Xs(64x128) @ B2.
// LDS 40KB: [0,8KB) A-half dbuf | [8KB,24KB) B dbuf | [24KB,40KB) Xs;
// stage-2 B2 dbuf (16KB) aliases [0,16KB).
struct GemmSeg {
  const ushort* A; const ushort* B; const float* bias;
  void* out; const ushort* xsP;
  int Ktiles, ldo, Mreal, skip_idx, epi, NT, start;
  int n2; const ushort* B2; const float* bias2;
  void* out2; int ldo2, Mreal2, epi2;
};
struct Gemm3 { GemmSeg s[3]; const float* skip; int nseg; };

__launch_bounds__(256)
__global__ void gemm_sched(Gemm3 g3)
{
  __shared__ __align__(16) ushort lds[20480];
  ushort* Xs = lds + 12288;    // 64x128 packed (4 k-chunks x 2048 ushorts)

  int bid = blockIdx.x;
  int si = 0;
  if (g3.nseg > 1 && bid >= g3.s[1].start)
    si = (g3.nseg > 2 && bid >= g3.s[2].start) ? 2 : 1;
  const GemmSeg sg = g3.s[si];
  int local = bid - sg.start;
  int tmH = local / sg.NT, tn = local - tmH * sg.NT;
  int tm = tmH >> 1, hm = tmH & 1;

  const int t = threadIdx.x;
  const int wave = t >> 6, lane = t & 63;
  const int wn = wave * 32;
  const int l16 = lane & 15, quad = lane >> 4;
  const int Ktiles = sg.Ktiles;
  const int swz = (quad ^ ((l16 >> 1) & 3)) * 8;

  const ushort* Ahalf = sg.A + ((size_t)tm * Ktiles) * 4096 + hm * 2048;
  const ushort* Bbase = sg.B + (size_t)tn * Ktiles * 4096;

  floatx4 acc[4][2];
#pragma unroll
  for (int i = 0; i < 4; ++i)
#pragma unroll
    for (int j = 0; j < 2; ++j) acc[i][j] = (floatx4){0.f, 0.f, 0.f, 0.f};

  // 12 wave-loads per K-tile: A-half 4 chunks + B 8 chunks; 3 per wave.
  auto stage = [&](int tk, int buf) {
#pragma unroll
    for (int j = 0; j < 3; ++j) {
      int c = wave * 3 + j;
      if (c < 4)
        gll16(Ahalf + (size_t)tk * 4096 + c * 512 + lane * 8,
              lds + buf * 2048 + c * 512);
      else
        gll16(Bbase + (size_t)tk * 4096 + (c - 4) * 512 + lane * 8,
              lds + 4096 + buf * 4096 + (c - 4) * 512);
    }
  };
  auto stage2L = [&](int s2, int buf) {
#pragma unroll
    for (int j = 0; j < 2; ++j) {
      int c = wave * 2 + j;
      gll16(sg.B2 + (size_t)s2 * 4096 + c * 512 + lane * 8,
            lds + buf * 4096 + c * 512);
    }
  };

  stage(0, 0);
  __syncthreads();

  for (int tk = 0; tk < Ktiles; ++tk) {
    int buf = tk & 1;
    if (tk + 1 < Ktiles) stage(tk + 1, buf ^ 1);

    short8 af[4], bfr[2];
#pragma unroll
    for (int i = 0; i < 4; ++i)
      af[i] = *(const short8*)&lds[buf * 2048 + (i * 16 + l16) * 32 + swz];
#pragma unroll
    for (int n = 0; n < 2; ++n)
      bfr[n] = *(const short8*)&lds[4096 + buf * 4096 + (wn + n * 16 + l16) * 32 + swz];
#pragma unroll
    for (int mi = 0; mi < 4; ++mi)
#pragma unroll
      for (int ni = 0; ni < 2; ++ni)
        acc[mi][ni] = __builtin_amdgcn_mfma_f32_16x16x32_bf16(
            bfr[ni], af[mi], acc[mi][ni], 0, 0, 0);
    __syncthreads();
  }

  // prefetch first stage-2 B tile under the epilogue (aliases dead stage-1 LDS)
  if (sg.n2 > 0) stage2L(0, 0);

  const int epi = sg.epi;
  float g = 0.f, omg = 0.f;
  if (epi == 2 || epi == 3 || epi == 5) {
    float s = g3.skip[sg.skip_idx];
    g = 1.f / (1.f + __expf(-s));
    omg = 1.f - g;
  }
#pragma unroll
  for (int ni = 0; ni < 2; ++ni) {
    int cl = wn + ni * 16 + quad * 4;     // 4 consecutive local cols
    int cb = tn * 128 + cl;
    float4 b4 = *(const float4*)&sg.bias[cb];
#pragma unroll
    for (int mi = 0; mi < 4; ++mi) {
      int prow = mi * 16 + l16;           // local row in the 64-row half
      int rr = tm * 128 + hm * 64 + prow;
      float v0 = acc[mi][ni][0] + b4.x;
      float v1 = acc[mi][ni][1] + b4.y;
      float v2 = acc[mi][ni][2] + b4.z;
      float v3 = acc[mi][ni][3] + b4.w;
      if (epi == 0) {
        uint2 o = make_uint2(((uint)f2b(v1) << 16) | f2b(v0),
                             ((uint)f2b(v3) << 16) | f2b(v2));
        *(uint2*)&((ushort*)sg.out)[(size_t)rr * sg.ldo + cb] = o;
      } else if (epi == 1) {
        if (rr < sg.Mreal)
          *(float4*)&((float*)sg.out)[(size_t)rr * sg.ldo + cb] =
              make_float4(v0, v1, v2, v3);
      } else if (epi == 2) {
        if (rr < sg.Mreal) {
          uint2 xo = *(const uint2*)&sg.xsP[a_packed_us(rr, cb)];
          float4 o;
          o.x = fmaxf(g * v0 + omg * blo(xo.x), 0.f);
          o.y = fmaxf(g * v1 + omg * bhi(xo.x), 0.f);
          o.z = fmaxf(g * v2 + omg * blo(xo.y), 0.f);
          o.w = fmaxf(g * v3 + omg * bhi(xo.y), 0.f);
          *(float4*)&((float*)sg.out)[(size_t)rr * sg.ldo + cb] = o;
        }
      } else if (epi == 3) {
        uint2 xo = *(const uint2*)&sg.xsP[a_packed_us(rr, cb)];
        uint2 o = make_uint2(
            ((uint)f2b(fmaxf(g * v1 + omg * bhi(xo.x), 0.f)) << 16) |
                   f2b(fmaxf(g * v0 + omg * blo(xo.x), 0.f)),
            ((uint)f2b(fmaxf(g * v3 + omg * bhi(xo.y), 0.f)) << 16) |
                   f2b(fmaxf(g * v2 + omg * blo(xo.y), 0.f)));
        *(uint2*)&((ushort*)sg.out)[a_packed_us(rr, cb)] = o;
      } else if (epi == 4) {
        uint2 o = make_uint2(((uint)f2b(v1) << 16) | f2b(v0),
                             ((uint)f2b(v3) << 16) | f2b(v2));
        *(uint2*)&((ushort*)sg.out)[a_packed_us(rr, cb)] = o;
        int kin = cl & 31;
        int sw2 = (kin >> 3) ^ ((prow >> 1) & 3);
        *(uint2*)&Xs[(cl >> 5) * 2048 + prow * 32 + sw2 * 8 + (kin & 7)] = o;
      } else {  // 5: skip-relu into Xs only
        uint2 xo = *(const uint2*)&sg.xsP[a_packed_us(rr, cb)];
        uint2 o = make_uint2(
            ((uint)f2b(fmaxf(g * v1 + omg * bhi(xo.x), 0.f)) << 16) |
                   f2b(fmaxf(g * v0 + omg * blo(xo.x), 0.f)),
            ((uint)f2b(fmaxf(g * v3 + omg * bhi(xo.y), 0.f)) << 16) |
                   f2b(fmaxf(g * v2 + omg * blo(xo.y), 0.f)));
        int kin = cl & 31;
        int sw2 = (kin >> 3) ^ ((prow >> 1) & 3);
        *(uint2*)&Xs[(cl >> 5) * 2048 + prow * 32 + sw2 * 8 + (kin & 7)] = o;
      }
    }
  }

  // ---------------- stage 2: flat pipeline over n2*4 k-steps ----------------
  if (sg.n2 == 0) return;
  __syncthreads();   // Xs + first B2 tile ready
  int total2 = sg.n2 * 4;
  floatx4 a2[4][2];
#pragma unroll
  for (int i = 0; i < 4; ++i)
#pragma unroll
    for (int j = 0; j < 2; ++j) a2[i][j] = (floatx4){0.f, 0.f, 0.f, 0.f};
  for (int s2 = 0; s2 < total2; ++s2) {
    int buf = s2 & 1;
    if (s2 + 1 < total2) stage2L(s2 + 1, buf ^ 1);
    int xb = (s2 & 3) * 2048;
    short8 af[4], bfr[2];
#pragma unroll
    for (int i = 0; i < 4; ++i)
      af[i] = *(const short8*)&Xs[xb + (i * 16 + l16) * 32 + swz];
#pragma unroll
    for (int n = 0; n < 2; ++n)
      bfr[n] = *(const short8*)&lds[buf * 4096 + (wn + n * 16 + l16) * 32 + swz];
#pragma unroll
    for (int mi = 0; mi < 4; ++mi)
#pragma unroll
      for (int ni = 0; ni < 2; ++ni)
        a2[mi][ni] = __builtin_amdgcn_mfma_f32_16x16x32_bf16(
            bfr[ni], af[mi], a2[mi][ni], 0, 0, 0);
    __syncthreads();
    if ((s2 & 3) == 3) {
      int t2 = s2 >> 2;
#pragma unroll
      for (int ni = 0; ni < 2; ++ni) {
        int cb2 = t2 * 128 + wn + ni * 16 + quad * 4;
        float4 b4 = *(const float4*)&sg.bias2[cb2];
#pragma unroll
        for (int mi = 0; mi < 4; ++mi) {
          int rr = tm * 128 + hm * 64 + mi * 16 + l16;
          float v0 = a2[mi][ni][0] + b4.x;
          float v1 = a2[mi][ni][1] + b4.y;
          float v2 = a2[mi][ni][2] + b4.z;
          float v3 = a2[mi][ni][3] + b4.w;
          if (sg.epi2 == 0) {
            uint2 o = make_uint2(((uint)f2b(v1) << 16) | f2b(v0),
                                 ((uint)f2b(v3) << 16) | f2b(v2));
            *(uint2*)&((ushort*)sg.out2)[(size_t)rr * sg.ldo2 + cb2] = o;
          } else {
            if (rr < sg.Mreal2)
              *(float4*)&((float*)sg.out2)[(size_t)rr * sg.ldo2 + cb2] =
                  make_float4(v0, v1, v2, v3);
          }
          a2[mi][ni] = (floatx4){0.f, 0.f, 0.f, 0.f};
        }
      }
    }
  }
}

// ================= gather: one wave per dst node, 2x4 edges/iter ==========
// (measured-best 8-edge form: VGPR 32, occupancy ~70%)
struct GatherType { const ushort* q; ushort* agg; int ldq; };
struct GatherDesc { GatherType ty[3]; int n0, n1; };

__launch_bounds__(256)
__global__ void gather_all(const int* __restrict__ starts,
                           const uint* __restrict__ payload,
                           const ushort* __restrict__ kvbase,
                           GatherDesc gd, int Ntot)
{
  int wid = (blockIdx.x * 256 + threadIdx.x) >> 6;
  if (wid >= Ntot) return;
  int lane = threadIdx.x & 63;
  int g = lane >> 4, l = lane & 15;

  GatherType T;
  int d;
  if (wid < gd.n0)      { T = gd.ty[0]; d = wid; }
  else if (wid < gd.n1) { T = gd.ty[1]; d = wid - gd.n0; }
  else                  { T = gd.ty[2]; d = wid - gd.n1; }

  const char* kvb = (const char*)kvbase;
  const uint lofs = (uint)l * 16u;

  uint4 qv = *(const uint4*)(T.q + (size_t)d * T.ldq + l * 8);
  f32x2 q0 = b2x2(qv.x), q1 = b2x2(qv.y), q2 = b2x2(qv.z), q3 = b2x2(qv.w);

  int e0 = starts[wid], e1 = starts[wid + 1];
  float lsum = 0.f;
  f32x2 ac0 = {0.f, 0.f}, ac1 = {0.f, 0.f}, ac2 = {0.f, 0.f}, ac3 = {0.f, 0.f};

  for (int eb = e0; eb < e1; eb += 8) {
    int eA = eb + g, eB = eA + 4;
    bool actA = eA < e1, actB = eB < e1;
    uint pA = payload[actA ? eA : e0];
    uint pB = payload[actB ? eB : e0];
    const char* bA = kvb + (pA + lofs);
    const char* bB = kvb + (pB + lofs);
    uint4 kA = *(const uint4*)bA;
    uint4 vA = *(const uint4*)(bA + 256);
    uint4 kB = *(const uint4*)bB;
    uint4 vB = *(const uint4*)(bB + 256);

    f32x2 dA = q0 * b2x2(kA.x);
    dA = __builtin_elementwise_fma(q1, b2x2(kA.y), dA);
    dA = __builtin_elementwise_fma(q2, b2x2(kA.z), dA);
    dA = __builtin_elementwise_fma(q3, b2x2(kA.w), dA);
    f32x2 dB = q0 * b2x2(kB.x);
    dB = __builtin_elementwise_fma(q1, b2x2(kB.y), dB);
    dB = __builtin_elementwise_fma(q2, b2x2(kB.z), dB);
    dB = __builtin_elementwise_fma(q3, b2x2(kB.w), dB);
    float pa = dA.x + dA.y;
    float pb = dB.x + dB.y;
    pa += __shfl_xor(pa, 1, 64);
    pb += __shfl_xor(pb, 1, 64);
    float exA = exp2f(fminf(pa, 115.4f));
    float exB = exp2f(fminf(pb, 115.4f));
    exA = actA ? exA : 0.f;
    exB = actB ? exB : 0.f;
    lsum += exA + exB;
    f32x2 xA = {exA, exA}, xB = {exB, exB};
    ac0 = __builtin_elementwise_fma(xA, b2x2(vA.x), ac0);
    ac1 = __builtin_elementwise_fma(xA, b2x2(vA.y), ac1);
    ac2 = __builtin_elementwise_fma(xA, b2x2(vA.z), ac2);
    ac3 = __builtin_elementwise_fma(xA, b2x2(vA.w), ac3);
    ac0 = __builtin_elementwise_fma(xB, b2x2(vB.x), ac0);
    ac1 = __builtin_elementwise_fma(xB, b2x2(vB.y), ac1);
    ac2 = __builtin_elementwise_fma(xB, b2x2(vB.z), ac2);
    ac3 = __builtin_elementwise_fma(xB, b2x2(vB.w), ac3);
  }

  float s0 = ac0.x, s1 = ac0.y, s2 = ac1.x, s3 = ac1.y;
  float s4 = ac2.x, s5 = ac2.y, s6 = ac3.x, s7 = ac3.y;
#define MRG(v) v += __shfl_xor(v, 16, 64); v += __shfl_xor(v, 32, 64)
  MRG(lsum); MRG(s0); MRG(s1); MRG(s2); MRG(s3); MRG(s4); MRG(s5); MRG(s6); MRG(s7);
#undef MRG

  // each lane finishes channels c0 = 8*l + 2*g and c0+1
  float inv = 1.f / (lsum + 1e-16f);
  float m0 = (g & 1) ? s2 : s0, m1 = (g & 1) ? s6 : s4;
  float n0 = (g & 1) ? s3 : s1, n1 = (g & 1) ? s7 : s5;
  float x0 = ((g & 2) ? m1 : m0) * inv;
  float x1 = ((g & 2) ? n1 : n0) * inv;
  float g0 = 0.5f * x0 * (1.f + erff(x0 * 0.70710678118654752f));
  float g1 = 0.5f * x1 * (1.f + erff(x1 * 0.70710678118654752f));
  int tm = d >> 7, row = d & 127;
  int tk = l >> 2, sw = (l & 3) ^ ((row >> 1) & 3);
  size_t us = (((size_t)tm * 4 + tk) * 512 + (size_t)row * 4 + sw) * 8 + 2 * g;
  *(uint*)(T.agg + us) = ((uint)f2b(g1) << 16) | (uint)f2b(g0);
}

// ================= host =====================================================
extern "C" void kernel_launch(void* const* d_in, const int* in_sizes, int n_in,
                              void* d_out, int out_size, void* d_ws, size_t ws_size,
                              hipStream_t stream)
{
  const float* x_herb = (const float*)d_in[0];
  const float* x_ing  = (const float*)d_in[1];
  const float* x_tgt  = (const float*)d_in[2];
  const float* W_herb = (const float*)d_in[3];
  const float* b_herb = (const float*)d_in[4];
  const float* W_ing  = (const float*)d_in[5];
  const float* b_ing  = (const float*)d_in[6];
  const float* W_tgt  = (const float*)d_in[7];
  const float* b_tgt  = (const float*)d_in[8];
  const float* Wk     = (const float*)d_in[9];
  const float* bk     = (const float*)d_in[10];
  const float* Wq     = (const float*)d_in[11];
  const float* bq     = (const float*)d_in[12];
  const float* Wv     = (const float*)d_in[13];
  const float* bv     = (const float*)d_in[14];
  const float* a_rel  = (const float*)d_in[15];
  const float* m_rel  = (const float*)d_in[16];
  const float* p_rel  = (const float*)d_in[17];
  const float* Wa     = (const float*)d_in[18];
  const float* ba     = (const float*)d_in[19];
  const float* skip   = (const float*)d_in[20];
  const float* W_out  = (const float*)d_in[21];
  const float* b_out  = (const float*)d_in[22];
  const int* srcs[4] = {(const int*)d_in[23], (const int*)d_in[25],
                        (const int*)d_in[27], (const int*)d_in[29]};
  const int* dsts[4] = {(const int*)d_in[24], (const int*)d_in[26],
                        (const int*)d_in[28], (const int*)d_in[30]};

  const int Nh = in_sizes[0] / 400;
  const int Ni = in_sizes[1] / 300;
  const int Nt = in_sizes[2] / 200;
  const int E  = in_sizes[23];
  const int Ntot = Nh + Ni + Nt;

  const int MT_h = (Nh + 127) / 128, MT_i = (Ni + 127) / 128, MT_t = (Nt + 127) / 128;
  const int KT_h = 13, KT_i = 10, KT_t = 7;   // Kpad 416/320/224

  // CSR sort params
  const int NBs = (E + CSR_CH - 1) / CSR_CH;
  const int NBH = 4 * NBs;
  const int NBK = (Ntot + (1 << CSR_SH) - 1) >> CSR_SH;   // <= 511

  char* base = (char*)d_ws;
  size_t off = 0;
  auto A = [&](size_t bytes) -> void* {
    void* p = base + off; off += (bytes + 255) & ~(size_t)255; return p;
  };
  ushort* xp_h  = (ushort*)A((size_t)MT_h * KT_h * 8192);
  ushort* xp_i  = (ushort*)A((size_t)MT_i * KT_i * 8192);
  ushort* xp_t  = (ushort*)A((size_t)MT_t * KT_t * 8192);
  ushort* xsP_h = (ushort*)A((size_t)MT_h * 4 * 8192);
  ushort* xsP_i = (ushort*)A((size_t)MT_i * 4 * 8192);
  ushort* xsP_t = (ushort*)A((size_t)MT_t * 4 * 8192);
  ushort* fused_h = (ushort*)A((size_t)MT_h * 128 * 384 * 2);  // [q|k0|v0]
  ushort* fused_i = (ushort*)A((size_t)MT_i * 128 * 640 * 2);  // [q|k1|v1|k2|v2]
  ushort* fused_t = (ushort*)A((size_t)MT_t * 128 * 384 * 2);  // [q|k3|v3]
  ushort* aggp_h  = (ushort*)A((size_t)MT_h * 4 * 8192);
  ushort* aggp_i  = (ushort*)A((size_t)MT_i * 4 * 8192);
  ushort* aggp_t  = (ushort*)A((size_t)MT_t * 4 * 8192);
  ushort* Weff1_h = (ushort*)A((size_t)KT_h * 8192);
  ushort* Weff1_i = (ushort*)A((size_t)KT_i * 8192);
  ushort* Weff1_t = (ushort*)A((size_t)KT_t * 8192);
  ushort* Wcat_h = (ushort*)A((size_t)3 * 4 * 8192);
  ushort* Wcat_i = (ushort*)A((size_t)5 * 4 * 8192);
  ushort* Wcat_t = (ushort*)A((size_t)3 * 4 * 8192);
  float* bcat   = (float*)A(1408 * 4);
  ushort* Wa_t   = (ushort*)A((size_t)3 * 16384 * 2);
  ushort* Wout_t = (ushort*)A((size_t)16384 * 2);
  int* starts  = (int*)A((size_t)(Ntot + 4) * 4);
  uint* payload = (uint*)A((size_t)(4 * E + 8) * 4);
  uint* hist    = (uint*)A((size_t)NBK * NBH * 4);
  uint* bucketTot  = (uint*)A((size_t)NBK * 4);
  uint2* inter  = (uint2*)A((size_t)(4 * E + 8) * 8);
  (void)ws_size; (void)n_in;

  const int toff_h = 0, toff_i = Nh, toff_t = Nh + Ni;
  dim3 blk(256);

  uint fi2 = (uint)((size_t)(fused_i - fused_h) * 2);
  uint ft2 = (uint)((size_t)(fused_t - fused_h) * 2);

  // --- 1: prologue (pack x3 + combine_rel + all weight prep + edge hist) ---
  int sl_h = MT_h * KT_h * 512, sl_i = MT_i * KT_i * 512, sl_t = MT_t * KT_t * 512;
  Prolog P;
  P.pk[0] = {x_herb, xp_h, Nh, 400, KT_h, 0};
  P.pk[1] = {x_ing,  xp_i, Ni, 300, KT_i, sl_h};
  P.pk[2] = {x_tgt,  xp_t, Nt, 200, KT_t, sl_h + sl_i};
  P.crwstart = sl_h + sl_i + sl_t;
  P.wstart = P.crwstart + 4 * 2 * 129 * 128;
  {
    const float* wsrc10[10] = {W_herb, W_ing, W_tgt, Wq, Wq + 16384, Wq + 32768,
                               Wa, Wa + 16384, Wa + 32768, W_out};
    ushort* wdst10[10] = {Weff1_h, Weff1_i, Weff1_t, Wcat_h, Wcat_i, Wcat_t,
                          Wa_t, Wa_t + 16384, Wa_t + 32768, Wout_t};
    int wk10[10] = {400, 300, 200, 128, 128, 128, 128, 128, 128, 128};
    int wcum = 0;
    for (int z = 0; z < 10; ++z) {
      P.wb[z] = {wsrc10[z], wdst10[z], wk10[z], wcum};
      wcum += ((wk10[z] + 31) / 32) * 512;
    }
    P.bstart = P.wstart + wcum;
  }
  P.total = P.bstart + 384;
  P.Wk = Wk; P.bk = bk; P.Wv = Wv; P.bv = bv;
  P.a_rel = a_rel; P.m_rel = m_rel; P.p_rel = p_rel;
  P.kw_dst[0] = Wcat_h + 16384; P.vw_dst[0] = Wcat_h + 32768;
  P.kw_dst[1] = Wcat_i + 16384; P.vw_dst[1] = Wcat_i + 32768;
  P.kw_dst[2] = Wcat_i + 49152; P.vw_dst[2] = Wcat_i + 65536;
  P.kw_dst[3] = Wcat_t + 16384; P.vw_dst[3] = Wcat_t + 32768;
  P.bcat = bcat;
  P.kb_off[0] = 128;  P.vb_off[0] = 256;
  P.kb_off[1] = 512;  P.vb_off[1] = 640;
  P.kb_off[2] = 768;  P.vb_off[2] = 896;
  P.kb_off[3] = 1152; P.vb_off[3] = 1280;
  P.bq = bq;
  P.bq_off[0] = 0; P.bq_off[1] = 384; P.bq_off[2] = 1024;
  P.edst[0] = dsts[0]; P.eoff[0] = toff_i;
  P.edst[1] = dsts[1]; P.eoff[1] = toff_h;
  P.edst[2] = dsts[2]; P.eoff[2] = toff_t;
  P.edst[3] = dsts[3]; P.eoff[3] = toff_i;
  P.hist = hist; P.NBs = NBs; P.NBH = NBH; P.NBK = NBK; P.E = E;
  prologue<<<NBH + (P.total + 255) / 256, blk, 0, stream>>>(P);

  // --- 2: CSR build (scan -> scatter -> finalize) ---
  EdgeStreams ES;
  ES.src[0] = srcs[0]; ES.dst[0] = dsts[0]; ES.off[0] = toff_i;
  ES.rel[0] = 256u;        ES.ldb[0] = 768u;
  ES.src[1] = srcs[1]; ES.dst[1] = dsts[1]; ES.off[1] = toff_h;
  ES.rel[1] = fi2 + 256u;  ES.ldb[1] = 1280u;
  ES.src[2] = srcs[2]; ES.dst[2] = dsts[2]; ES.off[2] = toff_t;
  ES.rel[2] = fi2 + 768u;  ES.ldb[2] = 1280u;
  ES.src[3] = srcs[3]; ES.dst[3] = dsts[3]; ES.off[3] = toff_i;
  ES.rel[3] = ft2 + 256u;  ES.ldb[3] = 768u;
  bucket_scan<<<NBK, blk, 0, stream>>>(hist, bucketTot, NBH);
  bucket_scatter<<<NBH, blk, 0, stream>>>(ES, hist, bucketTot, inter, NBs, NBH, NBK, E);
  bucket_finalize<<<NBK, blk, 0, stream>>>(inter, bucketTot, starts, payload, Ntot, NBK);

  // --- 3: K1 = GEMM1 + GEMM2 fused, 64-row blocks (grid = 2x tiles) ---
  Gemm3 G1;
  G1.skip = skip; G1.nseg = 3;
  G1.s[0] = {xp_h, Weff1_h, b_herb, xsP_h, nullptr, KT_h, 0, 0, 0, 4, 1, 0,
             3, Wcat_h, bcat + 0, fused_h, 384, 0, 0};
  G1.s[1] = {xp_i, Weff1_i, b_ing,  xsP_i, nullptr, KT_i, 0, 0, 0, 4, 1, 2 * MT_h,
             5, Wcat_i, bcat + 384, fused_i, 640, 0, 0};
  G1.s[2] = {xp_t, Weff1_t, b_tgt,  xsP_t, nullptr, KT_t, 0, 0, 0, 4, 1,
             2 * (MT_h + MT_i),
             3, Wcat_t, bcat + 1024, fused_t, 384, 0, 0};
  gemm_sched<<<2 * (MT_h + MT_i + MT_t), blk, 0, stream>>>(G1);

  // --- 4: gather attention (all types, one wave per node) ---
  GatherDesc GD;
  GD.n0 = Nh; GD.n1 = Nh + Ni;
  GD.ty[0] = {fused_h, aggp_h, 384};
  GD.ty[1] = {fused_i, aggp_i, 640};
  GD.ty[2] = {fused_t, aggp_t, 384};
  gather_all<<<(Ntot + 3) / 4, blk, 0, stream>>>(starts, payload, fused_h, GD, Ntot);

  // --- 5: K2 = epilogue GEMMs, 64-row blocks; herb chains W_out from LDS ---
  float* outp = (float*)d_out;
  float* out_herb = outp;
  float* out_ing  = outp + (size_t)Nh * HID;
  float* out_tgt  = outp + (size_t)(Nh + Ni) * HID;
  Gemm3 GE;
  GE.skip = skip; GE.nseg = 3;
  GE.s[0] = {aggp_h, Wa_t + 0 * 16384, ba + 0 * 128, nullptr, xsP_h,
             4, 0, 0, 0, 5, 1, 0,
             1, Wout_t, b_out, out_herb, 128, Nh, 1};
  GE.s[1] = {aggp_i, Wa_t + 1 * 16384, ba + 1 * 128, out_ing, xsP_i,
             4, 128, Ni, 1, 2, 1, 2 * MT_h,
             0, nullptr, nullptr, nullptr, 0, 0, 0};
  GE.s[2] = {aggp_t, Wa_t + 2 * 16384, ba + 2 * 128, out_tgt, xsP_t,
             4, 128, Nt, 2, 2, 1, 2 * (MT_h + MT_i),
             0, nullptr, nullptr, nullptr, 0, 0, 0};
  gemm_sched<<<2 * (MT_h + MT_i + MT_t), blk, 0, stream>>>(GE);
  (void)out_size;
}

// Round 7
// 367.316 us; speedup vs baseline: 1.2542x; 1.0315x over previous
//
#include <hip/hip_runtime.h>
#include <math.h>

#define HID 128
typedef unsigned int uint;
typedef unsigned short ushort;
typedef __attribute__((ext_vector_type(8))) short short8;
typedef __attribute__((ext_vector_type(4))) float floatx4;
typedef __attribute__((ext_vector_type(2))) float f32x2;

// ---------- bf16 helpers ----------
__device__ __forceinline__ ushort f2b(float f) {
  uint u = __float_as_uint(f);
  u += 0x7fffu + ((u >> 16) & 1u);
  return (ushort)(u >> 16);
}
__device__ __forceinline__ float b2f(ushort s) {
  return __uint_as_float(((uint)s) << 16);
}
__device__ __forceinline__ float blo(uint u) { return __uint_as_float(u << 16); }
__device__ __forceinline__ float bhi(uint u) { return __uint_as_float(u & 0xffff0000u); }
__device__ __forceinline__ f32x2 b2x2(uint u) {
  f32x2 r;
  r.x = __uint_as_float(u << 16);
  r.y = __uint_as_float(u & 0xffff0000u);
  return r;
}

__device__ __forceinline__ void gll16(const ushort* g, ushort* l) {
  __builtin_amdgcn_global_load_lds(
      (const __attribute__((address_space(1))) void*)g,
      (__attribute__((address_space(3))) void*)l, 16, 0, 0);
}

// Packed tile layout (128 rows x 32 k, bf16), 16B slot within tile:
//   slot = row*4 + (chunk ^ ((row>>1)&3)), chunk = k/8. Conflict-free staging+frags.
//   Rows [0,64) of a tile occupy the first 4096B contiguously (64-row halves
//   are independently addressable).
__device__ __forceinline__ size_t a_packed_us(int rr, int col) {
  int tm = rr >> 7, prow = rr & 127;
  int ptk = col >> 5, kin = col & 31;
  int sw = (kin >> 3) ^ ((prow >> 1) & 3);
  return (((size_t)tm * 4 + ptk) * 512 + (size_t)prow * 4 + sw) * 8 + (kin & 7);
}

// ================= CSR params ==============================================
#define CSR_CH 2048   // edges per block in hist/scatter passes
#define CSR_SH 9      // 512 nodes per bucket

struct EdgeStreams {
  const int* src[4]; const int* dst[4];
  int off[4]; uint rel[4]; uint ldb[4];
};

// ================= prologue: combine_rel + weight prep + hist ===============
// (x-packing is now fused into K1's A-staging)
struct WBlk { const float* src; ushort* dst; int K; int start; };
struct Prolog {
  int wstart, bstart, total;
  const float *Wk, *bk, *Wv, *bv, *a_rel, *m_rel, *p_rel;
  ushort* kw_dst[4];
  ushort* vw_dst[4];
  float* bcat;
  int kb_off[4], vb_off[4];
  WBlk wb[10];
  const float* bq;
  int bq_off[3];
  // edge-hist segment (block-granular, blocks [0, NBH))
  const int* edst[4];
  int eoff[4];
  uint* hist;       // transposed: hist[bucket][block]
  int NBs, NBH, NBK, E;
};

// combine_rel: Wk_rel[e] = Wk[i] @ a_rel[e] (and Wv/m_rel), written DIRECTLY in
// packed-B bf16 layout. p_rel[e,h]/sqrt(D)*log2(e) is baked into the k weights
// and bias so the gather's logit feeds exp2 with no per-edge scale.
__device__ void combine_rel_elem(const Prolog& P, int idx)
{
  int col  = idx & 127;
  int rest = idx >> 7;
  int row  = rest % 129;
  rest /= 129;
  int kv = rest & 1;
  int e  = rest >> 1;
  int i  = (e + 1) >> 1;           // styp = {0,1,1,2}
  int h = col >> 4, j = col & 15;
  const float* Wsrc = kv ? P.Wv : P.Wk;
  const float* bsrc = kv ? P.bv : P.bk;
  const float* rel  = kv ? P.m_rel : P.a_rel;
  float acc = 0.f;
  if (row < 128) {
#pragma unroll
    for (int d = 0; d < 16; ++d)
      acc += Wsrc[(size_t)i * 16384 + (size_t)row * 128 + h * 16 + d] *
             rel[((e * 8 + h) * 16 + d) * 16 + j];
  } else {
#pragma unroll
    for (int d = 0; d < 16; ++d)
      acc += bsrc[i * 128 + h * 16 + d] * rel[((e * 8 + h) * 16 + d) * 16 + j];
  }
  if (!kv) acc *= P.p_rel[e * 8 + h] * 0.36067376022224085f;  // 0.25 * log2(e)
  if (row < 128) {
    ushort* dst = kv ? P.vw_dst[e] : P.kw_dst[e];
    int tk = row >> 5, chunk = (row >> 3) & 3, m = row & 7;
    int swf = chunk ^ ((col >> 1) & 3);
    dst[((tk * 512 + col * 4 + swf) << 3) + m] = f2b(acc);
  } else {
    P.bcat[(kv ? P.vb_off[e] : P.kb_off[e]) + col] = acc;
  }
}

// pure layout conversion of row-major fp32 [K][128] weights to packed-B bf16
__device__ void conv_elem(const Prolog& P, int s0)
{
  int si = 0;
#pragma unroll
  for (int k = 1; k < 10; ++k)
    if (s0 >= P.wb[k].start) si = k;
  WBlk b = P.wb[si];
  int s = s0 - b.start;
  int tk = s >> 9, o = s & 511;
  int c = o >> 2, swf = o & 3;
  int chunk = swf ^ ((c >> 1) & 3);
  int r0 = tk * 32 + chunk * 8;
  ushort tmp[8];
#pragma unroll
  for (int m = 0; m < 8; ++m) {
    int r = r0 + m;
    tmp[m] = (r < b.K) ? f2b(b.src[(size_t)r * 128 + c]) : (ushort)0;
  }
  *(short8*)&b.dst[(size_t)s * 8] = *(short8*)tmp;
}

__global__ __launch_bounds__(256)
void prologue(Prolog P)
{
  __shared__ uint h[512];
  int bI = blockIdx.x;
  if (bI < P.NBH) {
    // --- edge histogram segment (block-granular) ---
    int et = bI / P.NBs;
    int i0 = (bI - et * P.NBs) * CSR_CH;
    const int* dp = P.edst[et];
    int off = P.eoff[et];
    for (int t = threadIdx.x; t < P.NBK; t += 256) h[t] = 0;
    __syncthreads();
#pragma unroll
    for (int j = 0; j < CSR_CH / 256; ++j) {
      int idx = i0 + j * 256 + threadIdx.x;
      if (idx < P.E) atomicAdd(&h[(uint)(off + dp[idx]) >> CSR_SH], 1u);
    }
    __syncthreads();
    for (int t = threadIdx.x; t < P.NBK; t += 256)
      P.hist[(size_t)t * P.NBH + bI] = h[t];
    return;
  }
  int gtid = (bI - P.NBH) * 256 + threadIdx.x;
  if (gtid >= P.total) return;
  if (gtid >= P.bstart) {
    int j = gtid - P.bstart;
    P.bcat[P.bq_off[j >> 7] + (j & 127)] = P.bq[j];
    return;
  }
  if (gtid >= P.wstart) { conv_elem(P, gtid - P.wstart); return; }
  combine_rel_elem(P, gtid);
}

// ================= CSR build: two-level counting sort =======================
__global__ __launch_bounds__(256)
void bucket_scan(uint* __restrict__ hist, uint* __restrict__ bucketTot, int NBH)
{
  __shared__ uint ws[4];
  __shared__ uint carry_s;
  int b = blockIdx.x;
  int t = threadIdx.x, lane = t & 63, w = t >> 6;
  if (t == 0) carry_s = 0;
  __syncthreads();
  for (int base = 0; base < NBH; base += 256) {
    int i = base + t;
    uint x = (i < NBH) ? hist[(size_t)b * NBH + i] : 0u;
    uint v = x;
#pragma unroll
    for (int o = 1; o < 64; o <<= 1) {
      uint y = __shfl_up(v, o, 64);
      if (lane >= o) v += y;
    }
    if (lane == 63) ws[w] = v;
    __syncthreads();
    uint add = carry_s;
    for (int k = 0; k < w; ++k) add += ws[k];
    if (i < NBH) hist[(size_t)b * NBH + i] = add + v - x;
    __syncthreads();
    if (t == 255) carry_s = add + v;
    __syncthreads();
  }
  if (t == 0) bucketTot[b] = carry_s;
}

// local exclusive scan of bucketTot (<=512 entries) into sb[]; 2 slots/thread
__device__ __forceinline__ void base_scan(const uint* __restrict__ bucketTot,
                                          uint* sb, uint* ws, int NBK)
{
  int t = threadIdx.x, lane = t & 63, w = t >> 6;
  sb[t] = (t < NBK) ? bucketTot[t] : 0u;
  sb[t + 256] = (t + 256 < NBK) ? bucketTot[t + 256] : 0u;
  __syncthreads();
  uint a0 = sb[2 * t], a1 = sb[2 * t + 1];
  uint s = a0 + a1;
  uint v = s;
#pragma unroll
  for (int o = 1; o < 64; o <<= 1) {
    uint y = __shfl_up(v, o, 64);
    if (lane >= o) v += y;
  }
  if (lane == 63) ws[w] = v;
  __syncthreads();
  uint add = 0;
  for (int k = 0; k < w; ++k) add += ws[k];
  uint e0 = add + v - s;
  sb[2 * t] = e0;
  sb[2 * t + 1] = e0 + a0;
  __syncthreads();
}

// Pass C: scatter (payload, dst) into bucket-contiguous intermediate
__global__ __launch_bounds__(256)
void bucket_scatter(EdgeStreams es, const uint* __restrict__ hist,
                    const uint* __restrict__ bucketTot,
                    uint2* __restrict__ inter, int NBs, int NBH, int NBK, int E)
{
  __shared__ uint sb[516];
  __shared__ uint ws[4];
  __shared__ uint cur[512];
  base_scan(bucketTot, sb, ws, NBK);
  int b = blockIdx.x;
  int et = b / NBs;
  int i0 = (b - et * NBs) * CSR_CH;
  const int* dp = es.dst[et];
  const int* sp = es.src[et];
  int off = es.off[et];
  uint rel = es.rel[et], ldb = es.ldb[et];
  for (int t = threadIdx.x; t < NBK; t += 256)
    cur[t] = sb[t] + hist[(size_t)t * NBH + b];
  __syncthreads();
#pragma unroll
  for (int j = 0; j < CSR_CH / 256; ++j) {
    int idx = i0 + j * 256 + threadIdx.x;
    if (idx < E) {
      int g = off + dp[idx];
      uint pos = atomicAdd(&cur[(uint)g >> CSR_SH], 1u);
      inter[pos] = make_uint2(rel + (uint)sp[idx] * ldb, (uint)g);
    }
  }
}

// Pass D: one block per bucket; per-node count+scan in LDS, write starts and
// final payload into this block's contiguous region (single-writer lines).
__global__ __launch_bounds__(256)
void bucket_finalize(const uint2* __restrict__ inter,
                     const uint* __restrict__ bucketTot,
                     int* __restrict__ starts, uint* __restrict__ payload,
                     int Ntot, int NBK)
{
  __shared__ uint sb[516];
  __shared__ uint ncnt[512];
  __shared__ uint ws[4];
  base_scan(bucketTot, sb, ws, NBK);
  int b = blockIdx.x;
  int g0 = b << CSR_SH;
  int t = threadIdx.x, lane = t & 63, w = t >> 6;
  uint r0 = sb[b], r1 = sb[b + 1];
  if (b == NBK - 1 && t == 0) starts[Ntot] = (int)r1;
  ncnt[t] = 0; ncnt[t + 256] = 0;
  __syncthreads();
  for (uint i = r0 + t; i < r1; i += 256)
    atomicAdd(&ncnt[inter[i].y - g0], 1u);
  __syncthreads();
  uint a0 = ncnt[2 * t], a1 = ncnt[2 * t + 1];
  uint s = a0 + a1;
  uint v = s;
#pragma unroll
  for (int o = 1; o < 64; o <<= 1) {
    uint y = __shfl_up(v, o, 64);
    if (lane >= o) v += y;
  }
  if (lane == 63) ws[w] = v;
  __syncthreads();
  uint add = r0;
  for (int k = 0; k < w; ++k) add += ws[k];
  uint e0 = add + v - s;
  int gi = g0 + 2 * t;
  if (gi < Ntot)     starts[gi]     = (int)e0;
  if (gi + 1 < Ntot) starts[gi + 1] = (int)(e0 + a0);
  ncnt[2 * t] = e0;          // reuse as cursors
  ncnt[2 * t + 1] = e0 + a0;
  __syncthreads();
  for (uint i = r0 + t; i < r1; i += 256) {
    uint2 rec = inter[i];
    uint pos = atomicAdd(&ncnt[rec.y - g0], 1u);
    payload[pos] = rec.x;
  }
}

// ================= fused multi-segment MFMA GEMM (two-stage, 64-row) =======
// Each block owns a 64-row half of a packed 128-row M-tile. 4 waves along N.
// TRANSPOSED mfma: lane's 4 acc regs = 4 consecutive output columns.
// A-staging: if Af != nullptr, stage A directly from fp32 row-major [Mf][Kf]
// (reg-stage: 8 floats -> cvt bf16 -> ds_write_b128 into the packed-swizzled
// slot; thread t owns slot t of the 64x32 half). This fuses the x-pack into
// the GEMM. Else gll16 from pre-packed sg.A.
// epi: 0 bf16 row-major unguarded; 1 fp32 guarded; 2 skip-relu fp32 guarded;
//      3 skip-relu bf16 packed; 4 plain bf16 packed (+Xs stash if n2>0);
//      5 skip-relu -> Xs ONLY (feeds stage 2)
// Stage 2 (n2>0): flat dbuf pipeline over n2*4 k-steps of Xs(64x128) @ B2.
// LDS 40KB: [0,8KB) A dbuf | [8KB,24KB) B dbuf | [24KB,40KB) Xs;
// stage-2 B2 dbuf (16KB) aliases [0,16KB).
struct GemmSeg {
  const ushort* A; const ushort* B; const float* bias;
  void* out; const ushort* xsP;
  int Ktiles, ldo, Mreal, skip_idx, epi, NT, start;
  int n2; const ushort* B2; const float* bias2;
  void* out2; int ldo2, Mreal2, epi2;
  const float* Af; int Kf, Mf;
};
struct Gemm3 { GemmSeg s[3]; const float* skip; int nseg; };

__launch_bounds__(256)
__global__ void gemm_sched(Gemm3 g3)
{
  __shared__ __align__(16) ushort lds[20480];
  ushort* Xs = lds + 12288;    // 64x128 packed (4 k-chunks x 2048 ushorts)

  int bid = blockIdx.x;
  int si = 0;
  if (g3.nseg > 1 && bid >= g3.s[1].start)
    si = (g3.nseg > 2 && bid >= g3.s[2].start) ? 2 : 1;
  const GemmSeg sg = g3.s[si];
  int local = bid - sg.start;
  int tmH = local / sg.NT, tn = local - tmH * sg.NT;
  int tm = tmH >> 1, hm = tmH & 1;

  const int t = threadIdx.x;
  const int wave = t >> 6, lane = t & 63;
  const int wn = wave * 32;
  const int l16 = lane & 15, quad = lane >> 4;
  const int Ktiles = sg.Ktiles;
  const int swz = (quad ^ ((l16 >> 1) & 3)) * 8;

  const ushort* Ahalf = sg.A + ((size_t)tm * Ktiles) * 4096 + hm * 2048;
  const ushort* Bbase = sg.B + (size_t)tn * Ktiles * 4096;

  // f32 A-staging decode: thread t owns packed slot t of the 64x32 half
  const int aprow = t >> 2, asw = t & 3;
  const int achunk = asw ^ ((aprow >> 1) & 3);
  const int agrow = tm * 128 + hm * 64 + aprow;
  const bool arowok = (sg.Af == nullptr) || (agrow < sg.Mf);
  const float* axrow = sg.Af + (size_t)(arowok ? agrow : 0) * sg.Kf;

  floatx4 acc[4][2];
#pragma unroll
  for (int i = 0; i < 4; ++i)
#pragma unroll
    for (int j = 0; j < 2; ++j) acc[i][j] = (floatx4){0.f, 0.f, 0.f, 0.f};

  auto stageA = [&](int tk, int buf) {
    if (sg.Af == nullptr) {
      // packed path: 4 chunks, one per wave
      gll16(Ahalf + (size_t)tk * 4096 + wave * 512 + lane * 8,
            lds + buf * 2048 + wave * 512);
    } else {
      int gk = tk * 32 + achunk * 8;
      ushort tmp[8];
      if (arowok && gk + 8 <= sg.Kf) {
        const float* p = axrow + gk;
        float4 a = *(const float4*)p, b = *(const float4*)(p + 4);
        tmp[0] = f2b(a.x); tmp[1] = f2b(a.y); tmp[2] = f2b(a.z); tmp[3] = f2b(a.w);
        tmp[4] = f2b(b.x); tmp[5] = f2b(b.y); tmp[6] = f2b(b.z); tmp[7] = f2b(b.w);
      } else {
#pragma unroll
        for (int j = 0; j < 8; ++j) {
          int kk = gk + j;
          tmp[j] = (arowok && kk < sg.Kf) ? f2b(axrow[kk]) : (ushort)0;
        }
      }
      *(short8*)&lds[buf * 2048 + t * 8] = *(short8*)tmp;
    }
  };
  auto stageB = [&](int tk, int buf) {
#pragma unroll
    for (int j = 0; j < 2; ++j) {
      int c = wave * 2 + j;
      gll16(Bbase + (size_t)tk * 4096 + c * 512 + lane * 8,
            lds + 4096 + buf * 4096 + c * 512);
    }
  };
  auto stage2L = [&](int s2, int buf) {
#pragma unroll
    for (int j = 0; j < 2; ++j) {
      int c = wave * 2 + j;
      gll16(sg.B2 + (size_t)s2 * 4096 + c * 512 + lane * 8,
            lds + buf * 4096 + c * 512);
    }
  };

  stageB(0, 0);
  stageA(0, 0);
  __syncthreads();

  for (int tk = 0; tk < Ktiles; ++tk) {
    int buf = tk & 1;
    if (tk + 1 < Ktiles) { stageB(tk + 1, buf ^ 1); stageA(tk + 1, buf ^ 1); }

    short8 af[4], bfr[2];
#pragma unroll
    for (int i = 0; i < 4; ++i)
      af[i] = *(const short8*)&lds[buf * 2048 + (i * 16 + l16) * 32 + swz];
#pragma unroll
    for (int n = 0; n < 2; ++n)
      bfr[n] = *(const short8*)&lds[4096 + buf * 4096 + (wn + n * 16 + l16) * 32 + swz];
#pragma unroll
    for (int mi = 0; mi < 4; ++mi)
#pragma unroll
      for (int ni = 0; ni < 2; ++ni)
        acc[mi][ni] = __builtin_amdgcn_mfma_f32_16x16x32_bf16(
            bfr[ni], af[mi], acc[mi][ni], 0, 0, 0);
    __syncthreads();
  }

  // prefetch first stage-2 B tile under the epilogue (aliases dead stage-1 LDS)
  if (sg.n2 > 0) stage2L(0, 0);

  const int epi = sg.epi;
  float g = 0.f, omg = 0.f;
  if (epi == 2 || epi == 3 || epi == 5) {
    float s = g3.skip[sg.skip_idx];
    g = 1.f / (1.f + __expf(-s));
    omg = 1.f - g;
  }
#pragma unroll
  for (int ni = 0; ni < 2; ++ni) {
    int cl = wn + ni * 16 + quad * 4;     // 4 consecutive local cols
    int cb = tn * 128 + cl;
    float4 b4 = *(const float4*)&sg.bias[cb];
#pragma unroll
    for (int mi = 0; mi < 4; ++mi) {
      int prow = mi * 16 + l16;           // local row in the 64-row half
      int rr = tm * 128 + hm * 64 + prow;
      float v0 = acc[mi][ni][0] + b4.x;
      float v1 = acc[mi][ni][1] + b4.y;
      float v2 = acc[mi][ni][2] + b4.z;
      float v3 = acc[mi][ni][3] + b4.w;
      if (epi == 0) {
        uint2 o = make_uint2(((uint)f2b(v1) << 16) | f2b(v0),
                             ((uint)f2b(v3) << 16) | f2b(v2));
        *(uint2*)&((ushort*)sg.out)[(size_t)rr * sg.ldo + cb] = o;
      } else if (epi == 1) {
        if (rr < sg.Mreal)
          *(float4*)&((float*)sg.out)[(size_t)rr * sg.ldo + cb] =
              make_float4(v0, v1, v2, v3);
      } else if (epi == 2) {
        if (rr < sg.Mreal) {
          uint2 xo = *(const uint2*)&sg.xsP[a_packed_us(rr, cb)];
          float4 o;
          o.x = fmaxf(g * v0 + omg * blo(xo.x), 0.f);
          o.y = fmaxf(g * v1 + omg * bhi(xo.x), 0.f);
          o.z = fmaxf(g * v2 + omg * blo(xo.y), 0.f);
          o.w = fmaxf(g * v3 + omg * bhi(xo.y), 0.f);
          *(float4*)&((float*)sg.out)[(size_t)rr * sg.ldo + cb] = o;
        }
      } else if (epi == 3) {
        uint2 xo = *(const uint2*)&sg.xsP[a_packed_us(rr, cb)];
        uint2 o = make_uint2(
            ((uint)f2b(fmaxf(g * v1 + omg * bhi(xo.x), 0.f)) << 16) |
                   f2b(fmaxf(g * v0 + omg * blo(xo.x), 0.f)),
            ((uint)f2b(fmaxf(g * v3 + omg * bhi(xo.y), 0.f)) << 16) |
                   f2b(fmaxf(g * v2 + omg * blo(xo.y), 0.f)));
        *(uint2*)&((ushort*)sg.out)[a_packed_us(rr, cb)] = o;
      } else if (epi == 4) {
        uint2 o = make_uint2(((uint)f2b(v1) << 16) | f2b(v0),
                             ((uint)f2b(v3) << 16) | f2b(v2));
        *(uint2*)&((ushort*)sg.out)[a_packed_us(rr, cb)] = o;
        int kin = cl & 31;
        int sw2 = (kin >> 3) ^ ((prow >> 1) & 3);
        *(uint2*)&Xs[(cl >> 5) * 2048 + prow * 32 + sw2 * 8 + (kin & 7)] = o;
      } else {  // 5: skip-relu into Xs only
        uint2 xo = *(const uint2*)&sg.xsP[a_packed_us(rr, cb)];
        uint2 o = make_uint2(
            ((uint)f2b(fmaxf(g * v1 + omg * bhi(xo.x), 0.f)) << 16) |
                   f2b(fmaxf(g * v0 + omg * blo(xo.x), 0.f)),
            ((uint)f2b(fmaxf(g * v3 + omg * bhi(xo.y), 0.f)) << 16) |
                   f2b(fmaxf(g * v2 + omg * blo(xo.y), 0.f)));
        int kin = cl & 31;
        int sw2 = (kin >> 3) ^ ((prow >> 1) & 3);
        *(uint2*)&Xs[(cl >> 5) * 2048 + prow * 32 + sw2 * 8 + (kin & 7)] = o;
      }
    }
  }

  // ---------------- stage 2: flat pipeline over n2*4 k-steps ----------------
  if (sg.n2 == 0) return;
  __syncthreads();   // Xs + first B2 tile ready
  int total2 = sg.n2 * 4;
  floatx4 a2[4][2];
#pragma unroll
  for (int i = 0; i < 4; ++i)
#pragma unroll
    for (int j = 0; j < 2; ++j) a2[i][j] = (floatx4){0.f, 0.f, 0.f, 0.f};
  for (int s2 = 0; s2 < total2; ++s2) {
    int buf = s2 & 1;
    if (s2 + 1 < total2) stage2L(s2 + 1, buf ^ 1);
    int xb = (s2 & 3) * 2048;
    short8 af[4], bfr[2];
#pragma unroll
    for (int i = 0; i < 4; ++i)
      af[i] = *(const short8*)&Xs[xb + (i * 16 + l16) * 32 + swz];
#pragma unroll
    for (int n = 0; n < 2; ++n)
      bfr[n] = *(const short8*)&lds[buf * 4096 + (wn + n * 16 + l16) * 32 + swz];
#pragma unroll
    for (int mi = 0; mi < 4; ++mi)
#pragma unroll
      for (int ni = 0; ni < 2; ++ni)
        a2[mi][ni] = __builtin_amdgcn_mfma_f32_16x16x32_bf16(
            bfr[ni], af[mi], a2[mi][ni], 0, 0, 0);
    __syncthreads();
    if ((s2 & 3) == 3) {
      int t2 = s2 >> 2;
#pragma unroll
      for (int ni = 0; ni < 2; ++ni) {
        int cb2 = t2 * 128 + wn + ni * 16 + quad * 4;
        float4 b4 = *(const float4*)&sg.bias2[cb2];
#pragma unroll
        for (int mi = 0; mi < 4; ++mi) {
          int rr = tm * 128 + hm * 64 + mi * 16 + l16;
          float v0 = a2[mi][ni][0] + b4.x;
          float v1 = a2[mi][ni][1] + b4.y;
          float v2 = a2[mi][ni][2] + b4.z;
          float v3 = a2[mi][ni][3] + b4.w;
          if (sg.epi2 == 0) {
            uint2 o = make_uint2(((uint)f2b(v1) << 16) | f2b(v0),
                                 ((uint)f2b(v3) << 16) | f2b(v2));
            *(uint2*)&((ushort*)sg.out2)[(size_t)rr * sg.ldo2 + cb2] = o;
          } else {
            if (rr < sg.Mreal2)
              *(float4*)&((float*)sg.out2)[(size_t)rr * sg.ldo2 + cb2] =
                  make_float4(v0, v1, v2, v3);
          }
          a2[mi][ni] = (floatx4){0.f, 0.f, 0.f, 0.f};
        }
      }
    }
  }
}

// ================= gather: one wave per dst node, 2x4 edges/iter ==========
// (measured-best 8-edge form: VGPR 32, occupancy ~70%)
struct GatherType { const ushort* q; ushort* agg; int ldq; };
struct GatherDesc { GatherType ty[3]; int n0, n1; };

__launch_bounds__(256)
__global__ void gather_all(const int* __restrict__ starts,
                           const uint* __restrict__ payload,
                           const ushort* __restrict__ kvbase,
                           GatherDesc gd, int Ntot)
{
  int wid = (blockIdx.x * 256 + threadIdx.x) >> 6;
  if (wid >= Ntot) return;
  int lane = threadIdx.x & 63;
  int g = lane >> 4, l = lane & 15;

  GatherType T;
  int d;
  if (wid < gd.n0)      { T = gd.ty[0]; d = wid; }
  else if (wid < gd.n1) { T = gd.ty[1]; d = wid - gd.n0; }
  else                  { T = gd.ty[2]; d = wid - gd.n1; }

  const char* kvb = (const char*)kvbase;
  const uint lofs = (uint)l * 16u;

  uint4 qv = *(const uint4*)(T.q + (size_t)d * T.ldq + l * 8);
  f32x2 q0 = b2x2(qv.x), q1 = b2x2(qv.y), q2 = b2x2(qv.z), q3 = b2x2(qv.w);

  int e0 = starts[wid], e1 = starts[wid + 1];
  float lsum = 0.f;
  f32x2 ac0 = {0.f, 0.f}, ac1 = {0.f, 0.f}, ac2 = {0.f, 0.f}, ac3 = {0.f, 0.f};

  for (int eb = e0; eb < e1; eb += 8) {
    int eA = eb + g, eB = eA + 4;
    bool actA = eA < e1, actB = eB < e1;
    uint pA = payload[actA ? eA : e0];
    uint pB = payload[actB ? eB : e0];
    const char* bA = kvb + (pA + lofs);
    const char* bB = kvb + (pB + lofs);
    uint4 kA = *(const uint4*)bA;
    uint4 vA = *(const uint4*)(bA + 256);
    uint4 kB = *(const uint4*)bB;
    uint4 vB = *(const uint4*)(bB + 256);

    f32x2 dA = q0 * b2x2(kA.x);
    dA = __builtin_elementwise_fma(q1, b2x2(kA.y), dA);
    dA = __builtin_elementwise_fma(q2, b2x2(kA.z), dA);
    dA = __builtin_elementwise_fma(q3, b2x2(kA.w), dA);
    f32x2 dB = q0 * b2x2(kB.x);
    dB = __builtin_elementwise_fma(q1, b2x2(kB.y), dB);
    dB = __builtin_elementwise_fma(q2, b2x2(kB.z), dB);
    dB = __builtin_elementwise_fma(q3, b2x2(kB.w), dB);
    float pa = dA.x + dA.y;
    float pb = dB.x + dB.y;
    pa += __shfl_xor(pa, 1, 64);
    pb += __shfl_xor(pb, 1, 64);
    float exA = exp2f(fminf(pa, 115.4f));
    float exB = exp2f(fminf(pb, 115.4f));
    exA = actA ? exA : 0.f;
    exB = actB ? exB : 0.f;
    lsum += exA + exB;
    f32x2 xA = {exA, exA}, xB = {exB, exB};
    ac0 = __builtin_elementwise_fma(xA, b2x2(vA.x), ac0);
    ac1 = __builtin_elementwise_fma(xA, b2x2(vA.y), ac1);
    ac2 = __builtin_elementwise_fma(xA, b2x2(vA.z), ac2);
    ac3 = __builtin_elementwise_fma(xA, b2x2(vA.w), ac3);
    ac0 = __builtin_elementwise_fma(xB, b2x2(vB.x), ac0);
    ac1 = __builtin_elementwise_fma(xB, b2x2(vB.y), ac1);
    ac2 = __builtin_elementwise_fma(xB, b2x2(vB.z), ac2);
    ac3 = __builtin_elementwise_fma(xB, b2x2(vB.w), ac3);
  }

  float s0 = ac0.x, s1 = ac0.y, s2 = ac1.x, s3 = ac1.y;
  float s4 = ac2.x, s5 = ac2.y, s6 = ac3.x, s7 = ac3.y;
#define MRG(v) v += __shfl_xor(v, 16, 64); v += __shfl_xor(v, 32, 64)
  MRG(lsum); MRG(s0); MRG(s1); MRG(s2); MRG(s3); MRG(s4); MRG(s5); MRG(s6); MRG(s7);
#undef MRG

  // each lane finishes channels c0 = 8*l + 2*g and c0+1
  float inv = 1.f / (lsum + 1e-16f);
  float m0 = (g & 1) ? s2 : s0, m1 = (g & 1) ? s6 : s4;
  float n0 = (g & 1) ? s3 : s1, n1 = (g & 1) ? s7 : s5;
  float x0 = ((g & 2) ? m1 : m0) * inv;
  float x1 = ((g & 2) ? n1 : n0) * inv;
  float g0 = 0.5f * x0 * (1.f + erff(x0 * 0.70710678118654752f));
  float g1 = 0.5f * x1 * (1.f + erff(x1 * 0.70710678118654752f));
  int tm = d >> 7, row = d & 127;
  int tk = l >> 2, sw = (l & 3) ^ ((row >> 1) & 3);
  size_t us = (((size_t)tm * 4 + tk) * 512 + (size_t)row * 4 + sw) * 8 + 2 * g;
  *(uint*)(T.agg + us) = ((uint)f2b(g1) << 16) | (uint)f2b(g0);
}

// ================= host =====================================================
extern "C" void kernel_launch(void* const* d_in, const int* in_sizes, int n_in,
                              void* d_out, int out_size, void* d_ws, size_t ws_size,
                              hipStream_t stream)
{
  const float* x_herb = (const float*)d_in[0];
  const float* x_ing  = (const float*)d_in[1];
  const float* x_tgt  = (const float*)d_in[2];
  const float* W_herb = (const float*)d_in[3];
  const float* b_herb = (const float*)d_in[4];
  const float* W_ing  = (const float*)d_in[5];
  const float* b_ing  = (const float*)d_in[6];
  const float* W_tgt  = (const float*)d_in[7];
  const float* b_tgt  = (const float*)d_in[8];
  const float* Wk     = (const float*)d_in[9];
  const float* bk     = (const float*)d_in[10];
  const float* Wq     = (const float*)d_in[11];
  const float* bq     = (const float*)d_in[12];
  const float* Wv     = (const float*)d_in[13];
  const float* bv     = (const float*)d_in[14];
  const float* a_rel  = (const float*)d_in[15];
  const float* m_rel  = (const float*)d_in[16];
  const float* p_rel  = (const float*)d_in[17];
  const float* Wa     = (const float*)d_in[18];
  const float* ba     = (const float*)d_in[19];
  const float* skip   = (const float*)d_in[20];
  const float* W_out  = (const float*)d_in[21];
  const float* b_out  = (const float*)d_in[22];
  const int* srcs[4] = {(const int*)d_in[23], (const int*)d_in[25],
                        (const int*)d_in[27], (const int*)d_in[29]};
  const int* dsts[4] = {(const int*)d_in[24], (const int*)d_in[26],
                        (const int*)d_in[28], (const int*)d_in[30]};

  const int Nh = in_sizes[0] / 400;
  const int Ni = in_sizes[1] / 300;
  const int Nt = in_sizes[2] / 200;
  const int E  = in_sizes[23];
  const int Ntot = Nh + Ni + Nt;

  const int MT_h = (Nh + 127) / 128, MT_i = (Ni + 127) / 128, MT_t = (Nt + 127) / 128;
  const int KT_h = 13, KT_i = 10, KT_t = 7;   // Kpad 416/320/224

  // CSR sort params
  const int NBs = (E + CSR_CH - 1) / CSR_CH;
  const int NBH = 4 * NBs;
  const int NBK = (Ntot + (1 << CSR_SH) - 1) >> CSR_SH;   // <= 511

  char* base = (char*)d_ws;
  size_t off = 0;
  auto A = [&](size_t bytes) -> void* {
    void* p = base + off; off += (bytes + 255) & ~(size_t)255; return p;
  };
  ushort* xsP_h = (ushort*)A((size_t)MT_h * 4 * 8192);
  ushort* xsP_i = (ushort*)A((size_t)MT_i * 4 * 8192);
  ushort* xsP_t = (ushort*)A((size_t)MT_t * 4 * 8192);
  ushort* fused_h = (ushort*)A((size_t)MT_h * 128 * 384 * 2);  // [q|k0|v0]
  ushort* fused_i = (ushort*)A((size_t)MT_i * 128 * 640 * 2);  // [q|k1|v1|k2|v2]
  ushort* fused_t = (ushort*)A((size_t)MT_t * 128 * 384 * 2);  // [q|k3|v3]
  ushort* aggp_h  = (ushort*)A((size_t)MT_h * 4 * 8192);
  ushort* aggp_i  = (ushort*)A((size_t)MT_i * 4 * 8192);
  ushort* aggp_t  = (ushort*)A((size_t)MT_t * 4 * 8192);
  ushort* Weff1_h = (ushort*)A((size_t)KT_h * 8192);
  ushort* Weff1_i = (ushort*)A((size_t)KT_i * 8192);
  ushort* Weff1_t = (ushort*)A((size_t)KT_t * 8192);
  ushort* Wcat_h = (ushort*)A((size_t)3 * 4 * 8192);
  ushort* Wcat_i = (ushort*)A((size_t)5 * 4 * 8192);
  ushort* Wcat_t = (ushort*)A((size_t)3 * 4 * 8192);
  float* bcat   = (float*)A(1408 * 4);
  ushort* Wa_t   = (ushort*)A((size_t)3 * 16384 * 2);
  ushort* Wout_t = (ushort*)A((size_t)16384 * 2);
  int* starts  = (int*)A((size_t)(Ntot + 4) * 4);
  uint* payload = (uint*)A((size_t)(4 * E + 8) * 4);
  uint* hist    = (uint*)A((size_t)NBK * NBH * 4);
  uint* bucketTot  = (uint*)A((size_t)NBK * 4);
  uint2* inter  = (uint2*)A((size_t)(4 * E + 8) * 8);
  (void)ws_size; (void)n_in;

  const int toff_h = 0, toff_i = Nh, toff_t = Nh + Ni;
  dim3 blk(256);

  uint fi2 = (uint)((size_t)(fused_i - fused_h) * 2);
  uint ft2 = (uint)((size_t)(fused_t - fused_h) * 2);

  // --- 1: prologue (combine_rel + weight prep + bq + edge hist) ---
  Prolog P;
  P.wstart = 4 * 2 * 129 * 128;
  {
    const float* wsrc10[10] = {W_herb, W_ing, W_tgt, Wq, Wq + 16384, Wq + 32768,
                               Wa, Wa + 16384, Wa + 32768, W_out};
    ushort* wdst10[10] = {Weff1_h, Weff1_i, Weff1_t, Wcat_h, Wcat_i, Wcat_t,
                          Wa_t, Wa_t + 16384, Wa_t + 32768, Wout_t};
    int wk10[10] = {400, 300, 200, 128, 128, 128, 128, 128, 128, 128};
    int wcum = 0;
    for (int z = 0; z < 10; ++z) {
      P.wb[z] = {wsrc10[z], wdst10[z], wk10[z], wcum};
      wcum += ((wk10[z] + 31) / 32) * 512;
    }
    P.bstart = P.wstart + wcum;
  }
  P.total = P.bstart + 384;
  P.Wk = Wk; P.bk = bk; P.Wv = Wv; P.bv = bv;
  P.a_rel = a_rel; P.m_rel = m_rel; P.p_rel = p_rel;
  P.kw_dst[0] = Wcat_h + 16384; P.vw_dst[0] = Wcat_h + 32768;
  P.kw_dst[1] = Wcat_i + 16384; P.vw_dst[1] = Wcat_i + 32768;
  P.kw_dst[2] = Wcat_i + 49152; P.vw_dst[2] = Wcat_i + 65536;
  P.kw_dst[3] = Wcat_t + 16384; P.vw_dst[3] = Wcat_t + 32768;
  P.bcat = bcat;
  P.kb_off[0] = 128;  P.vb_off[0] = 256;
  P.kb_off[1] = 512;  P.vb_off[1] = 640;
  P.kb_off[2] = 768;  P.vb_off[2] = 896;
  P.kb_off[3] = 1152; P.vb_off[3] = 1280;
  P.bq = bq;
  P.bq_off[0] = 0; P.bq_off[1] = 384; P.bq_off[2] = 1024;
  P.edst[0] = dsts[0]; P.eoff[0] = toff_i;
  P.edst[1] = dsts[1]; P.eoff[1] = toff_h;
  P.edst[2] = dsts[2]; P.eoff[2] = toff_t;
  P.edst[3] = dsts[3]; P.eoff[3] = toff_i;
  P.hist = hist; P.NBs = NBs; P.NBH = NBH; P.NBK = NBK; P.E = E;
  prologue<<<NBH + (P.total + 255) / 256, blk, 0, stream>>>(P);

  // --- 2: CSR build (scan -> scatter -> finalize) ---
  EdgeStreams ES;
  ES.src[0] = srcs[0]; ES.dst[0] = dsts[0]; ES.off[0] = toff_i;
  ES.rel[0] = 256u;        ES.ldb[0] = 768u;
  ES.src[1] = srcs[1]; ES.dst[1] = dsts[1]; ES.off[1] = toff_h;
  ES.rel[1] = fi2 + 256u;  ES.ldb[1] = 1280u;
  ES.src[2] = srcs[2]; ES.dst[2] = dsts[2]; ES.off[2] = toff_t;
  ES.rel[2] = fi2 + 768u;  ES.ldb[2] = 1280u;
  ES.src[3] = srcs[3]; ES.dst[3] = dsts[3]; ES.off[3] = toff_i;
  ES.rel[3] = ft2 + 256u;  ES.ldb[3] = 768u;
  bucket_scan<<<NBK, blk, 0, stream>>>(hist, bucketTot, NBH);
  bucket_scatter<<<NBH, blk, 0, stream>>>(ES, hist, bucketTot, inter, NBs, NBH, NBK, E);
  bucket_finalize<<<NBK, blk, 0, stream>>>(inter, bucketTot, starts, payload, Ntot, NBK);

  // --- 3: K1 = pack + GEMM1 + GEMM2 fused, 64-row blocks (A from fp32 x) ---
  Gemm3 G1;
  G1.skip = skip; G1.nseg = 3;
  G1.s[0] = {nullptr, Weff1_h, b_herb, xsP_h, nullptr, KT_h, 0, 0, 0, 4, 1, 0,
             3, Wcat_h, bcat + 0, fused_h, 384, 0, 0, x_herb, 400, Nh};
  G1.s[1] = {nullptr, Weff1_i, b_ing,  xsP_i, nullptr, KT_i, 0, 0, 0, 4, 1, 2 * MT_h,
             5, Wcat_i, bcat + 384, fused_i, 640, 0, 0, x_ing, 300, Ni};
  G1.s[2] = {nullptr, Weff1_t, b_tgt,  xsP_t, nullptr, KT_t, 0, 0, 0, 4, 1,
             2 * (MT_h + MT_i),
             3, Wcat_t, bcat + 1024, fused_t, 384, 0, 0, x_tgt, 200, Nt};
  gemm_sched<<<2 * (MT_h + MT_i + MT_t), blk, 0, stream>>>(G1);

  // --- 4: gather attention (all types, one wave per node) ---
  GatherDesc GD;
  GD.n0 = Nh; GD.n1 = Nh + Ni;
  GD.ty[0] = {fused_h, aggp_h, 384};
  GD.ty[1] = {fused_i, aggp_i, 640};
  GD.ty[2] = {fused_t, aggp_t, 384};
  gather_all<<<(Ntot + 3) / 4, blk, 0, stream>>>(starts, payload, fused_h, GD, Ntot);

  // --- 5: K2 = epilogue GEMMs, 64-row blocks; herb chains W_out from LDS ---
  float* outp = (float*)d_out;
  float* out_herb = outp;
  float* out_ing  = outp + (size_t)Nh * HID;
  float* out_tgt  = outp + (size_t)(Nh + Ni) * HID;
  Gemm3 GE;
  GE.skip = skip; GE.nseg = 3;
  GE.s[0] = {aggp_h, Wa_t + 0 * 16384, ba + 0 * 128, nullptr, xsP_h,
             4, 0, 0, 0, 5, 1, 0,
             1, Wout_t, b_out, out_herb, 128, Nh, 1, nullptr, 0, 0};
  GE.s[1] = {aggp_i, Wa_t + 1 * 16384, ba + 1 * 128, out_ing, xsP_i,
             4, 128, Ni, 1, 2, 1, 2 * MT_h,
             0, nullptr, nullptr, nullptr, 0, 0, 0, nullptr, 0, 0};
  GE.s[2] = {aggp_t, Wa_t + 2 * 16384, ba + 2 * 128, out_tgt, xsP_t,
             4, 128, Nt, 2, 2, 1, 2 * (MT_h + MT_i),
             0, nullptr, nullptr, nullptr, 0, 0, 0, nullptr, 0, 0};
  gemm_sched<<<2 * (MT_h + MT_i + MT_t), blk, 0, stream>>>(GE);
  (void)out_size;
}

// Round 8
// 367.249 us; speedup vs baseline: 1.2545x; 1.0002x over previous
//
#include <hip/hip_runtime.h>
#include <math.h>

#define HID 128
typedef unsigned int uint;
typedef unsigned short ushort;
typedef __attribute__((ext_vector_type(8))) short short8;
typedef __attribute__((ext_vector_type(4))) float floatx4;
typedef __attribute__((ext_vector_type(2))) float f32x2;

// ---------- bf16 helpers ----------
__device__ __forceinline__ ushort f2b(float f) {
  uint u = __float_as_uint(f);
  u += 0x7fffu + ((u >> 16) & 1u);
  return (ushort)(u >> 16);
}
__device__ __forceinline__ float b2f(ushort s) {
  return __uint_as_float(((uint)s) << 16);
}
__device__ __forceinline__ float blo(uint u) { return __uint_as_float(u << 16); }
__device__ __forceinline__ float bhi(uint u) { return __uint_as_float(u & 0xffff0000u); }
__device__ __forceinline__ f32x2 b2x2(uint u) {
  f32x2 r;
  r.x = __uint_as_float(u << 16);
  r.y = __uint_as_float(u & 0xffff0000u);
  return r;
}

__device__ __forceinline__ void gll16(const ushort* g, ushort* l) {
  __builtin_amdgcn_global_load_lds(
      (const __attribute__((address_space(1))) void*)g,
      (__attribute__((address_space(3))) void*)l, 16, 0, 0);
}

// Packed tile layout (128 rows x 32 k, bf16), 16B slot within tile:
//   slot = row*4 + (chunk ^ ((row>>1)&3)), chunk = k/8. Conflict-free staging+frags.
//   Rows [0,64) of a tile occupy the first 4096B contiguously (64-row halves
//   are independently addressable).
__device__ __forceinline__ size_t a_packed_us(int rr, int col) {
  int tm = rr >> 7, prow = rr & 127;
  int ptk = col >> 5, kin = col & 31;
  int sw = (kin >> 3) ^ ((prow >> 1) & 3);
  return (((size_t)tm * 4 + ptk) * 512 + (size_t)prow * 4 + sw) * 8 + (kin & 7);
}

// ================= CSR params ==============================================
#define CSR_CH 2048   // edges per block in hist/scatter passes
#define CSR_SH 9      // 512 nodes per bucket

struct EdgeStreams {
  const int* src[4]; const int* dst[4];
  int off[4]; uint rel[4]; uint ldb[4];
};

// ================= prologue: combine_rel + weight prep + hist ===============
// (x-packing is fused into K1's A-staging)
struct WBlk { const float* src; ushort* dst; int K; int start; };
struct Prolog {
  int wstart, bstart, total;
  const float *Wk, *bk, *Wv, *bv, *a_rel, *m_rel, *p_rel;
  ushort* kw_dst[4];
  ushort* vw_dst[4];
  float* bcat;
  int kb_off[4], vb_off[4];
  WBlk wb[10];
  const float* bq;
  int bq_off[3];
  // edge-hist segment (block-granular, blocks [0, NBH))
  const int* edst[4];
  int eoff[4];
  uint* hist;       // transposed: hist[bucket][block]
  int NBs, NBH, NBK, E;
};

// combine_rel: Wk_rel[e] = Wk[i] @ a_rel[e] (and Wv/m_rel), written DIRECTLY in
// packed-B bf16 layout. p_rel[e,h]/sqrt(D)*log2(e) is baked into the k weights
// and bias so the gather's logit feeds exp2 with no per-edge scale.
__device__ void combine_rel_elem(const Prolog& P, int idx)
{
  int col  = idx & 127;
  int rest = idx >> 7;
  int row  = rest % 129;
  rest /= 129;
  int kv = rest & 1;
  int e  = rest >> 1;
  int i  = (e + 1) >> 1;           // styp = {0,1,1,2}
  int h = col >> 4, j = col & 15;
  const float* Wsrc = kv ? P.Wv : P.Wk;
  const float* bsrc = kv ? P.bv : P.bk;
  const float* rel  = kv ? P.m_rel : P.a_rel;
  float acc = 0.f;
  if (row < 128) {
#pragma unroll
    for (int d = 0; d < 16; ++d)
      acc += Wsrc[(size_t)i * 16384 + (size_t)row * 128 + h * 16 + d] *
             rel[((e * 8 + h) * 16 + d) * 16 + j];
  } else {
#pragma unroll
    for (int d = 0; d < 16; ++d)
      acc += bsrc[i * 128 + h * 16 + d] * rel[((e * 8 + h) * 16 + d) * 16 + j];
  }
  if (!kv) acc *= P.p_rel[e * 8 + h] * 0.36067376022224085f;  // 0.25 * log2(e)
  if (row < 128) {
    ushort* dst = kv ? P.vw_dst[e] : P.kw_dst[e];
    int tk = row >> 5, chunk = (row >> 3) & 3, m = row & 7;
    int swf = chunk ^ ((col >> 1) & 3);
    dst[((tk * 512 + col * 4 + swf) << 3) + m] = f2b(acc);
  } else {
    P.bcat[(kv ? P.vb_off[e] : P.kb_off[e]) + col] = acc;
  }
}

// pure layout conversion of row-major fp32 [K][128] weights to packed-B bf16
__device__ void conv_elem(const Prolog& P, int s0)
{
  int si = 0;
#pragma unroll
  for (int k = 1; k < 10; ++k)
    if (s0 >= P.wb[k].start) si = k;
  WBlk b = P.wb[si];
  int s = s0 - b.start;
  int tk = s >> 9, o = s & 511;
  int c = o >> 2, swf = o & 3;
  int chunk = swf ^ ((c >> 1) & 3);
  int r0 = tk * 32 + chunk * 8;
  ushort tmp[8];
#pragma unroll
  for (int m = 0; m < 8; ++m) {
    int r = r0 + m;
    tmp[m] = (r < b.K) ? f2b(b.src[(size_t)r * 128 + c]) : (ushort)0;
  }
  *(short8*)&b.dst[(size_t)s * 8] = *(short8*)tmp;
}

__global__ __launch_bounds__(256)
void prologue(Prolog P)
{
  __shared__ uint h[512];
  int bI = blockIdx.x;
  if (bI < P.NBH) {
    // --- edge histogram segment (block-granular) ---
    int et = bI / P.NBs;
    int i0 = (bI - et * P.NBs) * CSR_CH;
    const int* dp = P.edst[et];
    int off = P.eoff[et];
    for (int t = threadIdx.x; t < P.NBK; t += 256) h[t] = 0;
    __syncthreads();
#pragma unroll
    for (int j = 0; j < CSR_CH / 256; ++j) {
      int idx = i0 + j * 256 + threadIdx.x;
      if (idx < P.E) atomicAdd(&h[(uint)(off + dp[idx]) >> CSR_SH], 1u);
    }
    __syncthreads();
    for (int t = threadIdx.x; t < P.NBK; t += 256)
      P.hist[(size_t)t * P.NBH + bI] = h[t];
    return;
  }
  int gtid = (bI - P.NBH) * 256 + threadIdx.x;
  if (gtid >= P.total) return;
  if (gtid >= P.bstart) {
    int j = gtid - P.bstart;
    P.bcat[P.bq_off[j >> 7] + (j & 127)] = P.bq[j];
    return;
  }
  if (gtid >= P.wstart) { conv_elem(P, gtid - P.wstart); return; }
  combine_rel_elem(P, gtid);
}

// ================= CSR build: two-level counting sort =======================
__global__ __launch_bounds__(256)
void bucket_scan(uint* __restrict__ hist, uint* __restrict__ bucketTot, int NBH)
{
  __shared__ uint ws[4];
  __shared__ uint carry_s;
  int b = blockIdx.x;
  int t = threadIdx.x, lane = t & 63, w = t >> 6;
  if (t == 0) carry_s = 0;
  __syncthreads();
  for (int base = 0; base < NBH; base += 256) {
    int i = base + t;
    uint x = (i < NBH) ? hist[(size_t)b * NBH + i] : 0u;
    uint v = x;
#pragma unroll
    for (int o = 1; o < 64; o <<= 1) {
      uint y = __shfl_up(v, o, 64);
      if (lane >= o) v += y;
    }
    if (lane == 63) ws[w] = v;
    __syncthreads();
    uint add = carry_s;
    for (int k = 0; k < w; ++k) add += ws[k];
    if (i < NBH) hist[(size_t)b * NBH + i] = add + v - x;
    __syncthreads();
    if (t == 255) carry_s = add + v;
    __syncthreads();
  }
  if (t == 0) bucketTot[b] = carry_s;
}

// local exclusive scan of bucketTot (<=512 entries) into sb[]; 2 slots/thread
__device__ __forceinline__ void base_scan(const uint* __restrict__ bucketTot,
                                          uint* sb, uint* ws, int NBK)
{
  int t = threadIdx.x, lane = t & 63, w = t >> 6;
  sb[t] = (t < NBK) ? bucketTot[t] : 0u;
  sb[t + 256] = (t + 256 < NBK) ? bucketTot[t + 256] : 0u;
  __syncthreads();
  uint a0 = sb[2 * t], a1 = sb[2 * t + 1];
  uint s = a0 + a1;
  uint v = s;
#pragma unroll
  for (int o = 1; o < 64; o <<= 1) {
    uint y = __shfl_up(v, o, 64);
    if (lane >= o) v += y;
  }
  if (lane == 63) ws[w] = v;
  __syncthreads();
  uint add = 0;
  for (int k = 0; k < w; ++k) add += ws[k];
  uint e0 = add + v - s;
  sb[2 * t] = e0;
  sb[2 * t + 1] = e0 + a0;
  __syncthreads();
}

// Pass C: scatter (payload, dst) into bucket-contiguous intermediate
__global__ __launch_bounds__(256)
void bucket_scatter(EdgeStreams es, const uint* __restrict__ hist,
                    const uint* __restrict__ bucketTot,
                    uint2* __restrict__ inter, int NBs, int NBH, int NBK, int E)
{
  __shared__ uint sb[516];
  __shared__ uint ws[4];
  __shared__ uint cur[512];
  base_scan(bucketTot, sb, ws, NBK);
  int b = blockIdx.x;
  int et = b / NBs;
  int i0 = (b - et * NBs) * CSR_CH;
  const int* dp = es.dst[et];
  const int* sp = es.src[et];
  int off = es.off[et];
  uint rel = es.rel[et], ldb = es.ldb[et];
  for (int t = threadIdx.x; t < NBK; t += 256)
    cur[t] = sb[t] + hist[(size_t)t * NBH + b];
  __syncthreads();
#pragma unroll
  for (int j = 0; j < CSR_CH / 256; ++j) {
    int idx = i0 + j * 256 + threadIdx.x;
    if (idx < E) {
      int g = off + dp[idx];
      uint pos = atomicAdd(&cur[(uint)g >> CSR_SH], 1u);
      inter[pos] = make_uint2(rel + (uint)sp[idx] * ldb, (uint)g);
    }
  }
}

// Pass D: one block per bucket; per-node count+scan in LDS, write starts and
// final payload into this block's contiguous region (single-writer lines).
__global__ __launch_bounds__(256)
void bucket_finalize(const uint2* __restrict__ inter,
                     const uint* __restrict__ bucketTot,
                     int* __restrict__ starts, uint* __restrict__ payload,
                     int Ntot, int NBK)
{
  __shared__ uint sb[516];
  __shared__ uint ncnt[512];
  __shared__ uint ws[4];
  base_scan(bucketTot, sb, ws, NBK);
  int b = blockIdx.x;
  int g0 = b << CSR_SH;
  int t = threadIdx.x, lane = t & 63, w = t >> 6;
  uint r0 = sb[b], r1 = sb[b + 1];
  if (b == NBK - 1 && t == 0) starts[Ntot] = (int)r1;
  ncnt[t] = 0; ncnt[t + 256] = 0;
  __syncthreads();
  for (uint i = r0 + t; i < r1; i += 256)
    atomicAdd(&ncnt[inter[i].y - g0], 1u);
  __syncthreads();
  uint a0 = ncnt[2 * t], a1 = ncnt[2 * t + 1];
  uint s = a0 + a1;
  uint v = s;
#pragma unroll
  for (int o = 1; o < 64; o <<= 1) {
    uint y = __shfl_up(v, o, 64);
    if (lane >= o) v += y;
  }
  if (lane == 63) ws[w] = v;
  __syncthreads();
  uint add = r0;
  for (int k = 0; k < w; ++k) add += ws[k];
  uint e0 = add + v - s;
  int gi = g0 + 2 * t;
  if (gi < Ntot)     starts[gi]     = (int)e0;
  if (gi + 1 < Ntot) starts[gi + 1] = (int)(e0 + a0);
  ncnt[2 * t] = e0;          // reuse as cursors
  ncnt[2 * t + 1] = e0 + a0;
  __syncthreads();
  for (uint i = r0 + t; i < r1; i += 256) {
    uint2 rec = inter[i];
    uint pos = atomicAdd(&ncnt[rec.y - g0], 1u);
    payload[pos] = rec.x;
  }
}

// ================= fused multi-segment MFMA GEMM (two-stage, 64-row) =======
// Each block owns a 64-row half of a packed 128-row M-tile. 4 waves along N.
// TRANSPOSED mfma: lane's 4 acc regs = 4 consecutive output columns.
// A-staging (Af != nullptr): T14 async split — issue fp32 x-loads into
// registers at iteration top (latency hides under the MFMAs), cvt+ds_write
// AFTER the MFMA cluster, before the barrier. Thread t owns packed slot t.
// epi: 0 bf16 row-major unguarded; 1 fp32 guarded; 2 skip-relu fp32 guarded;
//      3 skip-relu bf16 packed; 4 plain bf16 packed (+Xs stash if n2>0);
//      5 skip-relu -> Xs ONLY (feeds stage 2)
// Stage 2 (n2>0): flat dbuf pipeline over n2*4 k-steps of Xs(64x128) @ B2.
// LDS 40KB: [0,8KB) A dbuf | [8KB,24KB) B dbuf | [24KB,40KB) Xs;
// stage-2 B2 dbuf (16KB) aliases [0,16KB).
struct GemmSeg {
  const ushort* A; const ushort* B; const float* bias;
  void* out; const ushort* xsP;
  int Ktiles, ldo, Mreal, skip_idx, epi, NT, start;
  int n2; const ushort* B2; const float* bias2;
  void* out2; int ldo2, Mreal2, epi2;
  const float* Af; int Kf, Mf;
};
struct Gemm3 { GemmSeg s[3]; const float* skip; int nseg; };

__launch_bounds__(256)
__global__ void gemm_sched(Gemm3 g3)
{
  __shared__ __align__(16) ushort lds[20480];
  ushort* Xs = lds + 12288;    // 64x128 packed (4 k-chunks x 2048 ushorts)

  int bid = blockIdx.x;
  int si = 0;
  if (g3.nseg > 1 && bid >= g3.s[1].start)
    si = (g3.nseg > 2 && bid >= g3.s[2].start) ? 2 : 1;
  const GemmSeg sg = g3.s[si];
  int local = bid - sg.start;
  int tmH = local / sg.NT, tn = local - tmH * sg.NT;
  int tm = tmH >> 1, hm = tmH & 1;

  const int t = threadIdx.x;
  const int wave = t >> 6, lane = t & 63;
  const int wn = wave * 32;
  const int l16 = lane & 15, quad = lane >> 4;
  const int Ktiles = sg.Ktiles;
  const int swz = (quad ^ ((l16 >> 1) & 3)) * 8;

  const ushort* Ahalf = sg.A + ((size_t)tm * Ktiles) * 4096 + hm * 2048;
  const ushort* Bbase = sg.B + (size_t)tn * Ktiles * 4096;

  // f32 A-staging decode: thread t owns packed slot t of the 64x32 half
  const int aprow = t >> 2, asw = t & 3;
  const int achunk = asw ^ ((aprow >> 1) & 3);
  const int agrow = tm * 128 + hm * 64 + aprow;
  const bool arowok = (sg.Af == nullptr) || (agrow < sg.Mf);
  const float* axrow = sg.Af + (size_t)(arowok ? agrow : 0) * sg.Kf;

  floatx4 acc[4][2];
#pragma unroll
  for (int i = 0; i < 4; ++i)
#pragma unroll
    for (int j = 0; j < 2; ++j) acc[i][j] = (floatx4){0.f, 0.f, 0.f, 0.f};

  // T14 split: loadA issues the fp32 reads into registers (no wait consumed
  // until writeA converts+writes them to LDS after the MFMA cluster).
  auto loadA = [&](int tk, float4& a, float4& b) {
    int gk = tk * 32 + achunk * 8;
    if (arowok && gk + 8 <= sg.Kf) {
      const float* p = axrow + gk;
      a = *(const float4*)p;
      b = *(const float4*)(p + 4);
    } else {
      float tf[8];
#pragma unroll
      for (int j = 0; j < 8; ++j) {
        int kk = gk + j;
        tf[j] = (arowok && kk < sg.Kf) ? axrow[kk] : 0.f;
      }
      a = make_float4(tf[0], tf[1], tf[2], tf[3]);
      b = make_float4(tf[4], tf[5], tf[6], tf[7]);
    }
  };
  auto writeA = [&](int buf, float4 a, float4 b) {
    ushort tmp[8];
    tmp[0] = f2b(a.x); tmp[1] = f2b(a.y); tmp[2] = f2b(a.z); tmp[3] = f2b(a.w);
    tmp[4] = f2b(b.x); tmp[5] = f2b(b.y); tmp[6] = f2b(b.z); tmp[7] = f2b(b.w);
    *(short8*)&lds[buf * 2048 + t * 8] = *(short8*)tmp;
  };
  auto stageApacked = [&](int tk, int buf) {
    gll16(Ahalf + (size_t)tk * 4096 + wave * 512 + lane * 8,
          lds + buf * 2048 + wave * 512);
  };
  auto stageB = [&](int tk, int buf) {
#pragma unroll
    for (int j = 0; j < 2; ++j) {
      int c = wave * 2 + j;
      gll16(Bbase + (size_t)tk * 4096 + c * 512 + lane * 8,
            lds + 4096 + buf * 4096 + c * 512);
    }
  };
  auto stage2L = [&](int s2, int buf) {
#pragma unroll
    for (int j = 0; j < 2; ++j) {
      int c = wave * 2 + j;
      gll16(sg.B2 + (size_t)s2 * 4096 + c * 512 + lane * 8,
            lds + buf * 4096 + c * 512);
    }
  };

  stageB(0, 0);
  if (sg.Af != nullptr) {
    float4 a0, b0;
    loadA(0, a0, b0);
    writeA(0, a0, b0);
  } else {
    stageApacked(0, 0);
  }
  __syncthreads();

  float4 na, nb;
  for (int tk = 0; tk < Ktiles; ++tk) {
    int buf = tk & 1;
    bool pre = tk + 1 < Ktiles;
    if (pre) {
      stageB(tk + 1, buf ^ 1);
      if (sg.Af != nullptr) loadA(tk + 1, na, nb);   // issue only; no wait yet
      else stageApacked(tk + 1, buf ^ 1);
    }

    short8 af[4], bfr[2];
#pragma unroll
    for (int i = 0; i < 4; ++i)
      af[i] = *(const short8*)&lds[buf * 2048 + (i * 16 + l16) * 32 + swz];
#pragma unroll
    for (int n = 0; n < 2; ++n)
      bfr[n] = *(const short8*)&lds[4096 + buf * 4096 + (wn + n * 16 + l16) * 32 + swz];
#pragma unroll
    for (int mi = 0; mi < 4; ++mi)
#pragma unroll
      for (int ni = 0; ni < 2; ++ni)
        acc[mi][ni] = __builtin_amdgcn_mfma_f32_16x16x32_bf16(
            bfr[ni], af[mi], acc[mi][ni], 0, 0, 0);

    if (pre && sg.Af != nullptr) writeA(buf ^ 1, na, nb);  // wait lands here
    __syncthreads();
  }

  // prefetch first stage-2 B tile under the epilogue (aliases dead stage-1 LDS)
  if (sg.n2 > 0) stage2L(0, 0);

  const int epi = sg.epi;
  float g = 0.f, omg = 0.f;
  if (epi == 2 || epi == 3 || epi == 5) {
    float s = g3.skip[sg.skip_idx];
    g = 1.f / (1.f + __expf(-s));
    omg = 1.f - g;
  }
#pragma unroll
  for (int ni = 0; ni < 2; ++ni) {
    int cl = wn + ni * 16 + quad * 4;     // 4 consecutive local cols
    int cb = tn * 128 + cl;
    float4 b4 = *(const float4*)&sg.bias[cb];
#pragma unroll
    for (int mi = 0; mi < 4; ++mi) {
      int prow = mi * 16 + l16;           // local row in the 64-row half
      int rr = tm * 128 + hm * 64 + prow;
      float v0 = acc[mi][ni][0] + b4.x;
      float v1 = acc[mi][ni][1] + b4.y;
      float v2 = acc[mi][ni][2] + b4.z;
      float v3 = acc[mi][ni][3] + b4.w;
      if (epi == 0) {
        uint2 o = make_uint2(((uint)f2b(v1) << 16) | f2b(v0),
                             ((uint)f2b(v3) << 16) | f2b(v2));
        *(uint2*)&((ushort*)sg.out)[(size_t)rr * sg.ldo + cb] = o;
      } else if (epi == 1) {
        if (rr < sg.Mreal)
          *(float4*)&((float*)sg.out)[(size_t)rr * sg.ldo + cb] =
              make_float4(v0, v1, v2, v3);
      } else if (epi == 2) {
        if (rr < sg.Mreal) {
          uint2 xo = *(const uint2*)&sg.xsP[a_packed_us(rr, cb)];
          float4 o;
          o.x = fmaxf(g * v0 + omg * blo(xo.x), 0.f);
          o.y = fmaxf(g * v1 + omg * bhi(xo.x), 0.f);
          o.z = fmaxf(g * v2 + omg * blo(xo.y), 0.f);
          o.w = fmaxf(g * v3 + omg * bhi(xo.y), 0.f);
          *(float4*)&((float*)sg.out)[(size_t)rr * sg.ldo + cb] = o;
        }
      } else if (epi == 3) {
        uint2 xo = *(const uint2*)&sg.xsP[a_packed_us(rr, cb)];
        uint2 o = make_uint2(
            ((uint)f2b(fmaxf(g * v1 + omg * bhi(xo.x), 0.f)) << 16) |
                   f2b(fmaxf(g * v0 + omg * blo(xo.x), 0.f)),
            ((uint)f2b(fmaxf(g * v3 + omg * bhi(xo.y), 0.f)) << 16) |
                   f2b(fmaxf(g * v2 + omg * blo(xo.y), 0.f)));
        *(uint2*)&((ushort*)sg.out)[a_packed_us(rr, cb)] = o;
      } else if (epi == 4) {
        uint2 o = make_uint2(((uint)f2b(v1) << 16) | f2b(v0),
                             ((uint)f2b(v3) << 16) | f2b(v2));
        *(uint2*)&((ushort*)sg.out)[a_packed_us(rr, cb)] = o;
        int kin = cl & 31;
        int sw2 = (kin >> 3) ^ ((prow >> 1) & 3);
        *(uint2*)&Xs[(cl >> 5) * 2048 + prow * 32 + sw2 * 8 + (kin & 7)] = o;
      } else {  // 5: skip-relu into Xs only
        uint2 xo = *(const uint2*)&sg.xsP[a_packed_us(rr, cb)];
        uint2 o = make_uint2(
            ((uint)f2b(fmaxf(g * v1 + omg * bhi(xo.x), 0.f)) << 16) |
                   f2b(fmaxf(g * v0 + omg * blo(xo.x), 0.f)),
            ((uint)f2b(fmaxf(g * v3 + omg * bhi(xo.y), 0.f)) << 16) |
                   f2b(fmaxf(g * v2 + omg * blo(xo.y), 0.f)));
        int kin = cl & 31;
        int sw2 = (kin >> 3) ^ ((prow >> 1) & 3);
        *(uint2*)&Xs[(cl >> 5) * 2048 + prow * 32 + sw2 * 8 + (kin & 7)] = o;
      }
    }
  }

  // ---------------- stage 2: flat pipeline over n2*4 k-steps ----------------
  if (sg.n2 == 0) return;
  __syncthreads();   // Xs + first B2 tile ready
  int total2 = sg.n2 * 4;
  floatx4 a2[4][2];
#pragma unroll
  for (int i = 0; i < 4; ++i)
#pragma unroll
    for (int j = 0; j < 2; ++j) a2[i][j] = (floatx4){0.f, 0.f, 0.f, 0.f};
  for (int s2 = 0; s2 < total2; ++s2) {
    int buf = s2 & 1;
    if (s2 + 1 < total2) stage2L(s2 + 1, buf ^ 1);
    int xb = (s2 & 3) * 2048;
    short8 af[4], bfr[2];
#pragma unroll
    for (int i = 0; i < 4; ++i)
      af[i] = *(const short8*)&Xs[xb + (i * 16 + l16) * 32 + swz];
#pragma unroll
    for (int n = 0; n < 2; ++n)
      bfr[n] = *(const short8*)&lds[buf * 4096 + (wn + n * 16 + l16) * 32 + swz];
#pragma unroll
    for (int mi = 0; mi < 4; ++mi)
#pragma unroll
      for (int ni = 0; ni < 2; ++ni)
        a2[mi][ni] = __builtin_amdgcn_mfma_f32_16x16x32_bf16(
            bfr[ni], af[mi], a2[mi][ni], 0, 0, 0);
    __syncthreads();
    if ((s2 & 3) == 3) {
      int t2 = s2 >> 2;
#pragma unroll
      for (int ni = 0; ni < 2; ++ni) {
        int cb2 = t2 * 128 + wn + ni * 16 + quad * 4;
        float4 b4 = *(const float4*)&sg.bias2[cb2];
#pragma unroll
        for (int mi = 0; mi < 4; ++mi) {
          int rr = tm * 128 + hm * 64 + mi * 16 + l16;
          float v0 = a2[mi][ni][0] + b4.x;
          float v1 = a2[mi][ni][1] + b4.y;
          float v2 = a2[mi][ni][2] + b4.z;
          float v3 = a2[mi][ni][3] + b4.w;
          if (sg.epi2 == 0) {
            uint2 o = make_uint2(((uint)f2b(v1) << 16) | f2b(v0),
                                 ((uint)f2b(v3) << 16) | f2b(v2));
            *(uint2*)&((ushort*)sg.out2)[(size_t)rr * sg.ldo2 + cb2] = o;
          } else {
            if (rr < sg.Mreal2)
              *(float4*)&((float*)sg.out2)[(size_t)rr * sg.ldo2 + cb2] =
                  make_float4(v0, v1, v2, v3);
          }
          a2[mi][ni] = (floatx4){0.f, 0.f, 0.f, 0.f};
        }
      }
    }
  }
}

// ================= gather: one wave per dst node, 2x4 edges/iter ==========
// (measured-best 8-edge form: VGPR 32, occupancy ~70%)
struct GatherType { const ushort* q; ushort* agg; int ldq; };
struct GatherDesc { GatherType ty[3]; int n0, n1; };

__launch_bounds__(256)
__global__ void gather_all(const int* __restrict__ starts,
                           const uint* __restrict__ payload,
                           const ushort* __restrict__ kvbase,
                           GatherDesc gd, int Ntot)
{
  int wid = (blockIdx.x * 256 + threadIdx.x) >> 6;
  if (wid >= Ntot) return;
  int lane = threadIdx.x & 63;
  int g = lane >> 4, l = lane & 15;

  GatherType T;
  int d;
  if (wid < gd.n0)      { T = gd.ty[0]; d = wid; }
  else if (wid < gd.n1) { T = gd.ty[1]; d = wid - gd.n0; }
  else                  { T = gd.ty[2]; d = wid - gd.n1; }

  const char* kvb = (const char*)kvbase;
  const uint lofs = (uint)l * 16u;

  uint4 qv = *(const uint4*)(T.q + (size_t)d * T.ldq + l * 8);
  f32x2 q0 = b2x2(qv.x), q1 = b2x2(qv.y), q2 = b2x2(qv.z), q3 = b2x2(qv.w);

  int e0 = starts[wid], e1 = starts[wid + 1];
  float lsum = 0.f;
  f32x2 ac0 = {0.f, 0.f}, ac1 = {0.f, 0.f}, ac2 = {0.f, 0.f}, ac3 = {0.f, 0.f};

  for (int eb = e0; eb < e1; eb += 8) {
    int eA = eb + g, eB = eA + 4;
    bool actA = eA < e1, actB = eB < e1;
    uint pA = payload[actA ? eA : e0];
    uint pB = payload[actB ? eB : e0];
    const char* bA = kvb + (pA + lofs);
    const char* bB = kvb + (pB + lofs);
    uint4 kA = *(const uint4*)bA;
    uint4 vA = *(const uint4*)(bA + 256);
    uint4 kB = *(const uint4*)bB;
    uint4 vB = *(const uint4*)(bB + 256);

    f32x2 dA = q0 * b2x2(kA.x);
    dA = __builtin_elementwise_fma(q1, b2x2(kA.y), dA);
    dA = __builtin_elementwise_fma(q2, b2x2(kA.z), dA);
    dA = __builtin_elementwise_fma(q3, b2x2(kA.w), dA);
    f32x2 dB = q0 * b2x2(kB.x);
    dB = __builtin_elementwise_fma(q1, b2x2(kB.y), dB);
    dB = __builtin_elementwise_fma(q2, b2x2(kB.z), dB);
    dB = __builtin_elementwise_fma(q3, b2x2(kB.w), dB);
    float pa = dA.x + dA.y;
    float pb = dB.x + dB.y;
    pa += __shfl_xor(pa, 1, 64);
    pb += __shfl_xor(pb, 1, 64);
    float exA = exp2f(fminf(pa, 115.4f));
    float exB = exp2f(fminf(pb, 115.4f));
    exA = actA ? exA : 0.f;
    exB = actB ? exB : 0.f;
    lsum += exA + exB;
    f32x2 xA = {exA, exA}, xB = {exB, exB};
    ac0 = __builtin_elementwise_fma(xA, b2x2(vA.x), ac0);
    ac1 = __builtin_elementwise_fma(xA, b2x2(vA.y), ac1);
    ac2 = __builtin_elementwise_fma(xA, b2x2(vA.z), ac2);
    ac3 = __builtin_elementwise_fma(xA, b2x2(vA.w), ac3);
    ac0 = __builtin_elementwise_fma(xB, b2x2(vB.x), ac0);
    ac1 = __builtin_elementwise_fma(xB, b2x2(vB.y), ac1);
    ac2 = __builtin_elementwise_fma(xB, b2x2(vB.z), ac2);
    ac3 = __builtin_elementwise_fma(xB, b2x2(vB.w), ac3);
  }

  float s0 = ac0.x, s1 = ac0.y, s2 = ac1.x, s3 = ac1.y;
  float s4 = ac2.x, s5 = ac2.y, s6 = ac3.x, s7 = ac3.y;
#define MRG(v) v += __shfl_xor(v, 16, 64); v += __shfl_xor(v, 32, 64)
  MRG(lsum); MRG(s0); MRG(s1); MRG(s2); MRG(s3); MRG(s4); MRG(s5); MRG(s6); MRG(s7);
#undef MRG

  // each lane finishes channels c0 = 8*l + 2*g and c0+1
  float inv = 1.f / (lsum + 1e-16f);
  float m0 = (g & 1) ? s2 : s0, m1 = (g & 1) ? s6 : s4;
  float n0 = (g & 1) ? s3 : s1, n1 = (g & 1) ? s7 : s5;
  float x0 = ((g & 2) ? m1 : m0) * inv;
  float x1 = ((g & 2) ? n1 : n0) * inv;
  float g0 = 0.5f * x0 * (1.f + erff(x0 * 0.70710678118654752f));
  float g1 = 0.5f * x1 * (1.f + erff(x1 * 0.70710678118654752f));
  int tm = d >> 7, row = d & 127;
  int tk = l >> 2, sw = (l & 3) ^ ((row >> 1) & 3);
  size_t us = (((size_t)tm * 4 + tk) * 512 + (size_t)row * 4 + sw) * 8 + 2 * g;
  *(uint*)(T.agg + us) = ((uint)f2b(g1) << 16) | (uint)f2b(g0);
}

// ================= host =====================================================
extern "C" void kernel_launch(void* const* d_in, const int* in_sizes, int n_in,
                              void* d_out, int out_size, void* d_ws, size_t ws_size,
                              hipStream_t stream)
{
  const float* x_herb = (const float*)d_in[0];
  const float* x_ing  = (const float*)d_in[1];
  const float* x_tgt  = (const float*)d_in[2];
  const float* W_herb = (const float*)d_in[3];
  const float* b_herb = (const float*)d_in[4];
  const float* W_ing  = (const float*)d_in[5];
  const float* b_ing  = (const float*)d_in[6];
  const float* W_tgt  = (const float*)d_in[7];
  const float* b_tgt  = (const float*)d_in[8];
  const float* Wk     = (const float*)d_in[9];
  const float* bk     = (const float*)d_in[10];
  const float* Wq     = (const float*)d_in[11];
  const float* bq     = (const float*)d_in[12];
  const float* Wv     = (const float*)d_in[13];
  const float* bv     = (const float*)d_in[14];
  const float* a_rel  = (const float*)d_in[15];
  const float* m_rel  = (const float*)d_in[16];
  const float* p_rel  = (const float*)d_in[17];
  const float* Wa     = (const float*)d_in[18];
  const float* ba     = (const float*)d_in[19];
  const float* skip   = (const float*)d_in[20];
  const float* W_out  = (const float*)d_in[21];
  const float* b_out  = (const float*)d_in[22];
  const int* srcs[4] = {(const int*)d_in[23], (const int*)d_in[25],
                        (const int*)d_in[27], (const int*)d_in[29]};
  const int* dsts[4] = {(const int*)d_in[24], (const int*)d_in[26],
                        (const int*)d_in[28], (const int*)d_in[30]};

  const int Nh = in_sizes[0] / 400;
  const int Ni = in_sizes[1] / 300;
  const int Nt = in_sizes[2] / 200;
  const int E  = in_sizes[23];
  const int Ntot = Nh + Ni + Nt;

  const int MT_h = (Nh + 127) / 128, MT_i = (Ni + 127) / 128, MT_t = (Nt + 127) / 128;
  const int KT_h = 13, KT_i = 10, KT_t = 7;   // Kpad 416/320/224

  // CSR sort params
  const int NBs = (E + CSR_CH - 1) / CSR_CH;
  const int NBH = 4 * NBs;
  const int NBK = (Ntot + (1 << CSR_SH) - 1) >> CSR_SH;   // <= 511

  char* base = (char*)d_ws;
  size_t off = 0;
  auto A = [&](size_t bytes) -> void* {
    void* p = base + off; off += (bytes + 255) & ~(size_t)255; return p;
  };
  ushort* xsP_h = (ushort*)A((size_t)MT_h * 4 * 8192);
  ushort* xsP_i = (ushort*)A((size_t)MT_i * 4 * 8192);
  ushort* xsP_t = (ushort*)A((size_t)MT_t * 4 * 8192);
  ushort* fused_h = (ushort*)A((size_t)MT_h * 128 * 384 * 2);  // [q|k0|v0]
  ushort* fused_i = (ushort*)A((size_t)MT_i * 128 * 640 * 2);  // [q|k1|v1|k2|v2]
  ushort* fused_t = (ushort*)A((size_t)MT_t * 128 * 384 * 2);  // [q|k3|v3]
  ushort* aggp_h  = (ushort*)A((size_t)MT_h * 4 * 8192);
  ushort* aggp_i  = (ushort*)A((size_t)MT_i * 4 * 8192);
  ushort* aggp_t  = (ushort*)A((size_t)MT_t * 4 * 8192);
  ushort* Weff1_h = (ushort*)A((size_t)KT_h * 8192);
  ushort* Weff1_i = (ushort*)A((size_t)KT_i * 8192);
  ushort* Weff1_t = (ushort*)A((size_t)KT_t * 8192);
  ushort* Wcat_h = (ushort*)A((size_t)3 * 4 * 8192);
  ushort* Wcat_i = (ushort*)A((size_t)5 * 4 * 8192);
  ushort* Wcat_t = (ushort*)A((size_t)3 * 4 * 8192);
  float* bcat   = (float*)A(1408 * 4);
  ushort* Wa_t   = (ushort*)A((size_t)3 * 16384 * 2);
  ushort* Wout_t = (ushort*)A((size_t)16384 * 2);
  int* starts  = (int*)A((size_t)(Ntot + 4) * 4);
  uint* payload = (uint*)A((size_t)(4 * E + 8) * 4);
  uint* hist    = (uint*)A((size_t)NBK * NBH * 4);
  uint* bucketTot  = (uint*)A((size_t)NBK * 4);
  uint2* inter  = (uint2*)A((size_t)(4 * E + 8) * 8);
  (void)ws_size; (void)n_in;

  const int toff_h = 0, toff_i = Nh, toff_t = Nh + Ni;
  dim3 blk(256);

  uint fi2 = (uint)((size_t)(fused_i - fused_h) * 2);
  uint ft2 = (uint)((size_t)(fused_t - fused_h) * 2);

  // --- 1: prologue (combine_rel + weight prep + bq + edge hist) ---
  Prolog P;
  P.wstart = 4 * 2 * 129 * 128;
  {
    const float* wsrc10[10] = {W_herb, W_ing, W_tgt, Wq, Wq + 16384, Wq + 32768,
                               Wa, Wa + 16384, Wa + 32768, W_out};
    ushort* wdst10[10] = {Weff1_h, Weff1_i, Weff1_t, Wcat_h, Wcat_i, Wcat_t,
                          Wa_t, Wa_t + 16384, Wa_t + 32768, Wout_t};
    int wk10[10] = {400, 300, 200, 128, 128, 128, 128, 128, 128, 128};
    int wcum = 0;
    for (int z = 0; z < 10; ++z) {
      P.wb[z] = {wsrc10[z], wdst10[z], wk10[z], wcum};
      wcum += ((wk10[z] + 31) / 32) * 512;
    }
    P.bstart = P.wstart + wcum;
  }
  P.total = P.bstart + 384;
  P.Wk = Wk; P.bk = bk; P.Wv = Wv; P.bv = bv;
  P.a_rel = a_rel; P.m_rel = m_rel; P.p_rel = p_rel;
  P.kw_dst[0] = Wcat_h + 16384; P.vw_dst[0] = Wcat_h + 32768;
  P.kw_dst[1] = Wcat_i + 16384; P.vw_dst[1] = Wcat_i + 32768;
  P.kw_dst[2] = Wcat_i + 49152; P.vw_dst[2] = Wcat_i + 65536;
  P.kw_dst[3] = Wcat_t + 16384; P.vw_dst[3] = Wcat_t + 32768;
  P.bcat = bcat;
  P.kb_off[0] = 128;  P.vb_off[0] = 256;
  P.kb_off[1] = 512;  P.vb_off[1] = 640;
  P.kb_off[2] = 768;  P.vb_off[2] = 896;
  P.kb_off[3] = 1152; P.vb_off[3] = 1280;
  P.bq = bq;
  P.bq_off[0] = 0; P.bq_off[1] = 384; P.bq_off[2] = 1024;
  P.edst[0] = dsts[0]; P.eoff[0] = toff_i;
  P.edst[1] = dsts[1]; P.eoff[1] = toff_h;
  P.edst[2] = dsts[2]; P.eoff[2] = toff_t;
  P.edst[3] = dsts[3]; P.eoff[3] = toff_i;
  P.hist = hist; P.NBs = NBs; P.NBH = NBH; P.NBK = NBK; P.E = E;
  prologue<<<NBH + (P.total + 255) / 256, blk, 0, stream>>>(P);

  // --- 2: CSR build (scan -> scatter -> finalize) ---
  EdgeStreams ES;
  ES.src[0] = srcs[0]; ES.dst[0] = dsts[0]; ES.off[0] = toff_i;
  ES.rel[0] = 256u;        ES.ldb[0] = 768u;
  ES.src[1] = srcs[1]; ES.dst[1] = dsts[1]; ES.off[1] = toff_h;
  ES.rel[1] = fi2 + 256u;  ES.ldb[1] = 1280u;
  ES.src[2] = srcs[2]; ES.dst[2] = dsts[2]; ES.off[2] = toff_t;
  ES.rel[2] = fi2 + 768u;  ES.ldb[2] = 1280u;
  ES.src[3] = srcs[3]; ES.dst[3] = dsts[3]; ES.off[3] = toff_i;
  ES.rel[3] = ft2 + 256u;  ES.ldb[3] = 768u;
  bucket_scan<<<NBK, blk, 0, stream>>>(hist, bucketTot, NBH);
  bucket_scatter<<<NBH, blk, 0, stream>>>(ES, hist, bucketTot, inter, NBs, NBH, NBK, E);
  bucket_finalize<<<NBK, blk, 0, stream>>>(inter, bucketTot, starts, payload, Ntot, NBK);

  // --- 3: K1 = pack + GEMM1 + GEMM2 fused, 64-row blocks (A from fp32 x) ---
  Gemm3 G1;
  G1.skip = skip; G1.nseg = 3;
  G1.s[0] = {nullptr, Weff1_h, b_herb, xsP_h, nullptr, KT_h, 0, 0, 0, 4, 1, 0,
             3, Wcat_h, bcat + 0, fused_h, 384, 0, 0, x_herb, 400, Nh};
  G1.s[1] = {nullptr, Weff1_i, b_ing,  xsP_i, nullptr, KT_i, 0, 0, 0, 4, 1, 2 * MT_h,
             5, Wcat_i, bcat + 384, fused_i, 640, 0, 0, x_ing, 300, Ni};
  G1.s[2] = {nullptr, Weff1_t, b_tgt,  xsP_t, nullptr, KT_t, 0, 0, 0, 4, 1,
             2 * (MT_h + MT_i),
             3, Wcat_t, bcat + 1024, fused_t, 384, 0, 0, x_tgt, 200, Nt};
  gemm_sched<<<2 * (MT_h + MT_i + MT_t), blk, 0, stream>>>(G1);

  // --- 4: gather attention (all types, one wave per node) ---
  GatherDesc GD;
  GD.n0 = Nh; GD.n1 = Nh + Ni;
  GD.ty[0] = {fused_h, aggp_h, 384};
  GD.ty[1] = {fused_i, aggp_i, 640};
  GD.ty[2] = {fused_t, aggp_t, 384};
  gather_all<<<(Ntot + 3) / 4, blk, 0, stream>>>(starts, payload, fused_h, GD, Ntot);

  // --- 5: K2 = epilogue GEMMs, 64-row blocks; herb chains W_out from LDS ---
  float* outp = (float*)d_out;
  float* out_herb = outp;
  float* out_ing  = outp + (size_t)Nh * HID;
  float* out_tgt  = outp + (size_t)(Nh + Ni) * HID;
  Gemm3 GE;
  GE.skip = skip; GE.nseg = 3;
  GE.s[0] = {aggp_h, Wa_t + 0 * 16384, ba + 0 * 128, nullptr, xsP_h,
             4, 0, 0, 0, 5, 1, 0,
             1, Wout_t, b_out, out_herb, 128, Nh, 1, nullptr, 0, 0};
  GE.s[1] = {aggp_i, Wa_t + 1 * 16384, ba + 1 * 128, out_ing, xsP_i,
             4, 128, Ni, 1, 2, 1, 2 * MT_h,
             0, nullptr, nullptr, nullptr, 0, 0, 0, nullptr, 0, 0};
  GE.s[2] = {aggp_t, Wa_t + 2 * 16384, ba + 2 * 128, out_tgt, xsP_t,
             4, 128, Nt, 2, 2, 1, 2 * (MT_h + MT_i),
             0, nullptr, nullptr, nullptr, 0, 0, 0, nullptr, 0, 0};
  gemm_sched<<<2 * (MT_h + MT_i + MT_t), blk, 0, stream>>>(GE);
  (void)out_size;
}